// Round 8
// baseline (518.346 us; speedup 1.0000x reference)
//
#include <hip/hip_runtime.h>
#include <hip/hip_bf16.h>

#define TOK 9216   // 96*96 tokens per image
#define KSPLIT 5

typedef _Float16 half8 __attribute__((ext_vector_type(8)));
typedef float f32x4 __attribute__((ext_vector_type(4)));

// ---------------- workspace layout (in floats) ----------------
#define OFF_F1   0u
#define SZ_F1    (4u*64u*TOK)            // conv1 out  [img][64][9216]
#define OFF_FEAT (OFF_F1 + SZ_F1)
#define SZ_FEAT  (2u*128u*TOK)           // conv2 out, permuted: [b][c*2+n][9216]
#define OFF_Q    (OFF_FEAT + SZ_FEAT)
#define SZ_QKV   (2u*64u*TOK)
#define OFF_K    (OFF_Q + SZ_QKV)
#define OFF_V    (OFF_K + SZ_QKV)
#define OFF_W1   (OFF_V + SZ_QKV)        // [64][9] f32
#define OFF_B1   (OFF_W1 + 576u)
#define OFF_W2T  (OFF_B1 + 64u)          // [ci][9][co] f32 (transposed)
#define OFF_B2   (OFF_W2T + 36864u)
#define OFF_WCAT (OFF_B2 + 64u)          // [192][128] f32 (q;k;v)
#define OFF_BCAT (OFF_WCAT + 24576u)     // [192]

// f16 QKV overlaid on F1 (dead after conv2). Offsets in f32 units.
#define OFF_QT   OFF_F1                  // [b][t][64] f16, scale*log2e folded
#define OFF_KT   (OFF_F1 + 589824u)      // [b][t][64] f16
#define OFF_VH   (OFF_F1 + 1179648u)     // [b][64][t] f16, ends at 1769472

// KV-split partials: 10 slabs of 64*TOK f32 each (589824 floats).
// slab 0 -> free tail of F1 region (after VH); slabs 1..9 -> FEAT..V region.
// All dead once attn runs; rewritten by conv2/qkv/cvt every replay.
#define OFF_SLAB0 1769472u
#define OFF_ML2   (OFF_FEAT + 9u*589824u)   // [slab][2 (m,l)][TOK] f32

__device__ __forceinline__ const float* part_base_c(const float* ws, int slab) {
    return ws + (slab == 0 ? OFF_SLAB0 : (OFF_FEAT + (unsigned)(slab - 1) * 589824u));
}
__device__ __forceinline__ float* part_base(float* ws, int slab) {
    return ws + (slab == 0 ? OFF_SLAB0 : (OFF_FEAT + (unsigned)(slab - 1) * 589824u));
}

// ---------------- weight prep: copy/transpose f32 weights ----------------
__global__ __launch_bounds__(256) void prep_kernel(
    const float* __restrict__ w1, const float* __restrict__ b1,
    const float* __restrict__ w2, const float* __restrict__ b2,
    const float* __restrict__ qw, const float* __restrict__ qb,
    const float* __restrict__ kw, const float* __restrict__ kb,
    const float* __restrict__ vw, const float* __restrict__ vb,
    float* __restrict__ ws)
{
    int gid = blockIdx.x * 256 + threadIdx.x;
    if (gid < 576) ws[OFF_W1 + gid] = w1[gid];
    if (gid < 64) {
        ws[OFF_B1 + gid] = b1[gid];
        ws[OFF_B2 + gid] = b2[gid];
    }
    if (gid < 36864) {   // w2[co][ci][tap] -> w2t[ci][tap][co]
        int co = gid / 576; int rem = gid % 576;
        int ci = rem / 9;  int tp = rem % 9;
        ws[OFF_W2T + (ci*9 + tp)*64 + co] = w2[gid];
    }
    if (gid < 24576) {
        int o = gid >> 7; int c = gid & 127;
        float v;
        if (o < 64)       v = qw[o*128 + c];
        else if (o < 128) v = kw[(o-64)*128 + c];
        else              v = vw[(o-128)*128 + c];
        ws[OFF_WCAT + gid] = v;
    }
    if (gid < 192) {
        float v;
        if (gid < 64)       v = qb[gid];
        else if (gid < 128) v = kb[gid-64];
        else                v = vb[gid-128];
        ws[OFF_BCAT + gid] = v;
    }
}

// ---------------- conv1: 1->64 ch, 3x3, relu ----------------
__global__ __launch_bounds__(256) void conv1_kernel(
    const float* __restrict__ x, float* __restrict__ ws)
{
    const float* w1f = ws + OFF_W1;
    const float* b1f = ws + OFF_B1;
    float* f1 = ws + OFF_F1;
    int gid = blockIdx.x * 256 + threadIdx.x;
    int img = gid / TOK;
    int p   = gid % TOK;
    int h = p / 96, w = p % 96;
    float xv[9];
    #pragma unroll
    for (int dh = 0; dh < 3; ++dh)
        #pragma unroll
        for (int dw = 0; dw < 3; ++dw) {
            int r = h + dh - 1, c = w + dw - 1;
            bool ok = (r >= 0) && (r < 96) && (c >= 0) && (c < 96);
            xv[dh*3 + dw] = ok ? x[img*TOK + r*96 + c] : 0.f;
        }
    for (int co = 0; co < 64; ++co) {
        float a = b1f[co];
        #pragma unroll
        for (int t = 0; t < 9; ++t) a += w1f[co*9 + t] * xv[t];
        f1[(size_t)(img*64 + co)*TOK + p] = fmaxf(a, 0.f);
    }
}

// ---------------- conv2: 64->64 ch, 3x3, relu; writes permuted feat ----------------
__global__ __launch_bounds__(256) void conv2_kernel(float* __restrict__ ws)
{
    __align__(16) __shared__ float sT[64 * 156];
    const float* f1  = ws + OFF_F1;
    const float* w2t = ws + OFF_W2T;
    const float* b2f = ws + OFF_B2;
    float* feat = ws + OFF_FEAT;

    int bid = blockIdx.x;            // 4 img * 96 rows * 2 strips = 768
    int img = bid / 192;
    int rem = bid % 192;
    int h  = rem >> 1;
    int s2 = rem & 1;
    int tid = threadIdx.x;

    for (int idx = tid; idx < 9600; idx += 256) {
        int ci = idx / 150;
        int r2 = idx % 150;
        int r = r2 / 50, cc = r2 % 50;
        int row = h - 1 + r, col = s2*48 - 1 + cc;
        float v = 0.f;
        if (row >= 0 && row < 96 && col >= 0 && col < 96)
            v = f1[(size_t)(img*64 + ci)*TOK + row*96 + col];
        sT[ci*156 + r*52 + cc] = v;
    }
    __syncthreads();

    int co = tid & 63, g = tid >> 6;
    int px0 = g * 12;
    float acc[12];
    float bb = b2f[co];
    #pragma unroll
    for (int j = 0; j < 12; ++j) acc[j] = bb;

    for (int ci = 0; ci < 64; ++ci) {
        float wv[9];
        #pragma unroll
        for (int t = 0; t < 9; ++t) wv[t] = w2t[(ci*9 + t)*64 + co];
        #pragma unroll
        for (int r = 0; r < 3; ++r) {
            const float4* tp4 = (const float4*)&sT[ci*156 + r*52 + px0];
            float4 a0 = tp4[0], a1 = tp4[1], a2 = tp4[2], a3 = tp4[3];
            float t16[16] = {a0.x,a0.y,a0.z,a0.w, a1.x,a1.y,a1.z,a1.w,
                             a2.x,a2.y,a2.z,a2.w, a3.x,a3.y,a3.z,a3.w};
            #pragma unroll
            for (int dw = 0; dw < 3; ++dw) {
                float wgt = wv[r*3 + dw];
                #pragma unroll
                for (int j = 0; j < 12; ++j) acc[j] += wgt * t16[j + dw];
            }
        }
    }
    int b = img >> 1, n = img & 1;
    int colbase = s2*48 + px0;
    #pragma unroll
    for (int j = 0; j < 12; ++j)
        feat[(size_t)(b*128 + co*2 + n)*TOK + h*96 + colbase + j] = fmaxf(acc[j], 0.f);
}

// ---------------- fused 1x1 QKV: [192 out][128 in] GEMV per token ----------------
__global__ __launch_bounds__(256) void qkv_kernel(float* __restrict__ ws)
{
    const float* feat = ws + OFF_FEAT;
    const float* wcat = ws + OFF_WCAT;
    const float* bcat = ws + OFF_BCAT;
    int bid = blockIdx.x;            // 2 * 36 * 48 = 3456
    int b   = bid / (36*48);
    int rem = bid % (36*48);
    int tg  = rem / 48;
    int og  = rem % 48;
    int tid = threadIdx.x;
    int o    = og*4 + (tid >> 6);
    int lane = tid & 63;
    int t0   = tg*256 + lane*4;
    const float* fb   = feat + (size_t)b*128*TOK;
    const float* wrow = wcat + o*128;
    float a0, a1, a2, a3;
    a0 = a1 = a2 = a3 = bcat[o];
    for (int c = 0; c < 128; ++c) {
        float4 fv = *(const float4*)&fb[(size_t)c*TOK + t0];
        float w = wrow[c];
        a0 += w*fv.x; a1 += w*fv.y; a2 += w*fv.z; a3 += w*fv.w;
    }
    float* dst;
    if (o < 64)       dst = ws + OFF_Q + ((size_t)b*64 + o      )*TOK;
    else if (o < 128) dst = ws + OFF_K + ((size_t)b*64 + (o-64 ))*TOK;
    else              dst = ws + OFF_V + ((size_t)b*64 + (o-128))*TOK;
    float4 out4 = {a0, a1, a2, a3};
    *(float4*)&dst[t0] = out4;
}

// ---------------- cvt: f32 [d][t] -> f16 tiles for MFMA ----------------
// Q scale folds 0.125 * log2(e) -> softmax runs in exp2 domain.
__global__ __launch_bounds__(256) void cvt_kernel(float* __restrict__ ws)
{
    __shared__ __align__(16) float lds[64*68];
    int bid = blockIdx.x;
    int tid = threadIdx.x;
    if (bid < 576) {
        int tensor = bid / 288;          // 0=Q, 1=K
        int rem = bid % 288;
        int b = rem / 144, tile = rem % 144;
        int t0 = tile * 64;
        const float* src = ws + (tensor ? OFF_K : OFF_Q) + (size_t)b*64*TOK;
        _Float16* dst = (_Float16*)(ws + (tensor ? OFF_KT : OFF_QT)) + (size_t)b*TOK*64;
        float scale = tensor ? 1.0f : 0.18033688011112042f;   // 0.125*log2(e)
        int d = tid >> 2, seg = tid & 3;
        #pragma unroll
        for (int j = 0; j < 4; ++j) {
            float4 v = *(const float4*)&src[(size_t)d*TOK + t0 + seg*16 + j*4];
            *(float4*)&lds[d*68 + seg*16 + j*4] = v;
        }
        __syncthreads();
        int t = tid >> 2, dseg = tid & 3;
        __align__(16) _Float16 h[16];
        #pragma unroll
        for (int e = 0; e < 16; ++e)
            h[e] = (_Float16)(lds[(dseg*16 + e)*68 + t] * scale);
        *(uint4*)&dst[(size_t)(t0 + t)*64 + dseg*16]     = *(uint4*)&h[0];
        *(uint4*)&dst[(size_t)(t0 + t)*64 + dseg*16 + 8] = *(uint4*)&h[8];
    } else {
        size_t idx = (size_t)(bid - 576) * 1024 + tid * 4;   // over 2*64*TOK
        const float* src = ws + OFF_V;
        _Float16* dst = (_Float16*)(ws + OFF_VH);
        float4 v = *(const float4*)&src[idx];
        union { _Float16 h[4]; uint2 u; } pk;
        pk.h[0] = (_Float16)v.x; pk.h[1] = (_Float16)v.y;
        pk.h[2] = (_Float16)v.z; pk.h[3] = (_Float16)v.w;
        *(uint2*)&dst[idx] = pk.u;
    }
}

// ---------------- flash attention partial: barrier-free, K/V direct from L2 ----------------
// grid = 2b x 144qt x KSPLIT; 256 thr = 4 waves x 16 q-rows; KVBLK=64.
// K/V fragments are 16B-contiguous in global (L2-resident); only P uses LDS
// (wave-private rows -> zero barriers in the main loop).
__global__ __launch_bounds__(256, 6) void attn_kernel(float* __restrict__ ws)
{
    __shared__ __align__(16) char smem[17408];   // sP (8KB) | epilogue ldsf 64x68 f32
    char* sP = smem;            // [64 q][64 m] f16, byte^((q&7)<<4)
    float* ldsf = (float*)smem;

    int bid = blockIdx.x;       // 2 * 144 * KSPLIT
    int b   = bid / (144*KSPLIT);
    int rem = bid % (144*KSPLIT);
    int qt  = rem / KSPLIT;
    int ks  = rem % KSPLIT;
    int tid = threadIdx.x;
    int lane = tid & 63, w = tid >> 6;
    int q0 = qt * 64;
    int lr = lane & 15;         // fragment row/col index
    int lk = lane >> 4;         // k-group (0..3)

    int kb0 = (ks*144)/KSPLIT, kb1 = ((ks+1)*144)/KSPLIT;
    int slab = b*KSPLIT + ks;

    const _Float16* Qt = (const _Float16*)(ws + OFF_QT) + (size_t)b*TOK*64;
    const _Float16* Kt = (const _Float16*)(ws + OFF_KT) + (size_t)b*TOK*64;
    const _Float16* Vh = (const _Float16*)(ws + OFF_VH) + (size_t)b*64*TOK;
    float* part = part_base(ws, slab);
    float* ml   = ws + OFF_ML2 + (size_t)slab*2*TOK;

    // Q fragments in registers (A: row q = lr, k d = ch*32 + lk*8 + e)
    half8 qA[2];
    #pragma unroll
    for (int ch = 0; ch < 2; ++ch)
        qA[ch] = *(const half8*)&Qt[(size_t)(q0 + w*16 + lr)*64 + ch*32 + lk*8];

    f32x4 O[4];                 // [csub]: col c = csub*16+lr, row q = 4*lk+reg
    #pragma unroll
    for (int cs = 0; cs < 4; ++cs) O[cs] = (f32x4){0.f, 0.f, 0.f, 0.f};
    float mM[4], lS[4];
    #pragma unroll
    for (int r = 0; r < 4; ++r) { mM[r] = -INFINITY; lS[r] = 0.f; }

    for (int kb = kb0; kb < kb1; ++kb) {
        const _Float16* Kb = Kt + (size_t)kb*64*64;

        // ---- QK^T: S[q 16][kt 64] per wave; kB 16B-contiguous from L2 ----
        f32x4 S[4];
        #pragma unroll
        for (int st = 0; st < 4; ++st) S[st] = (f32x4){0.f, 0.f, 0.f, 0.f};
        __builtin_amdgcn_s_setprio(1);
        #pragma unroll
        for (int st = 0; st < 4; ++st) {
            int t = st*16 + lr;
            #pragma unroll
            for (int ch = 0; ch < 2; ++ch) {
                half8 kB = *(const half8*)&Kb[t*64 + ch*32 + lk*8];
                S[st] = __builtin_amdgcn_mfma_f32_16x16x32_f16(qA[ch], kB, S[st], 0, 0, 0);
            }
        }
        __builtin_amdgcn_s_setprio(0);

        // ---- online softmax, exp2 domain (rows live on 16-lane groups) ----
        float pm[4];
        #pragma unroll
        for (int r = 0; r < 4; ++r)
            pm[r] = fmaxf(fmaxf(S[0][r], S[1][r]), fmaxf(S[2][r], S[3][r]));
        #pragma unroll
        for (int mk = 1; mk <= 8; mk <<= 1)
            #pragma unroll
            for (int r = 0; r < 4; ++r)
                pm[r] = fmaxf(pm[r], __shfl_xor(pm[r], mk));
        float fs[4];
        #pragma unroll
        for (int r = 0; r < 4; ++r) {
            float mn = fmaxf(mM[r], pm[r]);
            fs[r] = exp2f(mM[r] - mn);
            mM[r] = mn;
        }
        float ps[4];
        #pragma unroll
        for (int r = 0; r < 4; ++r) ps[r] = 0.f;
        #pragma unroll
        for (int st = 0; st < 4; ++st)
            #pragma unroll
            for (int r = 0; r < 4; ++r) {
                S[st][r] = exp2f(S[st][r] - mM[r]);   // reuse S regs for p
                ps[r] += S[st][r];
            }
        #pragma unroll
        for (int mk = 1; mk <= 8; mk <<= 1)
            #pragma unroll
            for (int r = 0; r < 4; ++r)
                ps[r] += __shfl_xor(ps[r], mk);
        #pragma unroll
        for (int r = 0; r < 4; ++r) lS[r] = lS[r]*fs[r] + ps[r];
        #pragma unroll
        for (int cs = 0; cs < 4; ++cs)
            #pragma unroll
            for (int r = 0; r < 4; ++r) O[cs][r] *= fs[r];

        // ---- P -> f16 pairs -> swizzled LDS (wave-private rows; no barrier) ----
        #pragma unroll
        for (int st = 0; st < 4; ++st)
            #pragma unroll
            for (int r = 0; r < 4; ++r) {
                union { _Float16 h; unsigned short u; } cv;
                cv.h = (_Float16)S[st][r];
                unsigned int bits = cv.u;
                unsigned int nb = (unsigned int)__shfl_xor((int)bits, 1);
                if ((lane & 1) == 0) {
                    int qrow = w*16 + 4*lk + r;
                    int m = st*16 + lr;          // even
                    *(unsigned int*)(sP + ((qrow*128 + m*2) ^ ((qrow&7)<<4))) =
                        bits | (nb << 16);
                }
            }

        // ---- PV: O[q 16][c 64] += P[16x64] * V^T; vB 16B-contiguous from L2 ----
        __builtin_amdgcn_s_setprio(1);
        #pragma unroll
        for (int ch = 0; ch < 2; ++ch) {
            int qrow = w*16 + lr;
            half8 pA = *(const half8*)(sP + ((qrow*128 + ch*64 + lk*16) ^ ((qrow&7)<<4)));
            #pragma unroll
            for (int cs = 0; cs < 4; ++cs) {
                half8 vB = *(const half8*)&Vh[(size_t)(cs*16 + lr)*TOK + kb*64 + ch*32 + lk*8];
                O[cs] = __builtin_amdgcn_mfma_f32_16x16x32_f16(pA, vB, O[cs], 0, 0, 0);
            }
        }
        __builtin_amdgcn_s_setprio(0);
    }

    // ---- write m, l (uniform across each 16-lane group) ----
    if (lr == 0) {
        #pragma unroll
        for (int r = 0; r < 4; ++r) {
            int qrow = w*16 + 4*lk + r;
            ml[q0 + qrow]       = mM[r];
            ml[TOK + q0 + qrow] = lS[r];
        }
    }

    // ---- epilogue: transpose via LDS, coalesced unnormalized partial writes ----
    __syncthreads();
    #pragma unroll
    for (int cs = 0; cs < 4; ++cs)
        #pragma unroll
        for (int r = 0; r < 4; ++r)
            ldsf[(cs*16 + lr)*68 + w*16 + 4*lk + r] = O[cs][r];
    __syncthreads();
    int c = tid >> 2, sg = tid & 3;
    const float* srcr = &ldsf[c*68 + sg*16];
    float* dstr = &part[(size_t)c*TOK + q0 + sg*16];
    #pragma unroll
    for (int j = 0; j < 4; ++j)
        *(float4*)&dstr[j*4] = *(const float4*)&srcr[j*4];
}

// ---------------- recombine KV-split partials (exp2 domain) ----------------
__global__ __launch_bounds__(256) void recombine_kernel(
    const float* __restrict__ ws, float* __restrict__ out)
{
    int gid = blockIdx.x * 256 + threadIdx.x;   // 2 * 4cg * TOK = 73728
    int b   = gid / (4*TOK);
    int rem = gid % (4*TOK);
    int cg  = rem / TOK;
    int t   = rem % TOK;
    const float* mlp = ws + OFF_ML2;

    float m[KSPLIT], l[KSPLIT];
    float M = -INFINITY;
    #pragma unroll
    for (int ks = 0; ks < KSPLIT; ++ks) {
        int slab = b*KSPLIT + ks;
        m[ks] = mlp[(size_t)slab*2*TOK + t];
        l[ks] = mlp[(size_t)slab*2*TOK + TOK + t];
        M = fmaxf(M, m[ks]);
    }
    float wgt[KSPLIT];
    float denom = 0.f;
    #pragma unroll
    for (int ks = 0; ks < KSPLIT; ++ks) {
        wgt[ks] = exp2f(m[ks] - M);
        denom += l[ks] * wgt[ks];
    }
    float inv = 1.f / denom;
    #pragma unroll
    for (int cc = 0; cc < 16; ++cc) {
        int c = cg*16 + cc;
        float acc = 0.f;
        #pragma unroll
        for (int ks = 0; ks < KSPLIT; ++ks) {
            const float* part = part_base_c(ws, b*KSPLIT + ks);
            acc += part[(size_t)c*TOK + t] * wgt[ks];
        }
        out[(size_t)(b*64 + c)*TOK + t] = acc * inv;
    }
}

extern "C" void kernel_launch(void* const* d_in, const int* in_sizes, int n_in,
                              void* d_out, int out_size, void* d_ws, size_t ws_size,
                              hipStream_t stream)
{
    const float* frames = (const float*)d_in[0];
    const float* w1 = (const float*)d_in[1];
    const float* b1 = (const float*)d_in[2];
    const float* w2 = (const float*)d_in[3];
    const float* b2 = (const float*)d_in[4];
    const float* qw = (const float*)d_in[5];
    const float* qb = (const float*)d_in[6];
    const float* kw = (const float*)d_in[7];
    const float* kb = (const float*)d_in[8];
    const float* vw = (const float*)d_in[9];
    const float* vb = (const float*)d_in[10];
    float* ws = (float*)d_ws;
    float* out = (float*)d_out;

    hipLaunchKernelGGL(prep_kernel, dim3(144), dim3(256), 0, stream,
                       w1, b1, w2, b2, qw, qb, kw, kb, vw, vb, ws);
    hipLaunchKernelGGL(conv1_kernel, dim3(144), dim3(256), 0, stream, frames, ws);
    hipLaunchKernelGGL(conv2_kernel, dim3(768), dim3(256), 0, stream, ws);
    hipLaunchKernelGGL(qkv_kernel, dim3(3456), dim3(256), 0, stream, ws);
    hipLaunchKernelGGL(cvt_kernel, dim3(1728), dim3(256), 0, stream, ws);
    hipLaunchKernelGGL(attn_kernel, dim3(2*144*KSPLIT), dim3(256), 0, stream, ws);
    hipLaunchKernelGGL(recombine_kernel, dim3(288), dim3(256), 0, stream, ws, out);
}

// Round 9
// 387.316 us; speedup vs baseline: 1.3383x; 1.3383x over previous
//
#include <hip/hip_runtime.h>
#include <hip/hip_bf16.h>

#define TOK 9216   // 96*96 tokens per image
#define KSPLIT 5

typedef _Float16 half8 __attribute__((ext_vector_type(8)));
typedef float f32x4 __attribute__((ext_vector_type(4)));

// ---------------- workspace layout (in floats) ----------------
#define OFF_F1   0u
#define SZ_F1    (4u*64u*TOK)            // conv1 out  [img][64][9216]
#define OFF_FEAT (OFF_F1 + SZ_F1)
#define SZ_FEAT  (2u*128u*TOK)           // conv2 out, permuted: [b][c*2+n][9216]
#define OFF_Q    (OFF_FEAT + SZ_FEAT)
#define SZ_QKV   (2u*64u*TOK)
#define OFF_K    (OFF_Q + SZ_QKV)
#define OFF_V    (OFF_K + SZ_QKV)
#define OFF_W1   (OFF_V + SZ_QKV)        // [64][9] f32
#define OFF_B1   (OFF_W1 + 576u)
#define OFF_W2T  (OFF_B1 + 64u)          // [ci][9][co] f32 (transposed)
#define OFF_B2   (OFF_W2T + 36864u)
#define OFF_WCAT (OFF_B2 + 64u)          // [192][128] f32 (q;k;v)
#define OFF_BCAT (OFF_WCAT + 24576u)     // [192]

// f16 QKV overlaid on F1 (dead after conv2). Offsets in f32 units.
#define OFF_QT   OFF_F1                  // [b][t][64] f16, scale*log2e folded
#define OFF_KT   (OFF_F1 + 589824u)      // [b][t][64] f16
#define OFF_VH   (OFF_F1 + 1179648u)     // [b][64][t] f16, ends at 1769472

// KV-split partials: 10 slabs of 64*TOK f32 each (589824 floats).
// slab 0 -> free tail of F1 region (after VH); slabs 1..9 -> FEAT..V region.
// All dead once attn runs; rewritten by conv2/qkv/cvt every replay.
#define OFF_SLAB0 1769472u
#define OFF_ML2   (OFF_FEAT + 9u*589824u)   // [slab][2 (m,l)][TOK] f32

__device__ __forceinline__ const float* part_base_c(const float* ws, int slab) {
    return ws + (slab == 0 ? OFF_SLAB0 : (OFF_FEAT + (unsigned)(slab - 1) * 589824u));
}
__device__ __forceinline__ float* part_base(float* ws, int slab) {
    return ws + (slab == 0 ? OFF_SLAB0 : (OFF_FEAT + (unsigned)(slab - 1) * 589824u));
}

// ---------------- weight prep: copy/transpose f32 weights ----------------
__global__ __launch_bounds__(256) void prep_kernel(
    const float* __restrict__ w1, const float* __restrict__ b1,
    const float* __restrict__ w2, const float* __restrict__ b2,
    const float* __restrict__ qw, const float* __restrict__ qb,
    const float* __restrict__ kw, const float* __restrict__ kb,
    const float* __restrict__ vw, const float* __restrict__ vb,
    float* __restrict__ ws)
{
    int gid = blockIdx.x * 256 + threadIdx.x;
    if (gid < 576) ws[OFF_W1 + gid] = w1[gid];
    if (gid < 64) {
        ws[OFF_B1 + gid] = b1[gid];
        ws[OFF_B2 + gid] = b2[gid];
    }
    if (gid < 36864) {   // w2[co][ci][tap] -> w2t[ci][tap][co]
        int co = gid / 576; int rem = gid % 576;
        int ci = rem / 9;  int tp = rem % 9;
        ws[OFF_W2T + (ci*9 + tp)*64 + co] = w2[gid];
    }
    if (gid < 24576) {
        int o = gid >> 7; int c = gid & 127;
        float v;
        if (o < 64)       v = qw[o*128 + c];
        else if (o < 128) v = kw[(o-64)*128 + c];
        else              v = vw[(o-128)*128 + c];
        ws[OFF_WCAT + gid] = v;
    }
    if (gid < 192) {
        float v;
        if (gid < 64)       v = qb[gid];
        else if (gid < 128) v = kb[gid-64];
        else                v = vb[gid-128];
        ws[OFF_BCAT + gid] = v;
    }
}

// ---------------- conv1: 1->64 ch, 3x3, relu ----------------
__global__ __launch_bounds__(256) void conv1_kernel(
    const float* __restrict__ x, float* __restrict__ ws)
{
    const float* w1f = ws + OFF_W1;
    const float* b1f = ws + OFF_B1;
    float* f1 = ws + OFF_F1;
    int gid = blockIdx.x * 256 + threadIdx.x;
    int img = gid / TOK;
    int p   = gid % TOK;
    int h = p / 96, w = p % 96;
    float xv[9];
    #pragma unroll
    for (int dh = 0; dh < 3; ++dh)
        #pragma unroll
        for (int dw = 0; dw < 3; ++dw) {
            int r = h + dh - 1, c = w + dw - 1;
            bool ok = (r >= 0) && (r < 96) && (c >= 0) && (c < 96);
            xv[dh*3 + dw] = ok ? x[img*TOK + r*96 + c] : 0.f;
        }
    for (int co = 0; co < 64; ++co) {
        float a = b1f[co];
        #pragma unroll
        for (int t = 0; t < 9; ++t) a += w1f[co*9 + t] * xv[t];
        f1[(size_t)(img*64 + co)*TOK + p] = fmaxf(a, 0.f);
    }
}

// ---------------- conv2: 64->64 ch, 3x3, relu; writes permuted feat ----------------
__global__ __launch_bounds__(256) void conv2_kernel(float* __restrict__ ws)
{
    __align__(16) __shared__ float sT[64 * 156];
    const float* f1  = ws + OFF_F1;
    const float* w2t = ws + OFF_W2T;
    const float* b2f = ws + OFF_B2;
    float* feat = ws + OFF_FEAT;

    int bid = blockIdx.x;            // 4 img * 96 rows * 2 strips = 768
    int img = bid / 192;
    int rem = bid % 192;
    int h  = rem >> 1;
    int s2 = rem & 1;
    int tid = threadIdx.x;

    for (int idx = tid; idx < 9600; idx += 256) {
        int ci = idx / 150;
        int r2 = idx % 150;
        int r = r2 / 50, cc = r2 % 50;
        int row = h - 1 + r, col = s2*48 - 1 + cc;
        float v = 0.f;
        if (row >= 0 && row < 96 && col >= 0 && col < 96)
            v = f1[(size_t)(img*64 + ci)*TOK + row*96 + col];
        sT[ci*156 + r*52 + cc] = v;
    }
    __syncthreads();

    int co = tid & 63, g = tid >> 6;
    int px0 = g * 12;
    float acc[12];
    float bb = b2f[co];
    #pragma unroll
    for (int j = 0; j < 12; ++j) acc[j] = bb;

    for (int ci = 0; ci < 64; ++ci) {
        float wv[9];
        #pragma unroll
        for (int t = 0; t < 9; ++t) wv[t] = w2t[(ci*9 + t)*64 + co];
        #pragma unroll
        for (int r = 0; r < 3; ++r) {
            const float4* tp4 = (const float4*)&sT[ci*156 + r*52 + px0];
            float4 a0 = tp4[0], a1 = tp4[1], a2 = tp4[2], a3 = tp4[3];
            float t16[16] = {a0.x,a0.y,a0.z,a0.w, a1.x,a1.y,a1.z,a1.w,
                             a2.x,a2.y,a2.z,a2.w, a3.x,a3.y,a3.z,a3.w};
            #pragma unroll
            for (int dw = 0; dw < 3; ++dw) {
                float wgt = wv[r*3 + dw];
                #pragma unroll
                for (int j = 0; j < 12; ++j) acc[j] += wgt * t16[j + dw];
            }
        }
    }
    int b = img >> 1, n = img & 1;
    int colbase = s2*48 + px0;
    #pragma unroll
    for (int j = 0; j < 12; ++j)
        feat[(size_t)(b*128 + co*2 + n)*TOK + h*96 + colbase + j] = fmaxf(acc[j], 0.f);
}

// ---------------- fused 1x1 QKV: [192 out][128 in] GEMV per token ----------------
__global__ __launch_bounds__(256) void qkv_kernel(float* __restrict__ ws)
{
    const float* feat = ws + OFF_FEAT;
    const float* wcat = ws + OFF_WCAT;
    const float* bcat = ws + OFF_BCAT;
    int bid = blockIdx.x;            // 2 * 36 * 48 = 3456
    int b   = bid / (36*48);
    int rem = bid % (36*48);
    int tg  = rem / 48;
    int og  = rem % 48;
    int tid = threadIdx.x;
    int o    = og*4 + (tid >> 6);
    int lane = tid & 63;
    int t0   = tg*256 + lane*4;
    const float* fb   = feat + (size_t)b*128*TOK;
    const float* wrow = wcat + o*128;
    float a0, a1, a2, a3;
    a0 = a1 = a2 = a3 = bcat[o];
    for (int c = 0; c < 128; ++c) {
        float4 fv = *(const float4*)&fb[(size_t)c*TOK + t0];
        float w = wrow[c];
        a0 += w*fv.x; a1 += w*fv.y; a2 += w*fv.z; a3 += w*fv.w;
    }
    float* dst;
    if (o < 64)       dst = ws + OFF_Q + ((size_t)b*64 + o      )*TOK;
    else if (o < 128) dst = ws + OFF_K + ((size_t)b*64 + (o-64 ))*TOK;
    else              dst = ws + OFF_V + ((size_t)b*64 + (o-128))*TOK;
    float4 out4 = {a0, a1, a2, a3};
    *(float4*)&dst[t0] = out4;
}

// ---------------- cvt: f32 [d][t] -> f16 tiles for MFMA ----------------
// Q scale folds 0.125 * log2(e) -> softmax runs in exp2 domain.
__global__ __launch_bounds__(256) void cvt_kernel(float* __restrict__ ws)
{
    __shared__ __align__(16) float lds[64*68];
    int bid = blockIdx.x;
    int tid = threadIdx.x;
    if (bid < 576) {
        int tensor = bid / 288;          // 0=Q, 1=K
        int rem = bid % 288;
        int b = rem / 144, tile = rem % 144;
        int t0 = tile * 64;
        const float* src = ws + (tensor ? OFF_K : OFF_Q) + (size_t)b*64*TOK;
        _Float16* dst = (_Float16*)(ws + (tensor ? OFF_KT : OFF_QT)) + (size_t)b*TOK*64;
        float scale = tensor ? 1.0f : 0.18033688011112042f;   // 0.125*log2(e)
        int d = tid >> 2, seg = tid & 3;
        #pragma unroll
        for (int j = 0; j < 4; ++j) {
            float4 v = *(const float4*)&src[(size_t)d*TOK + t0 + seg*16 + j*4];
            *(float4*)&lds[d*68 + seg*16 + j*4] = v;
        }
        __syncthreads();
        int t = tid >> 2, dseg = tid & 3;
        __align__(16) _Float16 h[16];
        #pragma unroll
        for (int e = 0; e < 16; ++e)
            h[e] = (_Float16)(lds[(dseg*16 + e)*68 + t] * scale);
        *(uint4*)&dst[(size_t)(t0 + t)*64 + dseg*16]     = *(uint4*)&h[0];
        *(uint4*)&dst[(size_t)(t0 + t)*64 + dseg*16 + 8] = *(uint4*)&h[8];
    } else {
        size_t idx = (size_t)(bid - 576) * 1024 + tid * 4;   // over 2*64*TOK
        const float* src = ws + OFF_V;
        _Float16* dst = (_Float16*)(ws + OFF_VH);
        float4 v = *(const float4*)&src[idx];
        union { _Float16 h[4]; uint2 u; } pk;
        pk.h[0] = (_Float16)v.x; pk.h[1] = (_Float16)v.y;
        pk.h[2] = (_Float16)v.z; pk.h[3] = (_Float16)v.w;
        *(uint2*)&dst[idx] = pk.u;
    }
}

// ---------------- flash attention partial: double-buffered LDS, 1 barrier/iter ----------------
// grid = 2b x 144qt x KSPLIT; 256 thr = 4 waves x 16 q-rows; KVBLK=64.
// Pipeline: LDS holds tiles {it, it+1}; regs hold tile it+2 in flight.
__global__ __launch_bounds__(256, 4) void attn_kernel(float* __restrict__ ws)
{
    __shared__ __align__(16) char smem[40960];   // K0 V0 | K1 V1 | P
    char* sP = smem + 32768;    // [64 q][64 m] f16, byte^((q&7)<<4) (wave-private rows)
    float* ldsf = (float*)smem; // epilogue reuse: [64 c][68] f32

    int bid = blockIdx.x;       // 2 * 144 * KSPLIT
    int b   = bid / (144*KSPLIT);
    int rem = bid % (144*KSPLIT);
    int qt  = rem / KSPLIT;
    int ks  = rem % KSPLIT;
    int tid = threadIdx.x;
    int lane = tid & 63, w = tid >> 6;
    int q0 = qt * 64;
    int lr = lane & 15;         // fragment row/col index
    int lk = lane >> 4;         // k-group (0..3)

    int kb0 = (ks*144)/KSPLIT, kb1 = ((ks+1)*144)/KSPLIT;
    int nit = kb1 - kb0;
    int slab = b*KSPLIT + ks;

    const _Float16* Qt = (const _Float16*)(ws + OFF_QT) + (size_t)b*TOK*64;
    const _Float16* Kt = (const _Float16*)(ws + OFF_KT) + (size_t)b*TOK*64;
    const _Float16* Vh = (const _Float16*)(ws + OFF_VH) + (size_t)b*64*TOK;
    float* part = part_base(ws, slab);
    float* ml   = ws + OFF_ML2 + (size_t)slab*2*TOK;

    // Q fragments in registers (A: row q = lr, k d = ch*32 + lk*8 + e)
    half8 qA[2];
    #pragma unroll
    for (int ch = 0; ch < 2; ++ch)
        qA[ch] = *(const half8*)&Qt[(size_t)(q0 + w*16 + lr)*64 + ch*32 + lk*8];

    f32x4 O[4];                 // [csub]: col c = csub*16+lr, row q = 4*lk+reg
    #pragma unroll
    for (int cs = 0; cs < 4; ++cs) O[cs] = (f32x4){0.f, 0.f, 0.f, 0.f};
    float mM[4], lS[4];
    #pragma unroll
    for (int r = 0; r < 4; ++r) { mM[r] = -INFINITY; lS[r] = 0.f; }

    int srow = tid >> 3, seg = tid & 7;    // staging coords (rows srow, srow+32)

    // ---- prologue: stage tile kb0 into buf0; load tile kb0+1 into regs ----
    uint4 kvR[2], vvR[2];
    #pragma unroll
    for (int i = 0; i < 2; ++i) {
        int r2 = srow + 32*i;
        kvR[i] = *(const uint4*)&Kt[(size_t)(kb0*64 + r2)*64 + seg*8];
        vvR[i] = *(const uint4*)&Vh[(size_t)r2*TOK + kb0*64 + seg*8];
    }
    #pragma unroll
    for (int i = 0; i < 2; ++i) {
        int r2 = srow + 32*i;
        *(uint4*)(smem        + ((r2*128 + seg*16) ^ ((r2&7)<<4))) = kvR[i];
        *(uint4*)(smem + 8192 + ((r2*128 + seg*16) ^ ((r2&7)<<4))) = vvR[i];
    }
    if (nit > 1) {
        #pragma unroll
        for (int i = 0; i < 2; ++i) {
            int r2 = srow + 32*i;
            kvR[i] = *(const uint4*)&Kt[(size_t)((kb0+1)*64 + r2)*64 + seg*8];
            vvR[i] = *(const uint4*)&Vh[(size_t)r2*TOK + (kb0+1)*64 + seg*8];
        }
    }
    __syncthreads();            // buf0 visible

    for (int it = 0; it < nit; ++it) {
        char* sKb = smem + (it & 1) * 16384;
        char* sVb = sKb + 8192;
        char* sSt = smem + ((it + 1) & 1) * 16384;

        // ---- stage tile it+1 (regs -> LDS buf^1); overlaps compute below ----
        if (it + 1 < nit) {
            #pragma unroll
            for (int i = 0; i < 2; ++i) {
                int r2 = srow + 32*i;
                *(uint4*)(sSt        + ((r2*128 + seg*16) ^ ((r2&7)<<4))) = kvR[i];
                *(uint4*)(sSt + 8192 + ((r2*128 + seg*16) ^ ((r2&7)<<4))) = vvR[i];
            }
        }
        // ---- issue loads for tile it+2 ----
        if (it + 2 < nit) {
            int kb2 = kb0 + it + 2;
            #pragma unroll
            for (int i = 0; i < 2; ++i) {
                int r2 = srow + 32*i;
                kvR[i] = *(const uint4*)&Kt[(size_t)(kb2*64 + r2)*64 + seg*8];
                vvR[i] = *(const uint4*)&Vh[(size_t)r2*TOK + kb2*64 + seg*8];
            }
        }

        // ---- QK^T: S[q 16][kt 64] per wave ----
        f32x4 S[4];
        #pragma unroll
        for (int st = 0; st < 4; ++st) S[st] = (f32x4){0.f, 0.f, 0.f, 0.f};
        __builtin_amdgcn_s_setprio(1);
        #pragma unroll
        for (int st = 0; st < 4; ++st) {
            int t = st*16 + lr;
            #pragma unroll
            for (int ch = 0; ch < 2; ++ch) {
                half8 kB = *(const half8*)(sKb + ((t*128 + ch*64 + lk*16) ^ ((t&7)<<4)));
                S[st] = __builtin_amdgcn_mfma_f32_16x16x32_f16(qA[ch], kB, S[st], 0, 0, 0);
            }
        }
        __builtin_amdgcn_s_setprio(0);

        // ---- online softmax, exp2 domain (rows live on 16-lane groups) ----
        float pm[4];
        #pragma unroll
        for (int r = 0; r < 4; ++r)
            pm[r] = fmaxf(fmaxf(S[0][r], S[1][r]), fmaxf(S[2][r], S[3][r]));
        #pragma unroll
        for (int mk = 1; mk <= 8; mk <<= 1)
            #pragma unroll
            for (int r = 0; r < 4; ++r)
                pm[r] = fmaxf(pm[r], __shfl_xor(pm[r], mk));
        float fs[4];
        #pragma unroll
        for (int r = 0; r < 4; ++r) {
            float mn = fmaxf(mM[r], pm[r]);
            fs[r] = exp2f(mM[r] - mn);
            mM[r] = mn;
        }
        float ps[4];
        #pragma unroll
        for (int r = 0; r < 4; ++r) ps[r] = 0.f;
        #pragma unroll
        for (int st = 0; st < 4; ++st)
            #pragma unroll
            for (int r = 0; r < 4; ++r) {
                S[st][r] = exp2f(S[st][r] - mM[r]);   // reuse S regs for p
                ps[r] += S[st][r];
            }
        #pragma unroll
        for (int mk = 1; mk <= 8; mk <<= 1)
            #pragma unroll
            for (int r = 0; r < 4; ++r)
                ps[r] += __shfl_xor(ps[r], mk);
        #pragma unroll
        for (int r = 0; r < 4; ++r) lS[r] = lS[r]*fs[r] + ps[r];
        #pragma unroll
        for (int cs = 0; cs < 4; ++cs)
            #pragma unroll
            for (int r = 0; r < 4; ++r) O[cs][r] *= fs[r];

        // ---- P -> f16 pairs -> swizzled LDS (wave-private rows; no barrier) ----
        #pragma unroll
        for (int st = 0; st < 4; ++st)
            #pragma unroll
            for (int r = 0; r < 4; ++r) {
                union { _Float16 h; unsigned short u; } cv;
                cv.h = (_Float16)S[st][r];
                unsigned int bits = cv.u;
                unsigned int nb = (unsigned int)__shfl_xor((int)bits, 1);
                if ((lane & 1) == 0) {
                    int qrow = w*16 + 4*lk + r;
                    int m = st*16 + lr;          // even
                    *(unsigned int*)(sP + ((qrow*128 + m*2) ^ ((qrow&7)<<4))) =
                        bits | (nb << 16);
                }
            }

        // ---- PV: O[q 16][c 64] += P[16x64] * V^T ----
        __builtin_amdgcn_s_setprio(1);
        #pragma unroll
        for (int ch = 0; ch < 2; ++ch) {
            int qrow = w*16 + lr;
            half8 pA = *(const half8*)(sP + ((qrow*128 + ch*64 + lk*16) ^ ((qrow&7)<<4)));
            #pragma unroll
            for (int cs = 0; cs < 4; ++cs) {
                int crow = cs*16 + lr;
                half8 vB = *(const half8*)(sVb + ((crow*128 + ch*64 + lk*16) ^ ((crow&7)<<4)));
                O[cs] = __builtin_amdgcn_mfma_f32_16x16x32_f16(pA, vB, O[cs], 0, 0, 0);
            }
        }
        __builtin_amdgcn_s_setprio(0);

        __syncthreads();        // single barrier: buf^1 staged, buf reads done
    }

    // ---- write m, l (uniform across each 16-lane group) ----
    if (lr == 0) {
        #pragma unroll
        for (int r = 0; r < 4; ++r) {
            int qrow = w*16 + 4*lk + r;
            ml[q0 + qrow]       = mM[r];
            ml[TOK + q0 + qrow] = lS[r];
        }
    }

    // ---- epilogue: transpose via LDS, coalesced unnormalized partial writes ----
    #pragma unroll
    for (int cs = 0; cs < 4; ++cs)
        #pragma unroll
        for (int r = 0; r < 4; ++r)
            ldsf[(cs*16 + lr)*68 + w*16 + 4*lk + r] = O[cs][r];
    __syncthreads();
    int c = tid >> 2, sg = tid & 3;
    const float* srcr = &ldsf[c*68 + sg*16];
    float* dstr = &part[(size_t)c*TOK + q0 + sg*16];
    #pragma unroll
    for (int j = 0; j < 4; ++j)
        *(float4*)&dstr[j*4] = *(const float4*)&srcr[j*4];
}

// ---------------- recombine KV-split partials (exp2 domain) ----------------
__global__ __launch_bounds__(256) void recombine_kernel(
    const float* __restrict__ ws, float* __restrict__ out)
{
    int gid = blockIdx.x * 256 + threadIdx.x;   // 2 * 4cg * TOK = 73728
    int b   = gid / (4*TOK);
    int rem = gid % (4*TOK);
    int cg  = rem / TOK;
    int t   = rem % TOK;
    const float* mlp = ws + OFF_ML2;

    float m[KSPLIT], l[KSPLIT];
    float M = -INFINITY;
    #pragma unroll
    for (int ks = 0; ks < KSPLIT; ++ks) {
        int slab = b*KSPLIT + ks;
        m[ks] = mlp[(size_t)slab*2*TOK + t];
        l[ks] = mlp[(size_t)slab*2*TOK + TOK + t];
        M = fmaxf(M, m[ks]);
    }
    float wgt[KSPLIT];
    float denom = 0.f;
    #pragma unroll
    for (int ks = 0; ks < KSPLIT; ++ks) {
        wgt[ks] = exp2f(m[ks] - M);
        denom += l[ks] * wgt[ks];
    }
    float inv = 1.f / denom;
    #pragma unroll
    for (int cc = 0; cc < 16; ++cc) {
        int c = cg*16 + cc;
        float acc = 0.f;
        #pragma unroll
        for (int ks = 0; ks < KSPLIT; ++ks) {
            const float* part = part_base_c(ws, b*KSPLIT + ks);
            acc += part[(size_t)c*TOK + t] * wgt[ks];
        }
        out[(size_t)(b*64 + c)*TOK + t] = acc * inv;
    }
}

extern "C" void kernel_launch(void* const* d_in, const int* in_sizes, int n_in,
                              void* d_out, int out_size, void* d_ws, size_t ws_size,
                              hipStream_t stream)
{
    const float* frames = (const float*)d_in[0];
    const float* w1 = (const float*)d_in[1];
    const float* b1 = (const float*)d_in[2];
    const float* w2 = (const float*)d_in[3];
    const float* b2 = (const float*)d_in[4];
    const float* qw = (const float*)d_in[5];
    const float* qb = (const float*)d_in[6];
    const float* kw = (const float*)d_in[7];
    const float* kb = (const float*)d_in[8];
    const float* vw = (const float*)d_in[9];
    const float* vb = (const float*)d_in[10];
    float* ws = (float*)d_ws;
    float* out = (float*)d_out;

    hipLaunchKernelGGL(prep_kernel, dim3(144), dim3(256), 0, stream,
                       w1, b1, w2, b2, qw, qb, kw, kb, vw, vb, ws);
    hipLaunchKernelGGL(conv1_kernel, dim3(144), dim3(256), 0, stream, frames, ws);
    hipLaunchKernelGGL(conv2_kernel, dim3(768), dim3(256), 0, stream, ws);
    hipLaunchKernelGGL(qkv_kernel, dim3(3456), dim3(256), 0, stream, ws);
    hipLaunchKernelGGL(cvt_kernel, dim3(1728), dim3(256), 0, stream, ws);
    hipLaunchKernelGGL(attn_kernel, dim3(2*144*KSPLIT), dim3(256), 0, stream, ws);
    hipLaunchKernelGGL(recombine_kernel, dim3(288), dim3(256), 0, stream, ws, out);
}

// Round 10
// 355.726 us; speedup vs baseline: 1.4571x; 1.0888x over previous
//
#include <hip/hip_runtime.h>
#include <hip/hip_bf16.h>

#define TOK 9216   // 96*96 tokens per image
#define KSPLIT 5

typedef _Float16 half8 __attribute__((ext_vector_type(8)));
typedef float f32x4 __attribute__((ext_vector_type(4)));

// ---------------- workspace layout (in floats) ----------------
#define OFF_F1   0u
#define SZ_F1    (4u*64u*TOK)            // conv1 out  [img][64][9216]
#define OFF_FEAT (OFF_F1 + SZ_F1)
#define SZ_FEAT  (2u*128u*TOK)           // conv2 out, permuted: [b][c*2+n][9216]
#define OFF_Q    (OFF_FEAT + SZ_FEAT)
#define SZ_QKV   (2u*64u*TOK)
#define OFF_K    (OFF_Q + SZ_QKV)
#define OFF_V    (OFF_K + SZ_QKV)
#define OFF_W1   (OFF_V + SZ_QKV)        // [64][9] f32
#define OFF_B1   (OFF_W1 + 576u)
#define OFF_W2T  (OFF_B1 + 64u)          // [ci][9][co] f32 (transposed)
#define OFF_B2   (OFF_W2T + 36864u)
#define OFF_WCAT (OFF_B2 + 64u)          // [192][128] f32 (q;k;v)
#define OFF_BCAT (OFF_WCAT + 24576u)     // [192]

// f16 QKV overlaid on F1 (dead after conv2). Offsets in f32 units.
#define OFF_QT   OFF_F1                  // [b][t][64] f16, scale*log2e folded
#define OFF_KT   (OFF_F1 + 589824u)      // [b][t][64] f16
#define OFF_VH   (OFF_F1 + 1179648u)     // [b][64][t] f16, ends at 1769472

// KV-split partials: 10 slabs of 64*TOK f32 each (589824 floats).
// slab 0 -> free tail of F1 region (after VH); slabs 1..9 -> FEAT..V region.
// All dead once attn runs; rewritten by conv2/qkv/cvt every replay.
#define OFF_SLAB0 1769472u
#define OFF_ML2   (OFF_FEAT + 9u*589824u)   // [slab][2 (m,l)][TOK] f32

__device__ __forceinline__ const float* part_base_c(const float* ws, int slab) {
    return ws + (slab == 0 ? OFF_SLAB0 : (OFF_FEAT + (unsigned)(slab - 1) * 589824u));
}
__device__ __forceinline__ float* part_base(float* ws, int slab) {
    return ws + (slab == 0 ? OFF_SLAB0 : (OFF_FEAT + (unsigned)(slab - 1) * 589824u));
}

// ---------------- weight prep: copy/transpose f32 weights ----------------
__global__ __launch_bounds__(256) void prep_kernel(
    const float* __restrict__ w1, const float* __restrict__ b1,
    const float* __restrict__ w2, const float* __restrict__ b2,
    const float* __restrict__ qw, const float* __restrict__ qb,
    const float* __restrict__ kw, const float* __restrict__ kb,
    const float* __restrict__ vw, const float* __restrict__ vb,
    float* __restrict__ ws)
{
    int gid = blockIdx.x * 256 + threadIdx.x;
    if (gid < 576) ws[OFF_W1 + gid] = w1[gid];
    if (gid < 64) {
        ws[OFF_B1 + gid] = b1[gid];
        ws[OFF_B2 + gid] = b2[gid];
    }
    if (gid < 36864) {   // w2[co][ci][tap] -> w2t[ci][tap][co]
        int co = gid / 576; int rem = gid % 576;
        int ci = rem / 9;  int tp = rem % 9;
        ws[OFF_W2T + (ci*9 + tp)*64 + co] = w2[gid];
    }
    if (gid < 24576) {
        int o = gid >> 7; int c = gid & 127;
        float v;
        if (o < 64)       v = qw[o*128 + c];
        else if (o < 128) v = kw[(o-64)*128 + c];
        else              v = vw[(o-128)*128 + c];
        ws[OFF_WCAT + gid] = v;
    }
    if (gid < 192) {
        float v;
        if (gid < 64)       v = qb[gid];
        else if (gid < 128) v = kb[gid-64];
        else                v = vb[gid-128];
        ws[OFF_BCAT + gid] = v;
    }
}

// ---------------- conv1: 1->64 ch, 3x3, relu ----------------
__global__ __launch_bounds__(256) void conv1_kernel(
    const float* __restrict__ x, float* __restrict__ ws)
{
    const float* w1f = ws + OFF_W1;
    const float* b1f = ws + OFF_B1;
    float* f1 = ws + OFF_F1;
    int gid = blockIdx.x * 256 + threadIdx.x;
    int img = gid / TOK;
    int p   = gid % TOK;
    int h = p / 96, w = p % 96;
    float xv[9];
    #pragma unroll
    for (int dh = 0; dh < 3; ++dh)
        #pragma unroll
        for (int dw = 0; dw < 3; ++dw) {
            int r = h + dh - 1, c = w + dw - 1;
            bool ok = (r >= 0) && (r < 96) && (c >= 0) && (c < 96);
            xv[dh*3 + dw] = ok ? x[img*TOK + r*96 + c] : 0.f;
        }
    for (int co = 0; co < 64; ++co) {
        float a = b1f[co];
        #pragma unroll
        for (int t = 0; t < 9; ++t) a += w1f[co*9 + t] * xv[t];
        f1[(size_t)(img*64 + co)*TOK + p] = fmaxf(a, 0.f);
    }
}

// ---------------- conv2: 64->64 ch, 3x3, relu; writes permuted feat ----------------
__global__ __launch_bounds__(256) void conv2_kernel(float* __restrict__ ws)
{
    __align__(16) __shared__ float sT[64 * 156];
    const float* f1  = ws + OFF_F1;
    const float* w2t = ws + OFF_W2T;
    const float* b2f = ws + OFF_B2;
    float* feat = ws + OFF_FEAT;

    int bid = blockIdx.x;            // 4 img * 96 rows * 2 strips = 768
    int img = bid / 192;
    int rem = bid % 192;
    int h  = rem >> 1;
    int s2 = rem & 1;
    int tid = threadIdx.x;

    for (int idx = tid; idx < 9600; idx += 256) {
        int ci = idx / 150;
        int r2 = idx % 150;
        int r = r2 / 50, cc = r2 % 50;
        int row = h - 1 + r, col = s2*48 - 1 + cc;
        float v = 0.f;
        if (row >= 0 && row < 96 && col >= 0 && col < 96)
            v = f1[(size_t)(img*64 + ci)*TOK + row*96 + col];
        sT[ci*156 + r*52 + cc] = v;
    }
    __syncthreads();

    int co = tid & 63, g = tid >> 6;
    int px0 = g * 12;
    float acc[12];
    float bb = b2f[co];
    #pragma unroll
    for (int j = 0; j < 12; ++j) acc[j] = bb;

    for (int ci = 0; ci < 64; ++ci) {
        float wv[9];
        #pragma unroll
        for (int t = 0; t < 9; ++t) wv[t] = w2t[(ci*9 + t)*64 + co];
        #pragma unroll
        for (int r = 0; r < 3; ++r) {
            const float4* tp4 = (const float4*)&sT[ci*156 + r*52 + px0];
            float4 a0 = tp4[0], a1 = tp4[1], a2 = tp4[2], a3 = tp4[3];
            float t16[16] = {a0.x,a0.y,a0.z,a0.w, a1.x,a1.y,a1.z,a1.w,
                             a2.x,a2.y,a2.z,a2.w, a3.x,a3.y,a3.z,a3.w};
            #pragma unroll
            for (int dw = 0; dw < 3; ++dw) {
                float wgt = wv[r*3 + dw];
                #pragma unroll
                for (int j = 0; j < 12; ++j) acc[j] += wgt * t16[j + dw];
            }
        }
    }
    int b = img >> 1, n = img & 1;
    int colbase = s2*48 + px0;
    #pragma unroll
    for (int j = 0; j < 12; ++j)
        feat[(size_t)(b*128 + co*2 + n)*TOK + h*96 + colbase + j] = fmaxf(acc[j], 0.f);
}

// ---------------- fused 1x1 QKV: [192 out][128 in] GEMV per token ----------------
__global__ __launch_bounds__(256) void qkv_kernel(float* __restrict__ ws)
{
    const float* feat = ws + OFF_FEAT;
    const float* wcat = ws + OFF_WCAT;
    const float* bcat = ws + OFF_BCAT;
    int bid = blockIdx.x;            // 2 * 36 * 48 = 3456
    int b   = bid / (36*48);
    int rem = bid % (36*48);
    int tg  = rem / 48;
    int og  = rem % 48;
    int tid = threadIdx.x;
    int o    = og*4 + (tid >> 6);
    int lane = tid & 63;
    int t0   = tg*256 + lane*4;
    const float* fb   = feat + (size_t)b*128*TOK;
    const float* wrow = wcat + o*128;
    float a0, a1, a2, a3;
    a0 = a1 = a2 = a3 = bcat[o];
    for (int c = 0; c < 128; ++c) {
        float4 fv = *(const float4*)&fb[(size_t)c*TOK + t0];
        float w = wrow[c];
        a0 += w*fv.x; a1 += w*fv.y; a2 += w*fv.z; a3 += w*fv.w;
    }
    float* dst;
    if (o < 64)       dst = ws + OFF_Q + ((size_t)b*64 + o      )*TOK;
    else if (o < 128) dst = ws + OFF_K + ((size_t)b*64 + (o-64 ))*TOK;
    else              dst = ws + OFF_V + ((size_t)b*64 + (o-128))*TOK;
    float4 out4 = {a0, a1, a2, a3};
    *(float4*)&dst[t0] = out4;
}

// ---------------- cvt: f32 [d][t] -> f16 tiles for MFMA ----------------
// Q scale folds 0.125 * log2(e) -> softmax runs in exp2 domain.
__global__ __launch_bounds__(256) void cvt_kernel(float* __restrict__ ws)
{
    __shared__ __align__(16) float lds[64*68];
    int bid = blockIdx.x;
    int tid = threadIdx.x;
    if (bid < 576) {
        int tensor = bid / 288;          // 0=Q, 1=K
        int rem = bid % 288;
        int b = rem / 144, tile = rem % 144;
        int t0 = tile * 64;
        const float* src = ws + (tensor ? OFF_K : OFF_Q) + (size_t)b*64*TOK;
        _Float16* dst = (_Float16*)(ws + (tensor ? OFF_KT : OFF_QT)) + (size_t)b*TOK*64;
        float scale = tensor ? 1.0f : 0.18033688011112042f;   // 0.125*log2(e)
        int d = tid >> 2, seg = tid & 3;
        #pragma unroll
        for (int j = 0; j < 4; ++j) {
            float4 v = *(const float4*)&src[(size_t)d*TOK + t0 + seg*16 + j*4];
            *(float4*)&lds[d*68 + seg*16 + j*4] = v;
        }
        __syncthreads();
        int t = tid >> 2, dseg = tid & 3;
        __align__(16) _Float16 h[16];
        #pragma unroll
        for (int e = 0; e < 16; ++e)
            h[e] = (_Float16)(lds[(dseg*16 + e)*68 + t] * scale);
        *(uint4*)&dst[(size_t)(t0 + t)*64 + dseg*16]     = *(uint4*)&h[0];
        *(uint4*)&dst[(size_t)(t0 + t)*64 + dseg*16 + 8] = *(uint4*)&h[8];
    } else {
        size_t idx = (size_t)(bid - 576) * 1024 + tid * 4;   // over 2*64*TOK
        const float* src = ws + OFF_V;
        _Float16* dst = (_Float16*)(ws + OFF_VH);
        float4 v = *(const float4*)&src[idx];
        union { _Float16 h[4]; uint2 u; } pk;
        pk.h[0] = (_Float16)v.x; pk.h[1] = (_Float16)v.y;
        pk.h[2] = (_Float16)v.z; pk.h[3] = (_Float16)v.w;
        *(uint2*)&dst[idx] = pk.u;
    }
}

// ---------------- flash attention partial: swapped-MFMA, per-lane softmax ----------------
// grid = 2b x 144qt x KSPLIT; 256 thr = 4 waves x 16 q-rows; KVBLK=64.
// Swapped operands: S^T = mfma(K,Q) -> lane owns one q-row (q=lane&15, 16 kt regs).
// P redistributed to PV B-fragments via register shuffles (no P LDS, no extra barrier).
__global__ __launch_bounds__(256, 5) void attn_kernel(float* __restrict__ ws)
{
    __shared__ __align__(16) char smem[32768];   // K0 V0 | K1 V1 (dbuf)
    float* ldsf = (float*)smem;                  // epilogue reuse: [64 c][68] f32

    int bid = blockIdx.x;       // 2 * 144 * KSPLIT
    int b   = bid / (144*KSPLIT);
    int rem = bid % (144*KSPLIT);
    int qt  = rem / KSPLIT;
    int ks  = rem % KSPLIT;
    int tid = threadIdx.x;
    int lane = tid & 63, w = tid >> 6;
    int q0 = qt * 64;
    int lr = lane & 15;         // my q (within wave's 16-row tile) / frag row
    int lk = lane >> 4;         // k-subblock group (0..3)

    int kb0 = (ks*144)/KSPLIT, kb1 = ((ks+1)*144)/KSPLIT;
    int nit = kb1 - kb0;
    int slab = b*KSPLIT + ks;

    const _Float16* Qt = (const _Float16*)(ws + OFF_QT) + (size_t)b*TOK*64;
    const _Float16* Kt = (const _Float16*)(ws + OFF_KT) + (size_t)b*TOK*64;
    const _Float16* Vh = (const _Float16*)(ws + OFF_VH) + (size_t)b*64*TOK;
    float* part = part_base(ws, slab);
    float* ml   = ws + OFF_ML2 + (size_t)slab*2*TOK;

    // Q fragments (B-operand now; same lane map/bytes as before: col=q=lr, k=ch*32+lk*8+e)
    half8 qB[2];
    #pragma unroll
    for (int ch = 0; ch < 2; ++ch)
        qB[ch] = *(const half8*)&Qt[(size_t)(q0 + w*16 + lr)*64 + ch*32 + lk*8];

    f32x4 O[4];                 // O^T[c][q]: col q = lr, row c = cs*16 + 4*lk + r
    #pragma unroll
    for (int cs = 0; cs < 4; ++cs) O[cs] = (f32x4){0.f, 0.f, 0.f, 0.f};
    float mM = -INFINITY, lS = 0.f;   // per-lane scalars (q = lr), replicated over lk

    int srow = tid >> 3, seg = tid & 7;    // staging coords (rows srow, srow+32)

    // ---- prologue: stage tile kb0 into buf0; load tile kb0+1 into regs ----
    uint4 kvR[2], vvR[2];
    #pragma unroll
    for (int i = 0; i < 2; ++i) {
        int r2 = srow + 32*i;
        kvR[i] = *(const uint4*)&Kt[(size_t)(kb0*64 + r2)*64 + seg*8];
        vvR[i] = *(const uint4*)&Vh[(size_t)r2*TOK + kb0*64 + seg*8];
    }
    #pragma unroll
    for (int i = 0; i < 2; ++i) {
        int r2 = srow + 32*i;
        *(uint4*)(smem        + ((r2*128 + seg*16) ^ ((r2&7)<<4))) = kvR[i];
        *(uint4*)(smem + 8192 + ((r2*128 + seg*16) ^ ((r2&7)<<4))) = vvR[i];
    }
    if (nit > 1) {
        #pragma unroll
        for (int i = 0; i < 2; ++i) {
            int r2 = srow + 32*i;
            kvR[i] = *(const uint4*)&Kt[(size_t)((kb0+1)*64 + r2)*64 + seg*8];
            vvR[i] = *(const uint4*)&Vh[(size_t)r2*TOK + (kb0+1)*64 + seg*8];
        }
    }
    __syncthreads();            // buf0 visible

    for (int it = 0; it < nit; ++it) {
        char* sKb = smem + (it & 1) * 16384;
        char* sVb = sKb + 8192;
        char* sSt = smem + ((it + 1) & 1) * 16384;

        // ---- stage tile it+1 (regs -> LDS buf^1); overlaps compute below ----
        if (it + 1 < nit) {
            #pragma unroll
            for (int i = 0; i < 2; ++i) {
                int r2 = srow + 32*i;
                *(uint4*)(sSt        + ((r2*128 + seg*16) ^ ((r2&7)<<4))) = kvR[i];
                *(uint4*)(sSt + 8192 + ((r2*128 + seg*16) ^ ((r2&7)<<4))) = vvR[i];
            }
        }
        // ---- issue loads for tile it+2 ----
        if (it + 2 < nit) {
            int kb2 = kb0 + it + 2;
            #pragma unroll
            for (int i = 0; i < 2; ++i) {
                int r2 = srow + 32*i;
                kvR[i] = *(const uint4*)&Kt[(size_t)(kb2*64 + r2)*64 + seg*8];
                vvR[i] = *(const uint4*)&Vh[(size_t)r2*TOK + kb2*64 + seg*8];
            }
        }

        // ---- QK^T swapped: S^T[kt 64][q 16]; lane: q=lr, kt = st*16 + 4*lk + r ----
        f32x4 S[4];
        #pragma unroll
        for (int st = 0; st < 4; ++st) S[st] = (f32x4){0.f, 0.f, 0.f, 0.f};
        __builtin_amdgcn_s_setprio(1);
        #pragma unroll
        for (int st = 0; st < 4; ++st) {
            int t = st*16 + lr;     // A-operand row = kt
            #pragma unroll
            for (int ch = 0; ch < 2; ++ch) {
                half8 kA = *(const half8*)(sKb + ((t*128 + ch*64 + lk*16) ^ ((t&7)<<4)));
                S[st] = __builtin_amdgcn_mfma_f32_16x16x32_f16(kA, qB[ch], S[st], 0, 0, 0);
            }
        }
        __builtin_amdgcn_s_setprio(0);

        // ---- per-lane online softmax (exp2 domain), defer-max exact skip ----
        float pm = fmaxf(fmaxf(fmaxf(S[0][0], S[0][1]), fmaxf(S[0][2], S[0][3])),
                  fmaxf(fmaxf(fmaxf(S[1][0], S[1][1]), fmaxf(S[1][2], S[1][3])),
                  fmaxf(fmaxf(fmaxf(S[2][0], S[2][1]), fmaxf(S[2][2], S[2][3])),
                        fmaxf(fmaxf(S[3][0], S[3][1]), fmaxf(S[3][2], S[3][3])))));
        pm = fmaxf(pm, __shfl_xor(pm, 16));
        pm = fmaxf(pm, __shfl_xor(pm, 32));
        if (__any(pm > mM)) {
            float mn = fmaxf(mM, pm);
            float fs = exp2f(mM - mn);
            mM = mn;
            lS *= fs;
            #pragma unroll
            for (int cs = 0; cs < 4; ++cs)
                #pragma unroll
                for (int r = 0; r < 4; ++r) O[cs][r] *= fs;
        }
        float ps = 0.f;
        #pragma unroll
        for (int st = 0; st < 4; ++st)
            #pragma unroll
            for (int r = 0; r < 4; ++r) {
                S[st][r] = exp2f(S[st][r] - mM);   // p, reuse regs
                ps += S[st][r];
            }
        ps += __shfl_xor(ps, 16);
        ps += __shfl_xor(ps, 32);
        lS += ps;

        // ---- pack P pairs: pk[st][j] = f16x2(p[st][2j], p[st][2j+1]) ----
        unsigned int pk[4][2];
        #pragma unroll
        for (int st = 0; st < 4; ++st) {
            union { _Float16 h[2]; unsigned int u; } c0, c1;
            c0.h[0] = (_Float16)S[st][0]; c0.h[1] = (_Float16)S[st][1];
            c1.h[0] = (_Float16)S[st][2]; c1.h[1] = (_Float16)S[st][3];
            pk[st][0] = c0.u; pk[st][1] = c1.u;
        }

        // ---- PV swapped: O^T[c][q] += V^T[c][kt] · P^T[kt][q] ----
        // pB: lane (lr,lk) word w2 <- src lane lr+32*(lk&1)+16*(w2>>1),
        //     reg pk[ch2*2 + (lk>>1)][w2&1]   (derivation in journal)
        int srcA = lr + 32*(lk & 1);
        int sel  = lk >> 1;
        __builtin_amdgcn_s_setprio(1);
        #pragma unroll
        for (int ch2 = 0; ch2 < 2; ++ch2) {
            union { unsigned int u[4]; half8 h; } pb;
            #pragma unroll
            for (int w2 = 0; w2 < 4; ++w2) {
                int src = srcA + 16*(w2 >> 1);
                int lo = __shfl((int)pk[ch2*2 + 0][w2 & 1], src);
                int hi = __shfl((int)pk[ch2*2 + 1][w2 & 1], src);
                pb.u[w2] = (unsigned int)(sel ? hi : lo);
            }
            #pragma unroll
            for (int cs = 0; cs < 4; ++cs) {
                int crow = cs*16 + lr;
                half8 vA = *(const half8*)(sVb + ((crow*128 + ch2*64 + lk*16) ^ ((crow&7)<<4)));
                O[cs] = __builtin_amdgcn_mfma_f32_16x16x32_f16(vA, pb.h, O[cs], 0, 0, 0);
            }
        }
        __builtin_amdgcn_s_setprio(0);

        __syncthreads();        // single barrier: buf^1 staged, buf reads done
    }

    // ---- write m, l (per q-row; lk==0 lanes hold q = w*16 + lr) ----
    if (lk == 0) {
        ml[q0 + w*16 + lr]       = mM;
        ml[TOK + q0 + w*16 + lr] = lS;
    }

    // ---- epilogue: O^T already [c][q]; stage to LDS, coalesced partial writes ----
    #pragma unroll
    for (int cs = 0; cs < 4; ++cs)
        #pragma unroll
        for (int r = 0; r < 4; ++r)
            ldsf[(cs*16 + 4*lk + r)*68 + w*16 + lr] = O[cs][r];
    __syncthreads();
    int c = tid >> 2, sg = tid & 3;
    const float* srcr = &ldsf[c*68 + sg*16];
    float* dstr = &part[(size_t)c*TOK + q0 + sg*16];
    #pragma unroll
    for (int j = 0; j < 4; ++j)
        *(float4*)&dstr[j*4] = *(const float4*)&srcr[j*4];
}

// ---------------- recombine KV-split partials (exp2 domain) ----------------
__global__ __launch_bounds__(256) void recombine_kernel(
    const float* __restrict__ ws, float* __restrict__ out)
{
    int gid = blockIdx.x * 256 + threadIdx.x;   // 2 * 4cg * TOK = 73728
    int b   = gid / (4*TOK);
    int rem = gid % (4*TOK);
    int cg  = rem / TOK;
    int t   = rem % TOK;
    const float* mlp = ws + OFF_ML2;

    float m[KSPLIT], l[KSPLIT];
    float M = -INFINITY;
    #pragma unroll
    for (int ks = 0; ks < KSPLIT; ++ks) {
        int slab = b*KSPLIT + ks;
        m[ks] = mlp[(size_t)slab*2*TOK + t];
        l[ks] = mlp[(size_t)slab*2*TOK + TOK + t];
        M = fmaxf(M, m[ks]);
    }
    float wgt[KSPLIT];
    float denom = 0.f;
    #pragma unroll
    for (int ks = 0; ks < KSPLIT; ++ks) {
        wgt[ks] = exp2f(m[ks] - M);
        denom += l[ks] * wgt[ks];
    }
    float inv = 1.f / denom;
    #pragma unroll
    for (int cc = 0; cc < 16; ++cc) {
        int c = cg*16 + cc;
        float acc = 0.f;
        #pragma unroll
        for (int ks = 0; ks < KSPLIT; ++ks) {
            const float* part = part_base_c(ws, b*KSPLIT + ks);
            acc += part[(size_t)c*TOK + t] * wgt[ks];
        }
        out[(size_t)(b*64 + c)*TOK + t] = acc * inv;
    }
}

extern "C" void kernel_launch(void* const* d_in, const int* in_sizes, int n_in,
                              void* d_out, int out_size, void* d_ws, size_t ws_size,
                              hipStream_t stream)
{
    const float* frames = (const float*)d_in[0];
    const float* w1 = (const float*)d_in[1];
    const float* b1 = (const float*)d_in[2];
    const float* w2 = (const float*)d_in[3];
    const float* b2 = (const float*)d_in[4];
    const float* qw = (const float*)d_in[5];
    const float* qb = (const float*)d_in[6];
    const float* kw = (const float*)d_in[7];
    const float* kb = (const float*)d_in[8];
    const float* vw = (const float*)d_in[9];
    const float* vb = (const float*)d_in[10];
    float* ws = (float*)d_ws;
    float* out = (float*)d_out;

    hipLaunchKernelGGL(prep_kernel, dim3(144), dim3(256), 0, stream,
                       w1, b1, w2, b2, qw, qb, kw, kb, vw, vb, ws);
    hipLaunchKernelGGL(conv1_kernel, dim3(144), dim3(256), 0, stream, frames, ws);
    hipLaunchKernelGGL(conv2_kernel, dim3(768), dim3(256), 0, stream, ws);
    hipLaunchKernelGGL(qkv_kernel, dim3(3456), dim3(256), 0, stream, ws);
    hipLaunchKernelGGL(cvt_kernel, dim3(1728), dim3(256), 0, stream, ws);
    hipLaunchKernelGGL(attn_kernel, dim3(2*144*KSPLIT), dim3(256), 0, stream, ws);
    hipLaunchKernelGGL(recombine_kernel, dim3(288), dim3(256), 0, stream, ws, out);
}

// Round 11
// 278.186 us; speedup vs baseline: 1.8633x; 1.2787x over previous
//
#include <hip/hip_runtime.h>
#include <hip/hip_bf16.h>

#define TOK 9216   // 96*96 tokens per image
#define KSPLIT 5

typedef _Float16 half8 __attribute__((ext_vector_type(8)));
typedef float f32x4 __attribute__((ext_vector_type(4)));

// global_load_lds: 16B per lane, linear LDS dest (wave-uniform base + lane*16)
#define GLOAD_LDS(g, l) \
    __builtin_amdgcn_global_load_lds((const __attribute__((address_space(1))) void*)(g), \
                                     (__attribute__((address_space(3))) void*)(l), 16, 0, 0)

// ---------------- workspace layout (in floats) ----------------
#define OFF_F1   0u
#define SZ_F1    (4u*64u*TOK)            // conv1 out  [img][64][9216]
#define OFF_FEAT (OFF_F1 + SZ_F1)
#define SZ_FEAT  (2u*128u*TOK)           // conv2 out, permuted: [b][c*2+n][9216]
#define OFF_Q    (OFF_FEAT + SZ_FEAT)
#define SZ_QKV   (2u*64u*TOK)
#define OFF_K    (OFF_Q + SZ_QKV)
#define OFF_V    (OFF_K + SZ_QKV)
#define OFF_W1   (OFF_V + SZ_QKV)        // [64][9] f32
#define OFF_B1   (OFF_W1 + 576u)
#define OFF_W2T  (OFF_B1 + 64u)          // [ci][9][co] f32 (transposed)
#define OFF_B2   (OFF_W2T + 36864u)
#define OFF_WCAT (OFF_B2 + 64u)          // [192][128] f32 (q;k;v)
#define OFF_BCAT (OFF_WCAT + 24576u)     // [192]

// f16 QKV overlaid on F1 (dead after conv2). Offsets in f32 units.
#define OFF_QT   OFF_F1                  // [b][t][64] f16, scale*log2e folded
#define OFF_KT   (OFF_F1 + 589824u)      // [b][t][64] f16
#define OFF_VH   (OFF_F1 + 1179648u)     // [b][64][t] f16, ends at 1769472

// KV-split partials: 10 slabs of 64*TOK f32 each (589824 floats).
// slab 0 -> free tail of F1 region (after VH); slabs 1..9 -> FEAT..V region.
// All dead once attn runs; rewritten by conv2/qkv/cvt every replay.
#define OFF_SLAB0 1769472u
#define OFF_ML2   (OFF_FEAT + 9u*589824u)   // [slab][2 (m,l)][TOK] f32

__device__ __forceinline__ const float* part_base_c(const float* ws, int slab) {
    return ws + (slab == 0 ? OFF_SLAB0 : (OFF_FEAT + (unsigned)(slab - 1) * 589824u));
}
__device__ __forceinline__ float* part_base(float* ws, int slab) {
    return ws + (slab == 0 ? OFF_SLAB0 : (OFF_FEAT + (unsigned)(slab - 1) * 589824u));
}

// ---------------- weight prep: copy/transpose f32 weights ----------------
__global__ __launch_bounds__(256) void prep_kernel(
    const float* __restrict__ w1, const float* __restrict__ b1,
    const float* __restrict__ w2, const float* __restrict__ b2,
    const float* __restrict__ qw, const float* __restrict__ qb,
    const float* __restrict__ kw, const float* __restrict__ kb,
    const float* __restrict__ vw, const float* __restrict__ vb,
    float* __restrict__ ws)
{
    int gid = blockIdx.x * 256 + threadIdx.x;
    if (gid < 576) ws[OFF_W1 + gid] = w1[gid];
    if (gid < 64) {
        ws[OFF_B1 + gid] = b1[gid];
        ws[OFF_B2 + gid] = b2[gid];
    }
    if (gid < 36864) {   // w2[co][ci][tap] -> w2t[ci][tap][co]
        int co = gid / 576; int rem = gid % 576;
        int ci = rem / 9;  int tp = rem % 9;
        ws[OFF_W2T + (ci*9 + tp)*64 + co] = w2[gid];
    }
    if (gid < 24576) {
        int o = gid >> 7; int c = gid & 127;
        float v;
        if (o < 64)       v = qw[o*128 + c];
        else if (o < 128) v = kw[(o-64)*128 + c];
        else              v = vw[(o-128)*128 + c];
        ws[OFF_WCAT + gid] = v;
    }
    if (gid < 192) {
        float v;
        if (gid < 64)       v = qb[gid];
        else if (gid < 128) v = kb[gid-64];
        else                v = vb[gid-128];
        ws[OFF_BCAT + gid] = v;
    }
}

// ---------------- conv1: 1->64 ch, 3x3, relu ----------------
__global__ __launch_bounds__(256) void conv1_kernel(
    const float* __restrict__ x, float* __restrict__ ws)
{
    const float* w1f = ws + OFF_W1;
    const float* b1f = ws + OFF_B1;
    float* f1 = ws + OFF_F1;
    int gid = blockIdx.x * 256 + threadIdx.x;
    int img = gid / TOK;
    int p   = gid % TOK;
    int h = p / 96, w = p % 96;
    float xv[9];
    #pragma unroll
    for (int dh = 0; dh < 3; ++dh)
        #pragma unroll
        for (int dw = 0; dw < 3; ++dw) {
            int r = h + dh - 1, c = w + dw - 1;
            bool ok = (r >= 0) && (r < 96) && (c >= 0) && (c < 96);
            xv[dh*3 + dw] = ok ? x[img*TOK + r*96 + c] : 0.f;
        }
    for (int co = 0; co < 64; ++co) {
        float a = b1f[co];
        #pragma unroll
        for (int t = 0; t < 9; ++t) a += w1f[co*9 + t] * xv[t];
        f1[(size_t)(img*64 + co)*TOK + p] = fmaxf(a, 0.f);
    }
}

// ---------------- conv2: 64->64 ch, 3x3, relu; writes permuted feat ----------------
__global__ __launch_bounds__(256) void conv2_kernel(float* __restrict__ ws)
{
    __align__(16) __shared__ float sT[64 * 156];
    const float* f1  = ws + OFF_F1;
    const float* w2t = ws + OFF_W2T;
    const float* b2f = ws + OFF_B2;
    float* feat = ws + OFF_FEAT;

    int bid = blockIdx.x;            // 4 img * 96 rows * 2 strips = 768
    int img = bid / 192;
    int rem = bid % 192;
    int h  = rem >> 1;
    int s2 = rem & 1;
    int tid = threadIdx.x;

    for (int idx = tid; idx < 9600; idx += 256) {
        int ci = idx / 150;
        int r2 = idx % 150;
        int r = r2 / 50, cc = r2 % 50;
        int row = h - 1 + r, col = s2*48 - 1 + cc;
        float v = 0.f;
        if (row >= 0 && row < 96 && col >= 0 && col < 96)
            v = f1[(size_t)(img*64 + ci)*TOK + row*96 + col];
        sT[ci*156 + r*52 + cc] = v;
    }
    __syncthreads();

    int co = tid & 63, g = tid >> 6;
    int px0 = g * 12;
    float acc[12];
    float bb = b2f[co];
    #pragma unroll
    for (int j = 0; j < 12; ++j) acc[j] = bb;

    for (int ci = 0; ci < 64; ++ci) {
        float wv[9];
        #pragma unroll
        for (int t = 0; t < 9; ++t) wv[t] = w2t[(ci*9 + t)*64 + co];
        #pragma unroll
        for (int r = 0; r < 3; ++r) {
            const float4* tp4 = (const float4*)&sT[ci*156 + r*52 + px0];
            float4 a0 = tp4[0], a1 = tp4[1], a2 = tp4[2], a3 = tp4[3];
            float t16[16] = {a0.x,a0.y,a0.z,a0.w, a1.x,a1.y,a1.z,a1.w,
                             a2.x,a2.y,a2.z,a2.w, a3.x,a3.y,a3.z,a3.w};
            #pragma unroll
            for (int dw = 0; dw < 3; ++dw) {
                float wgt = wv[r*3 + dw];
                #pragma unroll
                for (int j = 0; j < 12; ++j) acc[j] += wgt * t16[j + dw];
            }
        }
    }
    int b = img >> 1, n = img & 1;
    int colbase = s2*48 + px0;
    #pragma unroll
    for (int j = 0; j < 12; ++j)
        feat[(size_t)(b*128 + co*2 + n)*TOK + h*96 + colbase + j] = fmaxf(acc[j], 0.f);
}

// ---------------- fused 1x1 QKV: [192 out][128 in] GEMV per token ----------------
__global__ __launch_bounds__(256) void qkv_kernel(float* __restrict__ ws)
{
    const float* feat = ws + OFF_FEAT;
    const float* wcat = ws + OFF_WCAT;
    const float* bcat = ws + OFF_BCAT;
    int bid = blockIdx.x;            // 2 * 36 * 48 = 3456
    int b   = bid / (36*48);
    int rem = bid % (36*48);
    int tg  = rem / 48;
    int og  = rem % 48;
    int tid = threadIdx.x;
    int o    = og*4 + (tid >> 6);
    int lane = tid & 63;
    int t0   = tg*256 + lane*4;
    const float* fb   = feat + (size_t)b*128*TOK;
    const float* wrow = wcat + o*128;
    float a0, a1, a2, a3;
    a0 = a1 = a2 = a3 = bcat[o];
    for (int c = 0; c < 128; ++c) {
        float4 fv = *(const float4*)&fb[(size_t)c*TOK + t0];
        float w = wrow[c];
        a0 += w*fv.x; a1 += w*fv.y; a2 += w*fv.z; a3 += w*fv.w;
    }
    float* dst;
    if (o < 64)       dst = ws + OFF_Q + ((size_t)b*64 + o      )*TOK;
    else if (o < 128) dst = ws + OFF_K + ((size_t)b*64 + (o-64 ))*TOK;
    else              dst = ws + OFF_V + ((size_t)b*64 + (o-128))*TOK;
    float4 out4 = {a0, a1, a2, a3};
    *(float4*)&dst[t0] = out4;
}

// ---------------- cvt: f32 [d][t] -> f16 tiles for MFMA ----------------
// Q scale folds 0.125 * log2(e) -> softmax runs in exp2 domain.
__global__ __launch_bounds__(256) void cvt_kernel(float* __restrict__ ws)
{
    __shared__ __align__(16) float lds[64*68];
    int bid = blockIdx.x;
    int tid = threadIdx.x;
    if (bid < 576) {
        int tensor = bid / 288;          // 0=Q, 1=K
        int rem = bid % 288;
        int b = rem / 144, tile = rem % 144;
        int t0 = tile * 64;
        const float* src = ws + (tensor ? OFF_K : OFF_Q) + (size_t)b*64*TOK;
        _Float16* dst = (_Float16*)(ws + (tensor ? OFF_KT : OFF_QT)) + (size_t)b*TOK*64;
        float scale = tensor ? 1.0f : 0.18033688011112042f;   // 0.125*log2(e)
        int d = tid >> 2, seg = tid & 3;
        #pragma unroll
        for (int j = 0; j < 4; ++j) {
            float4 v = *(const float4*)&src[(size_t)d*TOK + t0 + seg*16 + j*4];
            *(float4*)&lds[d*68 + seg*16 + j*4] = v;
        }
        __syncthreads();
        int t = tid >> 2, dseg = tid & 3;
        __align__(16) _Float16 h[16];
        #pragma unroll
        for (int e = 0; e < 16; ++e)
            h[e] = (_Float16)(lds[(dseg*16 + e)*68 + t] * scale);
        *(uint4*)&dst[(size_t)(t0 + t)*64 + dseg*16]     = *(uint4*)&h[0];
        *(uint4*)&dst[(size_t)(t0 + t)*64 + dseg*16 + 8] = *(uint4*)&h[8];
    } else {
        size_t idx = (size_t)(bid - 576) * 1024 + tid * 4;   // over 2*64*TOK
        const float* src = ws + OFF_V;
        _Float16* dst = (_Float16*)(ws + OFF_VH);
        float4 v = *(const float4*)&src[idx];
        union { _Float16 h[4]; uint2 u; } pk;
        pk.h[0] = (_Float16)v.x; pk.h[1] = (_Float16)v.y;
        pk.h[2] = (_Float16)v.z; pk.h[3] = (_Float16)v.w;
        *(uint2*)&dst[idx] = pk.u;
    }
}

// ---------------- flash attention partial: gload_lds pipeline, counted vmcnt ----------------
// grid = 2b x 144qt x KSPLIT; 256 thr = 4 waves x 16 q-rows; KVBLK=64.
// Staging = global_load_lds (linear dest, inverse-swizzled per-lane source);
// next tile issued at loop top, vmcnt(0) only at loop end (hidden under compute);
// raw s_barrier (no compiler vmcnt/lgkm drain).
__global__ __launch_bounds__(256, 5) void attn_kernel(float* __restrict__ ws)
{
    __shared__ __align__(16) char smem[32768];   // K0 V0 | K1 V1 (dbuf)
    float* ldsf = (float*)smem;                  // epilogue reuse: [64 c][68] f32

    int bid = blockIdx.x;       // 2 * 144 * KSPLIT
    int b   = bid / (144*KSPLIT);
    int rem = bid % (144*KSPLIT);
    int qt  = rem / KSPLIT;
    int ks  = rem % KSPLIT;
    int tid = threadIdx.x;
    int lane = tid & 63, w = tid >> 6;
    int q0 = qt * 64;
    int lr = lane & 15;         // my q (within wave's 16-row tile) / frag row
    int lk = lane >> 4;         // k-subblock group (0..3)

    int kb0 = (ks*144)/KSPLIT, kb1 = ((ks+1)*144)/KSPLIT;
    int nit = kb1 - kb0;
    int slab = b*KSPLIT + ks;

    const _Float16* Qt = (const _Float16*)(ws + OFF_QT) + (size_t)b*TOK*64;
    const _Float16* Kt = (const _Float16*)(ws + OFF_KT) + (size_t)b*TOK*64;
    const _Float16* Vh = (const _Float16*)(ws + OFF_VH) + (size_t)b*64*TOK;
    float* part = part_base(ws, slab);
    float* ml   = ws + OFF_ML2 + (size_t)slab*2*TOK;

    // Q fragments (B-operand; col=q=lr, k=ch*32+lk*8+e)
    half8 qB[2];
    #pragma unroll
    for (int ch = 0; ch < 2; ++ch)
        qB[ch] = *(const half8*)&Qt[(size_t)(q0 + w*16 + lr)*64 + ch*32 + lk*8];

    f32x4 O[4];                 // O^T[c][q]: col q = lr, row c = cs*16 + 4*lk + r
    #pragma unroll
    for (int cs = 0; cs < 4; ++cs) O[cs] = (f32x4){0.f, 0.f, 0.f, 0.f};
    float mM = -INFINITY, lS = 0.f;   // per-lane scalars (q = lr), replicated over lk

    // ---- staging geometry: wave w stages rows [w*16, w*16+16) of K and V,
    // as 2 chunks x 8 rows; linear LDS dest, inverse-swizzled global source.
    // lane l -> row r2 = chunkbase + (l>>3); logical seg = (l&7) ^ ((l>>3)&7).
    int segl = ((lane & 7) ^ ((lane >> 3) & 7)) * 8;     // f16 elems
    unsigned rbase = (unsigned)(w*16 + (lane >> 3));
    unsigned kOff = (unsigned)(kb0*64 + rbase)*64u + (unsigned)segl;  // +4096/iter
    unsigned vOff = rbase*(unsigned)TOK + (unsigned)(kb0*64) + (unsigned)segl; // +64/iter
    unsigned wk0 = (unsigned)(w * 2048);                 // wave's LDS byte base (uniform)

    // ---- prologue: stage tile kb0 into buf0 ----
    {
        char* bK = smem;
        char* bV = smem + 8192;
        GLOAD_LDS(Kt + kOff,           bK + wk0);
        GLOAD_LDS(Kt + kOff + 512,     bK + wk0 + 1024);
        GLOAD_LDS(Vh + vOff,           bV + wk0);
        GLOAD_LDS(Vh + vOff + 8u*TOK,  bV + wk0 + 1024);
    }
    asm volatile("s_waitcnt vmcnt(0)" ::: "memory");
    __builtin_amdgcn_s_barrier();

    for (int it = 0; it < nit; ++it) {
        char* sKb = smem + (it & 1) * 16384;
        char* sVb = sKb + 8192;
        char* sSt = smem + ((it + 1) & 1) * 16384;

        // ---- issue next tile's gload_lds NOW (latency hides under compute) ----
        if (it + 1 < nit) {
            unsigned kN = kOff + (unsigned)(it + 1) * 4096u;
            unsigned vN = vOff + (unsigned)(it + 1) * 64u;
            GLOAD_LDS(Kt + kN,           sSt + wk0);
            GLOAD_LDS(Kt + kN + 512,     sSt + wk0 + 1024);
            GLOAD_LDS(Vh + vN,           sSt + 8192 + wk0);
            GLOAD_LDS(Vh + vN + 8u*TOK,  sSt + 8192 + wk0 + 1024);
        }

        // ---- QK^T swapped: S^T[kt 64][q 16]; lane: q=lr, kt = st*16 + 4*lk + r ----
        f32x4 S[4];
        #pragma unroll
        for (int st = 0; st < 4; ++st) S[st] = (f32x4){0.f, 0.f, 0.f, 0.f};
        __builtin_amdgcn_s_setprio(1);
        #pragma unroll
        for (int st = 0; st < 4; ++st) {
            int t = st*16 + lr;     // A-operand row = kt
            #pragma unroll
            for (int ch = 0; ch < 2; ++ch) {
                half8 kA = *(const half8*)(sKb + ((t*128 + ch*64 + lk*16) ^ ((t&7)<<4)));
                S[st] = __builtin_amdgcn_mfma_f32_16x16x32_f16(kA, qB[ch], S[st], 0, 0, 0);
            }
        }
        __builtin_amdgcn_s_setprio(0);

        // ---- per-lane online softmax (exp2 domain), defer-max exact skip ----
        float pm = fmaxf(fmaxf(fmaxf(S[0][0], S[0][1]), fmaxf(S[0][2], S[0][3])),
                  fmaxf(fmaxf(fmaxf(S[1][0], S[1][1]), fmaxf(S[1][2], S[1][3])),
                  fmaxf(fmaxf(fmaxf(S[2][0], S[2][1]), fmaxf(S[2][2], S[2][3])),
                        fmaxf(fmaxf(S[3][0], S[3][1]), fmaxf(S[3][2], S[3][3])))));
        pm = fmaxf(pm, __shfl_xor(pm, 16));
        pm = fmaxf(pm, __shfl_xor(pm, 32));
        if (__any(pm > mM)) {
            float mn = fmaxf(mM, pm);
            float fs = exp2f(mM - mn);
            mM = mn;
            lS *= fs;
            #pragma unroll
            for (int cs = 0; cs < 4; ++cs)
                #pragma unroll
                for (int r = 0; r < 4; ++r) O[cs][r] *= fs;
        }
        float ps = 0.f;
        #pragma unroll
        for (int st = 0; st < 4; ++st)
            #pragma unroll
            for (int r = 0; r < 4; ++r) {
                S[st][r] = exp2f(S[st][r] - mM);   // p, reuse regs
                ps += S[st][r];
            }
        ps += __shfl_xor(ps, 16);
        ps += __shfl_xor(ps, 32);
        lS += ps;

        // ---- pack P pairs: pk[st][j] = f16x2(p[st][2j], p[st][2j+1]) ----
        unsigned int pk[4][2];
        #pragma unroll
        for (int st = 0; st < 4; ++st) {
            union { _Float16 h[2]; unsigned int u; } c0, c1;
            c0.h[0] = (_Float16)S[st][0]; c0.h[1] = (_Float16)S[st][1];
            c1.h[0] = (_Float16)S[st][2]; c1.h[1] = (_Float16)S[st][3];
            pk[st][0] = c0.u; pk[st][1] = c1.u;
        }

        // ---- PV swapped: O^T[c][q] += V^T[c][kt] · P^T[kt][q] ----
        // pB: lane (lr,lk) word w2 <- src lane lr+32*(lk&1)+16*(w2>>1),
        //     reg pk[ch2*2 + (lk>>1)][w2&1]
        int srcA = lr + 32*(lk & 1);
        int sel  = lk >> 1;
        __builtin_amdgcn_s_setprio(1);
        #pragma unroll
        for (int ch2 = 0; ch2 < 2; ++ch2) {
            union { unsigned int u[4]; half8 h; } pb;
            #pragma unroll
            for (int w2 = 0; w2 < 4; ++w2) {
                int src = srcA + 16*(w2 >> 1);
                int lo = __shfl((int)pk[ch2*2 + 0][w2 & 1], src);
                int hi = __shfl((int)pk[ch2*2 + 1][w2 & 1], src);
                pb.u[w2] = (unsigned int)(sel ? hi : lo);
            }
            #pragma unroll
            for (int cs = 0; cs < 4; ++cs) {
                int crow = cs*16 + lr;
                half8 vA = *(const half8*)(sVb + ((crow*128 + ch2*64 + lk*16) ^ ((crow&7)<<4)));
                O[cs] = __builtin_amdgcn_mfma_f32_16x16x32_f16(vA, pb.h, O[cs], 0, 0, 0);
            }
        }
        __builtin_amdgcn_s_setprio(0);

        // ---- end-of-iter sync: counted wait (loads hidden under compute), raw barrier ----
        asm volatile("s_waitcnt vmcnt(0)" ::: "memory");
        __builtin_amdgcn_s_barrier();
    }

    // ---- write m, l (per q-row; lk==0 lanes hold q = w*16 + lr) ----
    if (lk == 0) {
        ml[q0 + w*16 + lr]       = mM;
        ml[TOK + q0 + w*16 + lr] = lS;
    }

    // ---- epilogue: O^T already [c][q]; stage to LDS, coalesced partial writes ----
    #pragma unroll
    for (int cs = 0; cs < 4; ++cs)
        #pragma unroll
        for (int r = 0; r < 4; ++r)
            ldsf[(cs*16 + 4*lk + r)*68 + w*16 + lr] = O[cs][r];
    __syncthreads();
    int c = tid >> 2, sg = tid & 3;
    const float* srcr = &ldsf[c*68 + sg*16];
    float* dstr = &part[(size_t)c*TOK + q0 + sg*16];
    #pragma unroll
    for (int j = 0; j < 4; ++j)
        *(float4*)&dstr[j*4] = *(const float4*)&srcr[j*4];
}

// ---------------- recombine KV-split partials (exp2 domain) ----------------
__global__ __launch_bounds__(256) void recombine_kernel(
    const float* __restrict__ ws, float* __restrict__ out)
{
    int gid = blockIdx.x * 256 + threadIdx.x;   // 2 * 4cg * TOK = 73728
    int b   = gid / (4*TOK);
    int rem = gid % (4*TOK);
    int cg  = rem / TOK;
    int t   = rem % TOK;
    const float* mlp = ws + OFF_ML2;

    float m[KSPLIT], l[KSPLIT];
    float M = -INFINITY;
    #pragma unroll
    for (int ks = 0; ks < KSPLIT; ++ks) {
        int slab = b*KSPLIT + ks;
        m[ks] = mlp[(size_t)slab*2*TOK + t];
        l[ks] = mlp[(size_t)slab*2*TOK + TOK + t];
        M = fmaxf(M, m[ks]);
    }
    float wgt[KSPLIT];
    float denom = 0.f;
    #pragma unroll
    for (int ks = 0; ks < KSPLIT; ++ks) {
        wgt[ks] = exp2f(m[ks] - M);
        denom += l[ks] * wgt[ks];
    }
    float inv = 1.f / denom;
    #pragma unroll
    for (int cc = 0; cc < 16; ++cc) {
        int c = cg*16 + cc;
        float acc = 0.f;
        #pragma unroll
        for (int ks = 0; ks < KSPLIT; ++ks) {
            const float* part = part_base_c(ws, b*KSPLIT + ks);
            acc += part[(size_t)c*TOK + t] * wgt[ks];
        }
        out[(size_t)(b*64 + c)*TOK + t] = acc * inv;
    }
}

extern "C" void kernel_launch(void* const* d_in, const int* in_sizes, int n_in,
                              void* d_out, int out_size, void* d_ws, size_t ws_size,
                              hipStream_t stream)
{
    const float* frames = (const float*)d_in[0];
    const float* w1 = (const float*)d_in[1];
    const float* b1 = (const float*)d_in[2];
    const float* w2 = (const float*)d_in[3];
    const float* b2 = (const float*)d_in[4];
    const float* qw = (const float*)d_in[5];
    const float* qb = (const float*)d_in[6];
    const float* kw = (const float*)d_in[7];
    const float* kb = (const float*)d_in[8];
    const float* vw = (const float*)d_in[9];
    const float* vb = (const float*)d_in[10];
    float* ws = (float*)d_ws;
    float* out = (float*)d_out;

    hipLaunchKernelGGL(prep_kernel, dim3(144), dim3(256), 0, stream,
                       w1, b1, w2, b2, qw, qb, kw, kb, vw, vb, ws);
    hipLaunchKernelGGL(conv1_kernel, dim3(144), dim3(256), 0, stream, frames, ws);
    hipLaunchKernelGGL(conv2_kernel, dim3(768), dim3(256), 0, stream, ws);
    hipLaunchKernelGGL(qkv_kernel, dim3(3456), dim3(256), 0, stream, ws);
    hipLaunchKernelGGL(cvt_kernel, dim3(1728), dim3(256), 0, stream, ws);
    hipLaunchKernelGGL(attn_kernel, dim3(2*144*KSPLIT), dim3(256), 0, stream, ws);
    hipLaunchKernelGGL(recombine_kernel, dim3(288), dim3(256), 0, stream, ws, out);
}

// Round 12
// 218.366 us; speedup vs baseline: 2.3738x; 1.2739x over previous
//
#include <hip/hip_runtime.h>
#include <hip/hip_bf16.h>

#define TOK 9216   // 96*96 tokens per image
#define KSPLIT 5

typedef _Float16 half8 __attribute__((ext_vector_type(8)));
typedef float f32x4 __attribute__((ext_vector_type(4)));

// global_load_lds: 16B per lane, linear LDS dest (wave-uniform base + lane*16)
#define GLOAD_LDS(g, l) \
    __builtin_amdgcn_global_load_lds((const __attribute__((address_space(1))) void*)(g), \
                                     (__attribute__((address_space(3))) void*)(l), 16, 0, 0)

#define QSCALE 0.18033688011112042f   // 0.125 * log2(e); softmax runs in exp2 domain

// ---------------- workspace layout (in floats) ----------------
#define OFF_F1   0u
#define SZ_F1    (4u*64u*TOK)            // conv1 out  [img][64][9216] f32
#define OFF_FEAT (OFF_F1 + SZ_F1)        // conv2 out: [b][t][128] f16 (1.18M f32 slots)
#define SZ_FEAT  (2u*128u*TOK)
#define OFF_Q    (OFF_FEAT + SZ_FEAT)    // (unused f32 regions, kept for slab math)
#define SZ_QKV   (2u*64u*TOK)
#define OFF_K    (OFF_Q + SZ_QKV)
#define OFF_V    (OFF_K + SZ_QKV)
#define OFF_W1   (OFF_V + SZ_QKV)        // [64][9] f32
#define OFF_B1   (OFF_W1 + 576u)
#define OFF_W2T  (OFF_B1 + 64u)          // [ci][9][co] f32 (transposed)
#define OFF_B2   (OFF_W2T + 36864u)
#define OFF_WCAT (OFF_B2 + 64u)          // [192][128] f16 (q(scaled);k;v)
#define OFF_BCAT (OFF_WCAT + 24576u)     // [192] f32 (qb scaled)

// f16 QKV overlaid on F1 (dead after conv2+qkvgemm). Offsets in f32 units.
#define OFF_QT   OFF_F1                  // [b][t][64] f16, scale folded
#define OFF_KT   (OFF_F1 + 589824u)      // [b][t][64] f16
#define OFF_VH   (OFF_F1 + 1179648u)     // [b][64][t] f16, ends at 1769472

// KV-split partials: 10 slabs of 64*TOK f32 each (589824 floats).
// slab 0 -> free tail of F1 region (after VH); slabs 1..9 -> FEAT..V region.
// All dead once attn runs; rewritten by conv2/qkvgemm every replay.
#define OFF_SLAB0 1769472u
#define OFF_ML2   (OFF_FEAT + 9u*589824u)   // [slab][2 (m,l)][TOK] f32

__device__ __forceinline__ const float* part_base_c(const float* ws, int slab) {
    return ws + (slab == 0 ? OFF_SLAB0 : (OFF_FEAT + (unsigned)(slab - 1) * 589824u));
}
__device__ __forceinline__ float* part_base(float* ws, int slab) {
    return ws + (slab == 0 ? OFF_SLAB0 : (OFF_FEAT + (unsigned)(slab - 1) * 589824u));
}

// ---------------- weight prep ----------------
__global__ __launch_bounds__(256) void prep_kernel(
    const float* __restrict__ w1, const float* __restrict__ b1,
    const float* __restrict__ w2, const float* __restrict__ b2,
    const float* __restrict__ qw, const float* __restrict__ qb,
    const float* __restrict__ kw, const float* __restrict__ kb,
    const float* __restrict__ vw, const float* __restrict__ vb,
    float* __restrict__ ws)
{
    int gid = blockIdx.x * 256 + threadIdx.x;
    if (gid < 576) ws[OFF_W1 + gid] = w1[gid];
    if (gid < 64) {
        ws[OFF_B1 + gid] = b1[gid];
        ws[OFF_B2 + gid] = b2[gid];
    }
    if (gid < 36864) {   // w2[co][ci][tap] -> w2t[ci][tap][co]
        int co = gid / 576; int rem = gid % 576;
        int ci = rem / 9;  int tp = rem % 9;
        ws[OFF_W2T + (ci*9 + tp)*64 + co] = w2[gid];
    }
    if (gid < 24576) {   // WCAT f16, q rows pre-scaled (exp2-domain softmax)
        int o = gid >> 7; int c = gid & 127;
        float v;
        if (o < 64)       v = qw[o*128 + c] * QSCALE;
        else if (o < 128) v = kw[(o-64)*128 + c];
        else              v = vw[(o-128)*128 + c];
        ((_Float16*)(ws + OFF_WCAT))[gid] = (_Float16)v;
    }
    if (gid < 192) {
        float v;
        if (gid < 64)       v = qb[gid] * QSCALE;
        else if (gid < 128) v = kb[gid-64];
        else                v = vb[gid-128];
        ws[OFF_BCAT + gid] = v;
    }
}

// ---------------- conv1: 1->64 ch, 3x3, relu ----------------
__global__ __launch_bounds__(256) void conv1_kernel(
    const float* __restrict__ x, float* __restrict__ ws)
{
    const float* w1f = ws + OFF_W1;
    const float* b1f = ws + OFF_B1;
    float* f1 = ws + OFF_F1;
    int gid = blockIdx.x * 256 + threadIdx.x;
    int img = gid / TOK;
    int p   = gid % TOK;
    int h = p / 96, w = p % 96;
    float xv[9];
    #pragma unroll
    for (int dh = 0; dh < 3; ++dh)
        #pragma unroll
        for (int dw = 0; dw < 3; ++dw) {
            int r = h + dh - 1, c = w + dw - 1;
            bool ok = (r >= 0) && (r < 96) && (c >= 0) && (c < 96);
            xv[dh*3 + dw] = ok ? x[img*TOK + r*96 + c] : 0.f;
        }
    for (int co = 0; co < 64; ++co) {
        float a = b1f[co];
        #pragma unroll
        for (int t = 0; t < 9; ++t) a += w1f[co*9 + t] * xv[t];
        f1[(size_t)(img*64 + co)*TOK + p] = fmaxf(a, 0.f);
    }
}

// ---------------- conv2: 64->64 ch, 3x3, relu; writes f16 feat [b][t][128] ----------------
__global__ __launch_bounds__(256) void conv2_kernel(float* __restrict__ ws)
{
    __align__(16) __shared__ float sT[64 * 156];
    const float* f1  = ws + OFF_F1;
    const float* w2t = ws + OFF_W2T;
    const float* b2f = ws + OFF_B2;

    int bid = blockIdx.x;            // 4 img * 96 rows * 2 strips = 768
    int img = bid / 192;
    int rem = bid % 192;
    int h  = rem >> 1;
    int s2 = rem & 1;
    int tid = threadIdx.x;

    for (int idx = tid; idx < 9600; idx += 256) {
        int ci = idx / 150;
        int r2 = idx % 150;
        int r = r2 / 50, cc = r2 % 50;
        int row = h - 1 + r, col = s2*48 - 1 + cc;
        float v = 0.f;
        if (row >= 0 && row < 96 && col >= 0 && col < 96)
            v = f1[(size_t)(img*64 + ci)*TOK + row*96 + col];
        sT[ci*156 + r*52 + cc] = v;
    }
    __syncthreads();

    int co = tid & 63, g = tid >> 6;
    int px0 = g * 12;
    float acc[12];
    float bb = b2f[co];
    #pragma unroll
    for (int j = 0; j < 12; ++j) acc[j] = bb;

    for (int ci = 0; ci < 64; ++ci) {
        float wv[9];
        #pragma unroll
        for (int t = 0; t < 9; ++t) wv[t] = w2t[(ci*9 + t)*64 + co];
        #pragma unroll
        for (int r = 0; r < 3; ++r) {
            const float4* tp4 = (const float4*)&sT[ci*156 + r*52 + px0];
            float4 a0 = tp4[0], a1 = tp4[1], a2 = tp4[2], a3 = tp4[3];
            float t16[16] = {a0.x,a0.y,a0.z,a0.w, a1.x,a1.y,a1.z,a1.w,
                             a2.x,a2.y,a2.z,a2.w, a3.x,a3.y,a3.z,a3.w};
            #pragma unroll
            for (int dw = 0; dw < 3; ++dw) {
                float wgt = wv[r*3 + dw];
                #pragma unroll
                for (int j = 0; j < 12; ++j) acc[j] += wgt * t16[j + dw];
            }
        }
    }
    int b = img >> 1, n = img & 1;
    _Float16* featH = (_Float16*)(ws + OFF_FEAT) + (size_t)b*TOK*128;
    int tbase = h*96 + s2*48 + px0;
    #pragma unroll
    for (int j = 0; j < 12; ++j)
        featH[(size_t)(tbase + j)*128 + co*2 + n] = (_Float16)fmaxf(acc[j], 0.f);
}

// ---------------- fused QKV GEMM (MFMA, all-register): feat f16 -> QT/KT/VH ----------------
// grid = 2b x 288 token-tiles(32); 256 thr = 4 waves.
// Wave w: out-tiles {3w..3w+2} x 2 token-tiles; K=128 -> 24 MFMA/wave.
__global__ __launch_bounds__(256) void qkvgemm_kernel(float* __restrict__ ws)
{
    int bid = blockIdx.x;            // 2 * 288
    int b   = bid / 288;
    int tt0 = (bid % 288) * 32;
    int tid = threadIdx.x;
    int lane = tid & 63, w = tid >> 6;
    int lr = lane & 15, lk = lane >> 4;

    const _Float16* featH = (const _Float16*)(ws + OFF_FEAT) + (size_t)b*TOK*128;
    const _Float16* W  = (const _Float16*)(ws + OFF_WCAT);
    const float* bc = ws + OFF_BCAT;
    _Float16* QT = (_Float16*)(ws + OFF_QT) + (size_t)b*TOK*64;
    _Float16* KT = (_Float16*)(ws + OFF_KT) + (size_t)b*TOK*64;
    _Float16* VH = (_Float16*)(ws + OFF_VH) + (size_t)b*64*TOK;

    // B frags: feat row t = tt0 + tt*16 + lr, k = kc*32 + lk*8 (16B contiguous)
    half8 bf[2][4];
    #pragma unroll
    for (int tt = 0; tt < 2; ++tt)
        #pragma unroll
        for (int kc = 0; kc < 4; ++kc)
            bf[tt][kc] = *(const half8*)&featH[(size_t)(tt0 + tt*16 + lr)*128 + kc*32 + lk*8];

    // A frags: W row o = (3w+i)*16 + lr
    half8 af[3][4];
    #pragma unroll
    for (int i = 0; i < 3; ++i)
        #pragma unroll
        for (int kc = 0; kc < 4; ++kc)
            af[i][kc] = *(const half8*)&W[(size_t)((w*3 + i)*16 + lr)*128 + kc*32 + lk*8];

    #pragma unroll
    for (int i = 0; i < 3; ++i) {
        int ot = w*3 + i;
        f32x4 a0, a1;
        #pragma unroll
        for (int r = 0; r < 4; ++r) {
            float bv = bc[ot*16 + 4*lk + r];
            a0[r] = bv; a1[r] = bv;
        }
        #pragma unroll
        for (int kc = 0; kc < 4; ++kc) {
            a0 = __builtin_amdgcn_mfma_f32_16x16x32_f16(af[i][kc], bf[0][kc], a0, 0, 0, 0);
            a1 = __builtin_amdgcn_mfma_f32_16x16x32_f16(af[i][kc], bf[1][kc], a1, 0, 0, 0);
        }
        // D: col = token = (tt)*16+lr, rows = ot*16 + 4*lk + r
        #pragma unroll
        for (int tt = 0; tt < 2; ++tt) {
            f32x4 a = tt ? a1 : a0;
            int t = tt0 + tt*16 + lr;
            if (ot < 4) {
                union { _Float16 h[4]; uint2 u; } p;
                #pragma unroll
                for (int r = 0; r < 4; ++r) p.h[r] = (_Float16)a[r];
                *(uint2*)&QT[(size_t)t*64 + ot*16 + 4*lk] = p.u;
            } else if (ot < 8) {
                union { _Float16 h[4]; uint2 u; } p;
                #pragma unroll
                for (int r = 0; r < 4; ++r) p.h[r] = (_Float16)a[r];
                *(uint2*)&KT[(size_t)t*64 + (ot-4)*16 + 4*lk] = p.u;
            } else {
                #pragma unroll
                for (int r = 0; r < 4; ++r)
                    VH[(size_t)((ot-8)*16 + 4*lk + r)*TOK + t] = (_Float16)a[r];
            }
        }
    }
}

// ---------------- flash attention partial: gload_lds pipeline, counted vmcnt ----------------
// (unchanged from round 11)
__global__ __launch_bounds__(256, 5) void attn_kernel(float* __restrict__ ws)
{
    __shared__ __align__(16) char smem[32768];   // K0 V0 | K1 V1 (dbuf)
    float* ldsf = (float*)smem;                  // epilogue reuse: [64 c][68] f32

    int bid = blockIdx.x;       // 2 * 144 * KSPLIT
    int b   = bid / (144*KSPLIT);
    int rem = bid % (144*KSPLIT);
    int qt  = rem / KSPLIT;
    int ks  = rem % KSPLIT;
    int tid = threadIdx.x;
    int lane = tid & 63, w = tid >> 6;
    int q0 = qt * 64;
    int lr = lane & 15;
    int lk = lane >> 4;

    int kb0 = (ks*144)/KSPLIT, kb1 = ((ks+1)*144)/KSPLIT;
    int nit = kb1 - kb0;
    int slab = b*KSPLIT + ks;

    const _Float16* Qt = (const _Float16*)(ws + OFF_QT) + (size_t)b*TOK*64;
    const _Float16* Kt = (const _Float16*)(ws + OFF_KT) + (size_t)b*TOK*64;
    const _Float16* Vh = (const _Float16*)(ws + OFF_VH) + (size_t)b*64*TOK;
    float* part = part_base(ws, slab);
    float* ml   = ws + OFF_ML2 + (size_t)slab*2*TOK;

    half8 qB[2];
    #pragma unroll
    for (int ch = 0; ch < 2; ++ch)
        qB[ch] = *(const half8*)&Qt[(size_t)(q0 + w*16 + lr)*64 + ch*32 + lk*8];

    f32x4 O[4];
    #pragma unroll
    for (int cs = 0; cs < 4; ++cs) O[cs] = (f32x4){0.f, 0.f, 0.f, 0.f};
    float mM = -INFINITY, lS = 0.f;

    int segl = ((lane & 7) ^ ((lane >> 3) & 7)) * 8;
    unsigned rbase = (unsigned)(w*16 + (lane >> 3));
    unsigned kOff = (unsigned)(kb0*64 + rbase)*64u + (unsigned)segl;
    unsigned vOff = rbase*(unsigned)TOK + (unsigned)(kb0*64) + (unsigned)segl;
    unsigned wk0 = (unsigned)(w * 2048);

    {
        char* bK = smem;
        char* bV = smem + 8192;
        GLOAD_LDS(Kt + kOff,           bK + wk0);
        GLOAD_LDS(Kt + kOff + 512,     bK + wk0 + 1024);
        GLOAD_LDS(Vh + vOff,           bV + wk0);
        GLOAD_LDS(Vh + vOff + 8u*TOK,  bV + wk0 + 1024);
    }
    asm volatile("s_waitcnt vmcnt(0)" ::: "memory");
    __builtin_amdgcn_s_barrier();

    for (int it = 0; it < nit; ++it) {
        char* sKb = smem + (it & 1) * 16384;
        char* sVb = sKb + 8192;
        char* sSt = smem + ((it + 1) & 1) * 16384;

        if (it + 1 < nit) {
            unsigned kN = kOff + (unsigned)(it + 1) * 4096u;
            unsigned vN = vOff + (unsigned)(it + 1) * 64u;
            GLOAD_LDS(Kt + kN,           sSt + wk0);
            GLOAD_LDS(Kt + kN + 512,     sSt + wk0 + 1024);
            GLOAD_LDS(Vh + vN,           sSt + 8192 + wk0);
            GLOAD_LDS(Vh + vN + 8u*TOK,  sSt + 8192 + wk0 + 1024);
        }

        f32x4 S[4];
        #pragma unroll
        for (int st = 0; st < 4; ++st) S[st] = (f32x4){0.f, 0.f, 0.f, 0.f};
        __builtin_amdgcn_s_setprio(1);
        #pragma unroll
        for (int st = 0; st < 4; ++st) {
            int t = st*16 + lr;
            #pragma unroll
            for (int ch = 0; ch < 2; ++ch) {
                half8 kA = *(const half8*)(sKb + ((t*128 + ch*64 + lk*16) ^ ((t&7)<<4)));
                S[st] = __builtin_amdgcn_mfma_f32_16x16x32_f16(kA, qB[ch], S[st], 0, 0, 0);
            }
        }
        __builtin_amdgcn_s_setprio(0);

        float pm = fmaxf(fmaxf(fmaxf(S[0][0], S[0][1]), fmaxf(S[0][2], S[0][3])),
                  fmaxf(fmaxf(fmaxf(S[1][0], S[1][1]), fmaxf(S[1][2], S[1][3])),
                  fmaxf(fmaxf(fmaxf(S[2][0], S[2][1]), fmaxf(S[2][2], S[2][3])),
                        fmaxf(fmaxf(S[3][0], S[3][1]), fmaxf(S[3][2], S[3][3])))));
        pm = fmaxf(pm, __shfl_xor(pm, 16));
        pm = fmaxf(pm, __shfl_xor(pm, 32));
        if (__any(pm > mM)) {
            float mn = fmaxf(mM, pm);
            float fs = exp2f(mM - mn);
            mM = mn;
            lS *= fs;
            #pragma unroll
            for (int cs = 0; cs < 4; ++cs)
                #pragma unroll
                for (int r = 0; r < 4; ++r) O[cs][r] *= fs;
        }
        float ps = 0.f;
        #pragma unroll
        for (int st = 0; st < 4; ++st)
            #pragma unroll
            for (int r = 0; r < 4; ++r) {
                S[st][r] = exp2f(S[st][r] - mM);
                ps += S[st][r];
            }
        ps += __shfl_xor(ps, 16);
        ps += __shfl_xor(ps, 32);
        lS += ps;

        unsigned int pk[4][2];
        #pragma unroll
        for (int st = 0; st < 4; ++st) {
            union { _Float16 h[2]; unsigned int u; } c0, c1;
            c0.h[0] = (_Float16)S[st][0]; c0.h[1] = (_Float16)S[st][1];
            c1.h[0] = (_Float16)S[st][2]; c1.h[1] = (_Float16)S[st][3];
            pk[st][0] = c0.u; pk[st][1] = c1.u;
        }

        int srcA = lr + 32*(lk & 1);
        int sel  = lk >> 1;
        __builtin_amdgcn_s_setprio(1);
        #pragma unroll
        for (int ch2 = 0; ch2 < 2; ++ch2) {
            union { unsigned int u[4]; half8 h; } pb;
            #pragma unroll
            for (int w2 = 0; w2 < 4; ++w2) {
                int src = srcA + 16*(w2 >> 1);
                int lo = __shfl((int)pk[ch2*2 + 0][w2 & 1], src);
                int hi = __shfl((int)pk[ch2*2 + 1][w2 & 1], src);
                pb.u[w2] = (unsigned int)(sel ? hi : lo);
            }
            #pragma unroll
            for (int cs = 0; cs < 4; ++cs) {
                int crow = cs*16 + lr;
                half8 vA = *(const half8*)(sVb + ((crow*128 + ch2*64 + lk*16) ^ ((crow&7)<<4)));
                O[cs] = __builtin_amdgcn_mfma_f32_16x16x32_f16(vA, pb.h, O[cs], 0, 0, 0);
            }
        }
        __builtin_amdgcn_s_setprio(0);

        asm volatile("s_waitcnt vmcnt(0)" ::: "memory");
        __builtin_amdgcn_s_barrier();
    }

    if (lk == 0) {
        ml[q0 + w*16 + lr]       = mM;
        ml[TOK + q0 + w*16 + lr] = lS;
    }

    #pragma unroll
    for (int cs = 0; cs < 4; ++cs)
        #pragma unroll
        for (int r = 0; r < 4; ++r)
            ldsf[(cs*16 + 4*lk + r)*68 + w*16 + lr] = O[cs][r];
    __syncthreads();
    int c = tid >> 2, sg = tid & 3;
    const float* srcr = &ldsf[c*68 + sg*16];
    float* dstr = &part[(size_t)c*TOK + q0 + sg*16];
    #pragma unroll
    for (int j = 0; j < 4; ++j)
        *(float4*)&dstr[j*4] = *(const float4*)&srcr[j*4];
}

// ---------------- recombine KV-split partials (exp2 domain) ----------------
__global__ __launch_bounds__(256) void recombine_kernel(
    const float* __restrict__ ws, float* __restrict__ out)
{
    int gid = blockIdx.x * 256 + threadIdx.x;   // 2 * 4cg * TOK = 73728
    int b   = gid / (4*TOK);
    int rem = gid % (4*TOK);
    int cg  = rem / TOK;
    int t   = rem % TOK;
    const float* mlp = ws + OFF_ML2;

    float m[KSPLIT], l[KSPLIT];
    float M = -INFINITY;
    #pragma unroll
    for (int ks = 0; ks < KSPLIT; ++ks) {
        int slab = b*KSPLIT + ks;
        m[ks] = mlp[(size_t)slab*2*TOK + t];
        l[ks] = mlp[(size_t)slab*2*TOK + TOK + t];
        M = fmaxf(M, m[ks]);
    }
    float wgt[KSPLIT];
    float denom = 0.f;
    #pragma unroll
    for (int ks = 0; ks < KSPLIT; ++ks) {
        wgt[ks] = exp2f(m[ks] - M);
        denom += l[ks] * wgt[ks];
    }
    float inv = 1.f / denom;
    #pragma unroll
    for (int cc = 0; cc < 16; ++cc) {
        int c = cg*16 + cc;
        float acc = 0.f;
        #pragma unroll
        for (int ks = 0; ks < KSPLIT; ++ks) {
            const float* part = part_base_c(ws, b*KSPLIT + ks);
            acc += part[(size_t)c*TOK + t] * wgt[ks];
        }
        out[(size_t)(b*64 + c)*TOK + t] = acc * inv;
    }
}

extern "C" void kernel_launch(void* const* d_in, const int* in_sizes, int n_in,
                              void* d_out, int out_size, void* d_ws, size_t ws_size,
                              hipStream_t stream)
{
    const float* frames = (const float*)d_in[0];
    const float* w1 = (const float*)d_in[1];
    const float* b1 = (const float*)d_in[2];
    const float* w2 = (const float*)d_in[3];
    const float* b2 = (const float*)d_in[4];
    const float* qw = (const float*)d_in[5];
    const float* qb = (const float*)d_in[6];
    const float* kw = (const float*)d_in[7];
    const float* kb = (const float*)d_in[8];
    const float* vw = (const float*)d_in[9];
    const float* vb = (const float*)d_in[10];
    float* ws = (float*)d_ws;
    float* out = (float*)d_out;

    hipLaunchKernelGGL(prep_kernel, dim3(144), dim3(256), 0, stream,
                       w1, b1, w2, b2, qw, qb, kw, kb, vw, vb, ws);
    hipLaunchKernelGGL(conv1_kernel, dim3(144), dim3(256), 0, stream, frames, ws);
    hipLaunchKernelGGL(conv2_kernel, dim3(768), dim3(256), 0, stream, ws);
    hipLaunchKernelGGL(qkvgemm_kernel, dim3(576), dim3(256), 0, stream, ws);
    hipLaunchKernelGGL(attn_kernel, dim3(2*144*KSPLIT), dim3(256), 0, stream, ws);
    hipLaunchKernelGGL(recombine_kernel, dim3(288), dim3(256), 0, stream, ws, out);
}

// Round 13
// 208.641 us; speedup vs baseline: 2.4844x; 1.0466x over previous
//
#include <hip/hip_runtime.h>
#include <hip/hip_bf16.h>

#define TOK 9216   // 96*96 tokens per image
#define KSPLIT 5

typedef _Float16 half8 __attribute__((ext_vector_type(8)));
typedef float f32x4 __attribute__((ext_vector_type(4)));

// global_load_lds: 16B per lane, linear LDS dest (wave-uniform base + lane*16)
#define GLOAD_LDS(g, l) \
    __builtin_amdgcn_global_load_lds((const __attribute__((address_space(1))) void*)(g), \
                                     (__attribute__((address_space(3))) void*)(l), 16, 0, 0)

#define QSCALE 0.18033688011112042f   // 0.125 * log2(e); softmax runs in exp2 domain

// ---------------- workspace layout (in floats) ----------------
#define OFF_F1   0u
#define SZ_F1    (4u*64u*TOK)            // conv1 out  [img][64][9216] f32
#define OFF_FEAT (OFF_F1 + SZ_F1)        // conv2 out: [b][t][128] f16 (1.18M f32 slots)
#define SZ_FEAT  (2u*128u*TOK)
#define OFF_Q    (OFF_FEAT + SZ_FEAT)    // (unused f32 regions, kept for slab math)
#define SZ_QKV   (2u*64u*TOK)
#define OFF_K    (OFF_Q + SZ_QKV)
#define OFF_V    (OFF_K + SZ_QKV)
#define OFF_W1   (OFF_V + SZ_QKV)        // [64][9] f32
#define OFF_B1   (OFF_W1 + 576u)
#define OFF_W2T  (OFF_B1 + 64u)          // [ci][9][co] f32 (transposed)
#define OFF_B2   (OFF_W2T + 36864u)
#define OFF_WCAT (OFF_B2 + 64u)          // [192][128] f16 (q(scaled);k;v)
#define OFF_BCAT (OFF_WCAT + 24576u)     // [192] f32 (qb scaled)

// f16 QKV overlaid on F1 (dead after conv2+qkvgemm). Offsets in f32 units.
#define OFF_QT   OFF_F1                  // [b][t][64] f16, scale folded
#define OFF_KT   (OFF_F1 + 589824u)      // [b][t][64] f16
#define OFF_VH   (OFF_F1 + 1179648u)     // [b][64][t] f16, ends at 1769472

// KV-split partials: 10 slabs of 64*TOK f32 each (589824 floats).
// slab 0 -> free tail of F1 region (after VH); slabs 1..9 -> FEAT..V region.
// All dead once attn runs; rewritten by conv2/qkvgemm every replay.
#define OFF_SLAB0 1769472u
#define OFF_ML2   (OFF_FEAT + 9u*589824u)   // [slab][2 (m,l)][TOK] f32

__device__ __forceinline__ const float* part_base_c(const float* ws, int slab) {
    return ws + (slab == 0 ? OFF_SLAB0 : (OFF_FEAT + (unsigned)(slab - 1) * 589824u));
}
__device__ __forceinline__ float* part_base(float* ws, int slab) {
    return ws + (slab == 0 ? OFF_SLAB0 : (OFF_FEAT + (unsigned)(slab - 1) * 589824u));
}

// ---------------- weight prep ----------------
__global__ __launch_bounds__(256) void prep_kernel(
    const float* __restrict__ w1, const float* __restrict__ b1,
    const float* __restrict__ w2, const float* __restrict__ b2,
    const float* __restrict__ qw, const float* __restrict__ qb,
    const float* __restrict__ kw, const float* __restrict__ kb,
    const float* __restrict__ vw, const float* __restrict__ vb,
    float* __restrict__ ws)
{
    int gid = blockIdx.x * 256 + threadIdx.x;
    if (gid < 576) ws[OFF_W1 + gid] = w1[gid];
    if (gid < 64) {
        ws[OFF_B1 + gid] = b1[gid];
        ws[OFF_B2 + gid] = b2[gid];
    }
    if (gid < 36864) {   // w2[co][ci][tap] -> w2t[ci][tap][co]
        int co = gid / 576; int rem = gid % 576;
        int ci = rem / 9;  int tp = rem % 9;
        ws[OFF_W2T + (ci*9 + tp)*64 + co] = w2[gid];
    }
    if (gid < 24576) {   // WCAT f16, q rows pre-scaled (exp2-domain softmax)
        int o = gid >> 7; int c = gid & 127;
        float v;
        if (o < 64)       v = qw[o*128 + c] * QSCALE;
        else if (o < 128) v = kw[(o-64)*128 + c];
        else              v = vw[(o-128)*128 + c];
        ((_Float16*)(ws + OFF_WCAT))[gid] = (_Float16)v;
    }
    if (gid < 192) {
        float v;
        if (gid < 64)       v = qb[gid] * QSCALE;
        else if (gid < 128) v = kb[gid-64];
        else                v = vb[gid-128];
        ws[OFF_BCAT + gid] = v;
    }
}

// ---------------- conv1: 1->64 ch, 3x3, relu ----------------
__global__ __launch_bounds__(256) void conv1_kernel(
    const float* __restrict__ x, float* __restrict__ ws)
{
    const float* w1f = ws + OFF_W1;
    const float* b1f = ws + OFF_B1;
    float* f1 = ws + OFF_F1;
    int gid = blockIdx.x * 256 + threadIdx.x;
    int img = gid / TOK;
    int p   = gid % TOK;
    int h = p / 96, w = p % 96;
    float xv[9];
    #pragma unroll
    for (int dh = 0; dh < 3; ++dh)
        #pragma unroll
        for (int dw = 0; dw < 3; ++dw) {
            int r = h + dh - 1, c = w + dw - 1;
            bool ok = (r >= 0) && (r < 96) && (c >= 0) && (c < 96);
            xv[dh*3 + dw] = ok ? x[img*TOK + r*96 + c] : 0.f;
        }
    for (int co = 0; co < 64; ++co) {
        float a = b1f[co];
        #pragma unroll
        for (int t = 0; t < 9; ++t) a += w1f[co*9 + t] * xv[t];
        f1[(size_t)(img*64 + co)*TOK + p] = fmaxf(a, 0.f);
    }
}

// ---------------- conv2: 64->64 ch, 3x3, relu; writes f16 feat [b][t][128] ----------------
__global__ __launch_bounds__(256) void conv2_kernel(float* __restrict__ ws)
{
    __align__(16) __shared__ float sT[64 * 156];
    const float* f1  = ws + OFF_F1;
    const float* w2t = ws + OFF_W2T;
    const float* b2f = ws + OFF_B2;

    int bid = blockIdx.x;            // 4 img * 96 rows * 2 strips = 768
    int img = bid / 192;
    int rem = bid % 192;
    int h  = rem >> 1;
    int s2 = rem & 1;
    int tid = threadIdx.x;

    for (int idx = tid; idx < 9600; idx += 256) {
        int ci = idx / 150;
        int r2 = idx % 150;
        int r = r2 / 50, cc = r2 % 50;
        int row = h - 1 + r, col = s2*48 - 1 + cc;
        float v = 0.f;
        if (row >= 0 && row < 96 && col >= 0 && col < 96)
            v = f1[(size_t)(img*64 + ci)*TOK + row*96 + col];
        sT[ci*156 + r*52 + cc] = v;
    }
    __syncthreads();

    int co = tid & 63, g = tid >> 6;
    int px0 = g * 12;
    float acc[12];
    float bb = b2f[co];
    #pragma unroll
    for (int j = 0; j < 12; ++j) acc[j] = bb;

    for (int ci = 0; ci < 64; ++ci) {
        float wv[9];
        #pragma unroll
        for (int t = 0; t < 9; ++t) wv[t] = w2t[(ci*9 + t)*64 + co];
        #pragma unroll
        for (int r = 0; r < 3; ++r) {
            const float4* tp4 = (const float4*)&sT[ci*156 + r*52 + px0];
            float4 a0 = tp4[0], a1 = tp4[1], a2 = tp4[2], a3 = tp4[3];
            float t16[16] = {a0.x,a0.y,a0.z,a0.w, a1.x,a1.y,a1.z,a1.w,
                             a2.x,a2.y,a2.z,a2.w, a3.x,a3.y,a3.z,a3.w};
            #pragma unroll
            for (int dw = 0; dw < 3; ++dw) {
                float wgt = wv[r*3 + dw];
                #pragma unroll
                for (int j = 0; j < 12; ++j) acc[j] += wgt * t16[j + dw];
            }
        }
    }
    int b = img >> 1, n = img & 1;
    _Float16* featH = (_Float16*)(ws + OFF_FEAT) + (size_t)b*TOK*128;
    int tbase = h*96 + s2*48 + px0;
    #pragma unroll
    for (int j = 0; j < 12; ++j)
        featH[(size_t)(tbase + j)*128 + co*2 + n] = (_Float16)fmaxf(acc[j], 0.f);
}

// ---------------- fused QKV GEMM (MFMA, all-register): feat f16 -> QT/KT/VH ----------------
__global__ __launch_bounds__(256) void qkvgemm_kernel(float* __restrict__ ws)
{
    int bid = blockIdx.x;            // 2 * 288
    int b   = bid / 288;
    int tt0 = (bid % 288) * 32;
    int tid = threadIdx.x;
    int lane = tid & 63, w = tid >> 6;
    int lr = lane & 15, lk = lane >> 4;

    const _Float16* featH = (const _Float16*)(ws + OFF_FEAT) + (size_t)b*TOK*128;
    const _Float16* W  = (const _Float16*)(ws + OFF_WCAT);
    const float* bc = ws + OFF_BCAT;
    _Float16* QT = (_Float16*)(ws + OFF_QT) + (size_t)b*TOK*64;
    _Float16* KT = (_Float16*)(ws + OFF_KT) + (size_t)b*TOK*64;
    _Float16* VH = (_Float16*)(ws + OFF_VH) + (size_t)b*64*TOK;

    half8 bf[2][4];
    #pragma unroll
    for (int tt = 0; tt < 2; ++tt)
        #pragma unroll
        for (int kc = 0; kc < 4; ++kc)
            bf[tt][kc] = *(const half8*)&featH[(size_t)(tt0 + tt*16 + lr)*128 + kc*32 + lk*8];

    half8 af[3][4];
    #pragma unroll
    for (int i = 0; i < 3; ++i)
        #pragma unroll
        for (int kc = 0; kc < 4; ++kc)
            af[i][kc] = *(const half8*)&W[(size_t)((w*3 + i)*16 + lr)*128 + kc*32 + lk*8];

    #pragma unroll
    for (int i = 0; i < 3; ++i) {
        int ot = w*3 + i;
        f32x4 a0, a1;
        #pragma unroll
        for (int r = 0; r < 4; ++r) {
            float bv = bc[ot*16 + 4*lk + r];
            a0[r] = bv; a1[r] = bv;
        }
        #pragma unroll
        for (int kc = 0; kc < 4; ++kc) {
            a0 = __builtin_amdgcn_mfma_f32_16x16x32_f16(af[i][kc], bf[0][kc], a0, 0, 0, 0);
            a1 = __builtin_amdgcn_mfma_f32_16x16x32_f16(af[i][kc], bf[1][kc], a1, 0, 0, 0);
        }
        #pragma unroll
        for (int tt = 0; tt < 2; ++tt) {
            f32x4 a = tt ? a1 : a0;
            int t = tt0 + tt*16 + lr;
            if (ot < 4) {
                union { _Float16 h[4]; uint2 u; } p;
                #pragma unroll
                for (int r = 0; r < 4; ++r) p.h[r] = (_Float16)a[r];
                *(uint2*)&QT[(size_t)t*64 + ot*16 + 4*lk] = p.u;
            } else if (ot < 8) {
                union { _Float16 h[4]; uint2 u; } p;
                #pragma unroll
                for (int r = 0; r < 4; ++r) p.h[r] = (_Float16)a[r];
                *(uint2*)&KT[(size_t)t*64 + (ot-4)*16 + 4*lk] = p.u;
            } else {
                #pragma unroll
                for (int r = 0; r < 4; ++r)
                    VH[(size_t)((ot-8)*16 + 4*lk + r)*TOK + t] = (_Float16)a[r];
            }
        }
    }
}

// ---------------- flash attention partial ----------------
// r13: zero-C S-init, max3 tree, defer-max THR=8, l via ones-row MFMA.
__global__ __launch_bounds__(256, 5) void attn_kernel(float* __restrict__ ws)
{
    __shared__ __align__(16) char smem[32768];   // K0 V0 | K1 V1 (dbuf)
    float* ldsf = (float*)smem;                  // epilogue reuse: [64 c][68] f32

    int bid = blockIdx.x;       // 2 * 144 * KSPLIT
    int b   = bid / (144*KSPLIT);
    int rem = bid % (144*KSPLIT);
    int qt  = rem / KSPLIT;
    int ks  = rem % KSPLIT;
    int tid = threadIdx.x;
    int lane = tid & 63, w = tid >> 6;
    int q0 = qt * 64;
    int lr = lane & 15;
    int lk = lane >> 4;

    int kb0 = (ks*144)/KSPLIT, kb1 = ((ks+1)*144)/KSPLIT;
    int nit = kb1 - kb0;
    int slab = b*KSPLIT + ks;

    const _Float16* Qt = (const _Float16*)(ws + OFF_QT) + (size_t)b*TOK*64;
    const _Float16* Kt = (const _Float16*)(ws + OFF_KT) + (size_t)b*TOK*64;
    const _Float16* Vh = (const _Float16*)(ws + OFF_VH) + (size_t)b*64*TOK;
    float* part = part_base(ws, slab);
    float* ml   = ws + OFF_ML2 + (size_t)slab*2*TOK;

    half8 qB[2];
    #pragma unroll
    for (int ch = 0; ch < 2; ++ch)
        qB[ch] = *(const half8*)&Qt[(size_t)(q0 + w*16 + lr)*64 + ch*32 + lk*8];

    const f32x4 Z4 = (f32x4){0.f, 0.f, 0.f, 0.f};
    half8 ones;
    #pragma unroll
    for (int i = 0; i < 8; ++i) ones[i] = (_Float16)1.0f;

    f32x4 O[4];
    #pragma unroll
    for (int cs = 0; cs < 4; ++cs) O[cs] = Z4;
    f32x4 lacc = Z4;                  // l via ones-row MFMA (all 4 rows equal)
    float mM = -INFINITY;

    int segl = ((lane & 7) ^ ((lane >> 3) & 7)) * 8;
    unsigned rbase = (unsigned)(w*16 + (lane >> 3));
    unsigned kOff = (unsigned)(kb0*64 + rbase)*64u + (unsigned)segl;
    unsigned vOff = rbase*(unsigned)TOK + (unsigned)(kb0*64) + (unsigned)segl;
    unsigned wk0 = (unsigned)(w * 2048);

    {
        char* bK = smem;
        char* bV = smem + 8192;
        GLOAD_LDS(Kt + kOff,           bK + wk0);
        GLOAD_LDS(Kt + kOff + 512,     bK + wk0 + 1024);
        GLOAD_LDS(Vh + vOff,           bV + wk0);
        GLOAD_LDS(Vh + vOff + 8u*TOK,  bV + wk0 + 1024);
    }
    asm volatile("s_waitcnt vmcnt(0)" ::: "memory");
    __builtin_amdgcn_s_barrier();

    for (int it = 0; it < nit; ++it) {
        char* sKb = smem + (it & 1) * 16384;
        char* sVb = sKb + 8192;
        char* sSt = smem + ((it + 1) & 1) * 16384;

        if (it + 1 < nit) {
            unsigned kN = kOff + (unsigned)(it + 1) * 4096u;
            unsigned vN = vOff + (unsigned)(it + 1) * 64u;
            GLOAD_LDS(Kt + kN,           sSt + wk0);
            GLOAD_LDS(Kt + kN + 512,     sSt + wk0 + 1024);
            GLOAD_LDS(Vh + vN,           sSt + 8192 + wk0);
            GLOAD_LDS(Vh + vN + 8u*TOK,  sSt + 8192 + wk0 + 1024);
        }

        // ---- QK^T swapped: S^T[kt 64][q 16]; zero-C init ----
        f32x4 S[4];
        __builtin_amdgcn_s_setprio(1);
        #pragma unroll
        for (int st = 0; st < 4; ++st) {
            int t = st*16 + lr;
            half8 kA0 = *(const half8*)(sKb + ((t*128 +       lk*16) ^ ((t&7)<<4)));
            half8 kA1 = *(const half8*)(sKb + ((t*128 + 64 +  lk*16) ^ ((t&7)<<4)));
            f32x4 s = __builtin_amdgcn_mfma_f32_16x16x32_f16(kA0, qB[0], Z4, 0, 0, 0);
            S[st]   = __builtin_amdgcn_mfma_f32_16x16x32_f16(kA1, qB[1], s,  0, 0, 0);
        }
        __builtin_amdgcn_s_setprio(0);

        // ---- row max via max3 tree ----
        float a0 = fmaxf(fmaxf(S[0][0], S[0][1]), S[0][2]);
        float a1 = fmaxf(fmaxf(S[0][3], S[1][0]), S[1][1]);
        float a2 = fmaxf(fmaxf(S[1][2], S[1][3]), S[2][0]);
        float a3 = fmaxf(fmaxf(S[2][1], S[2][2]), S[2][3]);
        float a4 = fmaxf(fmaxf(S[3][0], S[3][1]), S[3][2]);
        float pm = fmaxf(fmaxf(fmaxf(a0, a1), a2),
                         fmaxf(fmaxf(a3, a4), S[3][3]));
        pm = fmaxf(pm, __shfl_xor(pm, 16));
        pm = fmaxf(pm, __shfl_xor(pm, 32));

        // ---- defer-max: rescale only when max grew past THR=8 (exp2 domain) ----
        if (__any(pm > mM + 8.0f)) {
            float mn = fmaxf(mM, pm);
            float fs = exp2f(mM - mn);
            mM = mn;
            #pragma unroll
            for (int cs = 0; cs < 4; ++cs)
                #pragma unroll
                for (int r = 0; r < 4; ++r) O[cs][r] *= fs;
            #pragma unroll
            for (int r = 0; r < 4; ++r) lacc[r] *= fs;
        }

        // ---- p = exp2(S - mM); bounded by 2^8 ----
        #pragma unroll
        for (int st = 0; st < 4; ++st)
            #pragma unroll
            for (int r = 0; r < 4; ++r)
                S[st][r] = exp2f(S[st][r] - mM);

        // ---- pack P pairs ----
        unsigned int pk[4][2];
        #pragma unroll
        for (int st = 0; st < 4; ++st) {
            union { _Float16 h[2]; unsigned int u; } c0, c1;
            c0.h[0] = (_Float16)S[st][0]; c0.h[1] = (_Float16)S[st][1];
            c1.h[0] = (_Float16)S[st][2]; c1.h[1] = (_Float16)S[st][3];
            pk[st][0] = c0.u; pk[st][1] = c1.u;
        }

        // ---- PV swapped + l via ones-row MFMA ----
        int srcA = lr + 32*(lk & 1);
        int sel  = lk >> 1;
        __builtin_amdgcn_s_setprio(1);
        #pragma unroll
        for (int ch2 = 0; ch2 < 2; ++ch2) {
            union { unsigned int u[4]; half8 h; } pb;
            #pragma unroll
            for (int w2 = 0; w2 < 4; ++w2) {
                int src = srcA + 16*(w2 >> 1);
                int lo = __shfl((int)pk[ch2*2 + 0][w2 & 1], src);
                int hi = __shfl((int)pk[ch2*2 + 1][w2 & 1], src);
                pb.u[w2] = (unsigned int)(sel ? hi : lo);
            }
            lacc = __builtin_amdgcn_mfma_f32_16x16x32_f16(ones, pb.h, lacc, 0, 0, 0);
            #pragma unroll
            for (int cs = 0; cs < 4; ++cs) {
                int crow = cs*16 + lr;
                half8 vA = *(const half8*)(sVb + ((crow*128 + ch2*64 + lk*16) ^ ((crow&7)<<4)));
                O[cs] = __builtin_amdgcn_mfma_f32_16x16x32_f16(vA, pb.h, O[cs], 0, 0, 0);
            }
        }
        __builtin_amdgcn_s_setprio(0);

        asm volatile("s_waitcnt vmcnt(0)" ::: "memory");
        __builtin_amdgcn_s_barrier();
    }

    if (lk == 0) {
        ml[q0 + w*16 + lr]       = mM;
        ml[TOK + q0 + w*16 + lr] = lacc[0];
    }

    #pragma unroll
    for (int cs = 0; cs < 4; ++cs)
        #pragma unroll
        for (int r = 0; r < 4; ++r)
            ldsf[(cs*16 + 4*lk + r)*68 + w*16 + lr] = O[cs][r];
    __syncthreads();
    int c = tid >> 2, sg = tid & 3;
    const float* srcr = &ldsf[c*68 + sg*16];
    float* dstr = &part[(size_t)c*TOK + q0 + sg*16];
    #pragma unroll
    for (int j = 0; j < 4; ++j)
        *(float4*)&dstr[j*4] = *(const float4*)&srcr[j*4];
}

// ---------------- recombine KV-split partials (exp2 domain) ----------------
__global__ __launch_bounds__(256) void recombine_kernel(
    const float* __restrict__ ws, float* __restrict__ out)
{
    int gid = blockIdx.x * 256 + threadIdx.x;   // 2 * 4cg * TOK = 73728
    int b   = gid / (4*TOK);
    int rem = gid % (4*TOK);
    int cg  = rem / TOK;
    int t   = rem % TOK;
    const float* mlp = ws + OFF_ML2;

    float m[KSPLIT], l[KSPLIT];
    float M = -INFINITY;
    #pragma unroll
    for (int ks = 0; ks < KSPLIT; ++ks) {
        int slab = b*KSPLIT + ks;
        m[ks] = mlp[(size_t)slab*2*TOK + t];
        l[ks] = mlp[(size_t)slab*2*TOK + TOK + t];
        M = fmaxf(M, m[ks]);
    }
    float wgt[KSPLIT];
    float denom = 0.f;
    #pragma unroll
    for (int ks = 0; ks < KSPLIT; ++ks) {
        wgt[ks] = exp2f(m[ks] - M);
        denom += l[ks] * wgt[ks];
    }
    float inv = 1.f / denom;
    #pragma unroll
    for (int cc = 0; cc < 16; ++cc) {
        int c = cg*16 + cc;
        float acc = 0.f;
        #pragma unroll
        for (int ks = 0; ks < KSPLIT; ++ks) {
            const float* part = part_base_c(ws, b*KSPLIT + ks);
            acc += part[(size_t)c*TOK + t] * wgt[ks];
        }
        out[(size_t)(b*64 + c)*TOK + t] = acc * inv;
    }
}

extern "C" void kernel_launch(void* const* d_in, const int* in_sizes, int n_in,
                              void* d_out, int out_size, void* d_ws, size_t ws_size,
                              hipStream_t stream)
{
    const float* frames = (const float*)d_in[0];
    const float* w1 = (const float*)d_in[1];
    const float* b1 = (const float*)d_in[2];
    const float* w2 = (const float*)d_in[3];
    const float* b2 = (const float*)d_in[4];
    const float* qw = (const float*)d_in[5];
    const float* qb = (const float*)d_in[6];
    const float* kw = (const float*)d_in[7];
    const float* kb = (const float*)d_in[8];
    const float* vw = (const float*)d_in[9];
    const float* vb = (const float*)d_in[10];
    float* ws = (float*)d_ws;
    float* out = (float*)d_out;

    hipLaunchKernelGGL(prep_kernel, dim3(144), dim3(256), 0, stream,
                       w1, b1, w2, b2, qw, qb, kw, kb, vw, vb, ws);
    hipLaunchKernelGGL(conv1_kernel, dim3(144), dim3(256), 0, stream, frames, ws);
    hipLaunchKernelGGL(conv2_kernel, dim3(768), dim3(256), 0, stream, ws);
    hipLaunchKernelGGL(qkvgemm_kernel, dim3(576), dim3(256), 0, stream, ws);
    hipLaunchKernelGGL(attn_kernel, dim3(2*144*KSPLIT), dim3(256), 0, stream, ws);
    hipLaunchKernelGGL(recombine_kernel, dim3(288), dim3(256), 0, stream, ws, out);
}

// Round 14
// 175.741 us; speedup vs baseline: 2.9495x; 1.1872x over previous
//
#include <hip/hip_runtime.h>
#include <hip/hip_bf16.h>

#define TOK 9216   // 96*96 tokens per image
#define KSPLIT 5

typedef _Float16 half8 __attribute__((ext_vector_type(8)));
typedef float f32x4 __attribute__((ext_vector_type(4)));

// global_load_lds: 16B per lane, linear LDS dest (wave-uniform base + lane*16)
#define GLOAD_LDS(g, l) \
    __builtin_amdgcn_global_load_lds((const __attribute__((address_space(1))) void*)(g), \
                                     (__attribute__((address_space(3))) void*)(l), 16, 0, 0)

#define QSCALE 0.18033688011112042f   // 0.125 * log2(e); softmax runs in exp2 domain

// ---------------- workspace layout (in floats) ----------------
#define OFF_F1   0u                      // conv1 out: f16 [img][t][64] (1.18M f32 slots)
#define SZ_F1    (4u*64u*TOK)
#define OFF_FEAT (OFF_F1 + SZ_F1)        // conv2 out: f16 [b][n][t][64] (1.18M f32 slots)
#define SZ_FEAT  (2u*128u*TOK)
#define OFF_Q    (OFF_FEAT + SZ_FEAT)    // (dead f32 regions, kept for slab math)
#define SZ_QKV   (2u*64u*TOK)
#define OFF_K    (OFF_Q + SZ_QKV)
#define OFF_V    (OFF_K + SZ_QKV)
#define OFF_W1   (OFF_V + SZ_QKV)        // [64][9] f32
#define OFF_B1   (OFF_W1 + 576u)
#define OFF_W2T  (OFF_B1 + 64u)          // WCONV f16 [64 co][576 k], k=tap*64+ci
#define OFF_B2   (OFF_W2T + 36864u)
#define OFF_WCAT (OFF_B2 + 64u)          // [192][128] f16, col k = n*64+c (q rows scaled)
#define OFF_BCAT (OFF_WCAT + 24576u)     // [192] f32 (qb scaled)

// f16 QKV overlaid on F1 (f1h dead after conv2). Offsets in f32 units.
#define OFF_QT   OFF_F1                  // [b][t][64] f16, scale folded
#define OFF_KT   (OFF_F1 + 589824u)      // [b][t][64] f16
#define OFF_VH   (OFF_F1 + 1179648u)     // [b][64][t] f16, ends at 1769472

// KV-split partials: 10 slabs of 64*TOK f32 each (589824 floats).
#define OFF_SLAB0 1769472u
#define OFF_ML2   (OFF_FEAT + 9u*589824u)   // [slab][2 (m,l)][TOK] f32

__device__ __forceinline__ const float* part_base_c(const float* ws, int slab) {
    return ws + (slab == 0 ? OFF_SLAB0 : (OFF_FEAT + (unsigned)(slab - 1) * 589824u));
}
__device__ __forceinline__ float* part_base(float* ws, int slab) {
    return ws + (slab == 0 ? OFF_SLAB0 : (OFF_FEAT + (unsigned)(slab - 1) * 589824u));
}

// ---------------- weight prep ----------------
__global__ __launch_bounds__(256) void prep_kernel(
    const float* __restrict__ w1, const float* __restrict__ b1,
    const float* __restrict__ w2, const float* __restrict__ b2,
    const float* __restrict__ qw, const float* __restrict__ qb,
    const float* __restrict__ kw, const float* __restrict__ kb,
    const float* __restrict__ vw, const float* __restrict__ vb,
    float* __restrict__ ws)
{
    int gid = blockIdx.x * 256 + threadIdx.x;
    if (gid < 576) ws[OFF_W1 + gid] = w1[gid];
    if (gid < 64) {
        ws[OFF_B1 + gid] = b1[gid];
        ws[OFF_B2 + gid] = b2[gid];
    }
    if (gid < 36864) {   // WCONV f16: [co][tap*64+ci] <- w2[co][ci][tap]
        int co = gid / 576; int rem = gid % 576;
        int ci = rem / 9;  int tp = rem % 9;
        ((_Float16*)(ws + OFF_W2T))[co*576 + tp*64 + ci] = (_Float16)w2[gid];
    }
    if (gid < 24576) {   // WCAT f16, col k = n*64+c <- source col c*2+n; q rows scaled
        int o = gid >> 7; int kidx = gid & 127;
        int n = kidx >> 6, c = kidx & 63;
        int sc = c*2 + n;
        float v;
        if (o < 64)       v = qw[o*128 + sc] * QSCALE;
        else if (o < 128) v = kw[(o-64)*128 + sc];
        else              v = vw[(o-128)*128 + sc];
        ((_Float16*)(ws + OFF_WCAT))[gid] = (_Float16)v;
    }
    if (gid < 192) {
        float v;
        if (gid < 64)       v = qb[gid] * QSCALE;
        else if (gid < 128) v = kb[gid-64];
        else                v = vb[gid-128];
        ws[OFF_BCAT + gid] = v;
    }
}

// ---------------- conv1: 1->64 ch, 3x3, relu; writes f16 channel-last ----------------
__global__ __launch_bounds__(256) void conv1_kernel(
    const float* __restrict__ x, float* __restrict__ ws)
{
    const float* w1f = ws + OFF_W1;
    const float* b1f = ws + OFF_B1;
    _Float16* f1h = (_Float16*)(ws + OFF_F1);
    int gid = blockIdx.x * 256 + threadIdx.x;   // 4*9216
    int img = gid / TOK;
    int p   = gid % TOK;
    int h = p / 96, w = p % 96;
    float xv[9];
    #pragma unroll
    for (int dh = 0; dh < 3; ++dh)
        #pragma unroll
        for (int dw = 0; dw < 3; ++dw) {
            int r = h + dh - 1, c = w + dw - 1;
            bool ok = (r >= 0) && (r < 96) && (c >= 0) && (c < 96);
            xv[dh*3 + dw] = ok ? x[img*TOK + r*96 + c] : 0.f;
        }
    _Float16* dst = f1h + (size_t)gid * 64;     // [img][p][64], 128B contiguous
    #pragma unroll
    for (int g8 = 0; g8 < 8; ++g8) {
        union { _Float16 h[8]; uint4 u; } pk8;
        #pragma unroll
        for (int j = 0; j < 8; ++j) {
            int co = g8*8 + j;
            float a = b1f[co];
            #pragma unroll
            for (int t = 0; t < 9; ++t) a += w1f[co*9 + t] * xv[t];
            pk8.h[j] = (_Float16)fmaxf(a, 0.f);
        }
        *(uint4*)&dst[g8*8] = pk8.u;
    }
}

// ---------------- conv2 as MFMA im2col GEMM: f1h -> featH2 [img][t][64] ----------------
// grid = 4 img x 144 token-tiles(64); 256 thr = 4 waves x 16 tokens.
// A = im2col patches (rows=tokens, k=tap*64+ci, 16B contiguous in f1h, halo->0),
// B = WCONV (cols=co), D[t][co]; bias C-init; relu on store.
__global__ __launch_bounds__(256) void conv2_kernel(float* __restrict__ ws)
{
    int bid = blockIdx.x;            // 4 img * 144
    int img = bid & 3;
    int tile = bid >> 2;
    int tid = threadIdx.x;
    int lane = tid & 63, w = tid >> 6;
    int lr = lane & 15, lk = lane >> 4;

    const _Float16* f1h = (const _Float16*)(ws + OFF_F1) + (size_t)img*TOK*64;
    const _Float16* Wc  = (const _Float16*)(ws + OFF_W2T);   // [64][576]
    const float* b2f = ws + OFF_B2;

    int t = tile*64 + w*16 + lr;
    int h = t / 96, wc = t % 96;

    half8 z8;
    #pragma unroll
    for (int i = 0; i < 8; ++i) z8[i] = (_Float16)0.f;

    f32x4 acc[4];
    #pragma unroll
    for (int cs = 0; cs < 4; ++cs) {
        float bv = b2f[cs*16 + lr];
        acc[cs] = (f32x4){bv, bv, bv, bv};
    }

    #pragma unroll
    for (int ch = 0; ch < 18; ++ch) {
        int k = ch*32 + lk*8;
        int tap = k >> 6, ci = k & 63;
        int dh = tap / 3, dw = tap % 3;
        int r = h + dh - 1, c = wc + dw - 1;
        half8 af = z8;
        if ((unsigned)r < 96u && (unsigned)c < 96u)
            af = *(const half8*)&f1h[(size_t)(r*96 + c)*64 + ci];
        #pragma unroll
        for (int cs = 0; cs < 4; ++cs) {
            half8 bfr = *(const half8*)&Wc[(size_t)(cs*16 + lr)*576 + k];
            acc[cs] = __builtin_amdgcn_mfma_f32_16x16x32_f16(af, bfr, acc[cs], 0, 0, 0);
        }
    }

    // D: row t = tbase + reg, col co = cs*16 + lr (16-lane-contiguous stores)
    _Float16* featH2 = (_Float16*)(ws + OFF_FEAT) + (size_t)img*TOK*64;
    int tbase = tile*64 + w*16 + 4*lk;
    #pragma unroll
    for (int cs = 0; cs < 4; ++cs)
        #pragma unroll
        for (int r = 0; r < 4; ++r)
            featH2[(size_t)(tbase + r)*64 + cs*16 + lr] = (_Float16)fmaxf(acc[cs][r], 0.f);
}

// ---------------- fused QKV GEMM (MFMA, all-register): featH2 -> QT/KT/VH ----------------
__global__ __launch_bounds__(256) void qkvgemm_kernel(float* __restrict__ ws)
{
    int bid = blockIdx.x;            // 2 * 288
    int b   = bid / 288;
    int tt0 = (bid % 288) * 32;
    int tid = threadIdx.x;
    int lane = tid & 63, w = tid >> 6;
    int lr = lane & 15, lk = lane >> 4;

    const _Float16* fH = (const _Float16*)(ws + OFF_FEAT) + (size_t)b*2*TOK*64;
    const _Float16* W  = (const _Float16*)(ws + OFF_WCAT);
    const float* bc = ws + OFF_BCAT;
    _Float16* QT = (_Float16*)(ws + OFF_QT) + (size_t)b*TOK*64;
    _Float16* KT = (_Float16*)(ws + OFF_KT) + (size_t)b*TOK*64;
    _Float16* VH = (_Float16*)(ws + OFF_VH) + (size_t)b*64*TOK;

    // B frags: k = kc*32 + lk*8 -> plane n = k>>6, ci = k&63 (16B contiguous)
    half8 bf[2][4];
    #pragma unroll
    for (int tt = 0; tt < 2; ++tt)
        #pragma unroll
        for (int kc = 0; kc < 4; ++kc) {
            int k = kc*32 + lk*8;
            bf[tt][kc] = *(const half8*)&fH[(size_t)(k >> 6)*TOK*64
                                            + (size_t)(tt0 + tt*16 + lr)*64 + (k & 63)];
        }

    half8 af[3][4];
    #pragma unroll
    for (int i = 0; i < 3; ++i)
        #pragma unroll
        for (int kc = 0; kc < 4; ++kc)
            af[i][kc] = *(const half8*)&W[(size_t)((w*3 + i)*16 + lr)*128 + kc*32 + lk*8];

    #pragma unroll
    for (int i = 0; i < 3; ++i) {
        int ot = w*3 + i;
        f32x4 a0, a1;
        #pragma unroll
        for (int r = 0; r < 4; ++r) {
            float bv = bc[ot*16 + 4*lk + r];
            a0[r] = bv; a1[r] = bv;
        }
        #pragma unroll
        for (int kc = 0; kc < 4; ++kc) {
            a0 = __builtin_amdgcn_mfma_f32_16x16x32_f16(af[i][kc], bf[0][kc], a0, 0, 0, 0);
            a1 = __builtin_amdgcn_mfma_f32_16x16x32_f16(af[i][kc], bf[1][kc], a1, 0, 0, 0);
        }
        #pragma unroll
        for (int tt = 0; tt < 2; ++tt) {
            f32x4 a = tt ? a1 : a0;
            int t = tt0 + tt*16 + lr;
            if (ot < 4) {
                union { _Float16 h[4]; uint2 u; } p;
                #pragma unroll
                for (int r = 0; r < 4; ++r) p.h[r] = (_Float16)a[r];
                *(uint2*)&QT[(size_t)t*64 + ot*16 + 4*lk] = p.u;
            } else if (ot < 8) {
                union { _Float16 h[4]; uint2 u; } p;
                #pragma unroll
                for (int r = 0; r < 4; ++r) p.h[r] = (_Float16)a[r];
                *(uint2*)&KT[(size_t)t*64 + (ot-4)*16 + 4*lk] = p.u;
            } else {
                #pragma unroll
                for (int r = 0; r < 4; ++r)
                    VH[(size_t)((ot-8)*16 + 4*lk + r)*TOK + t] = (_Float16)a[r];
            }
        }
    }
}

// ---------------- flash attention partial (frozen from round 13) ----------------
__global__ __launch_bounds__(256, 5) void attn_kernel(float* __restrict__ ws)
{
    __shared__ __align__(16) char smem[32768];   // K0 V0 | K1 V1 (dbuf)
    float* ldsf = (float*)smem;                  // epilogue reuse: [64 c][68] f32

    int bid = blockIdx.x;       // 2 * 144 * KSPLIT
    int b   = bid / (144*KSPLIT);
    int rem = bid % (144*KSPLIT);
    int qt  = rem / KSPLIT;
    int ks  = rem % KSPLIT;
    int tid = threadIdx.x;
    int lane = tid & 63, w = tid >> 6;
    int q0 = qt * 64;
    int lr = lane & 15;
    int lk = lane >> 4;

    int kb0 = (ks*144)/KSPLIT, kb1 = ((ks+1)*144)/KSPLIT;
    int nit = kb1 - kb0;
    int slab = b*KSPLIT + ks;

    const _Float16* Qt = (const _Float16*)(ws + OFF_QT) + (size_t)b*TOK*64;
    const _Float16* Kt = (const _Float16*)(ws + OFF_KT) + (size_t)b*TOK*64;
    const _Float16* Vh = (const _Float16*)(ws + OFF_VH) + (size_t)b*64*TOK;
    float* part = part_base(ws, slab);
    float* ml   = ws + OFF_ML2 + (size_t)slab*2*TOK;

    half8 qB[2];
    #pragma unroll
    for (int ch = 0; ch < 2; ++ch)
        qB[ch] = *(const half8*)&Qt[(size_t)(q0 + w*16 + lr)*64 + ch*32 + lk*8];

    const f32x4 Z4 = (f32x4){0.f, 0.f, 0.f, 0.f};
    half8 ones;
    #pragma unroll
    for (int i = 0; i < 8; ++i) ones[i] = (_Float16)1.0f;

    f32x4 O[4];
    #pragma unroll
    for (int cs = 0; cs < 4; ++cs) O[cs] = Z4;
    f32x4 lacc = Z4;
    float mM = -INFINITY;

    int segl = ((lane & 7) ^ ((lane >> 3) & 7)) * 8;
    unsigned rbase = (unsigned)(w*16 + (lane >> 3));
    unsigned kOff = (unsigned)(kb0*64 + rbase)*64u + (unsigned)segl;
    unsigned vOff = rbase*(unsigned)TOK + (unsigned)(kb0*64) + (unsigned)segl;
    unsigned wk0 = (unsigned)(w * 2048);

    {
        char* bK = smem;
        char* bV = smem + 8192;
        GLOAD_LDS(Kt + kOff,           bK + wk0);
        GLOAD_LDS(Kt + kOff + 512,     bK + wk0 + 1024);
        GLOAD_LDS(Vh + vOff,           bV + wk0);
        GLOAD_LDS(Vh + vOff + 8u*TOK,  bV + wk0 + 1024);
    }
    asm volatile("s_waitcnt vmcnt(0)" ::: "memory");
    __builtin_amdgcn_s_barrier();

    for (int it = 0; it < nit; ++it) {
        char* sKb = smem + (it & 1) * 16384;
        char* sVb = sKb + 8192;
        char* sSt = smem + ((it + 1) & 1) * 16384;

        if (it + 1 < nit) {
            unsigned kN = kOff + (unsigned)(it + 1) * 4096u;
            unsigned vN = vOff + (unsigned)(it + 1) * 64u;
            GLOAD_LDS(Kt + kN,           sSt + wk0);
            GLOAD_LDS(Kt + kN + 512,     sSt + wk0 + 1024);
            GLOAD_LDS(Vh + vN,           sSt + 8192 + wk0);
            GLOAD_LDS(Vh + vN + 8u*TOK,  sSt + 8192 + wk0 + 1024);
        }

        f32x4 S[4];
        __builtin_amdgcn_s_setprio(1);
        #pragma unroll
        for (int st = 0; st < 4; ++st) {
            int t = st*16 + lr;
            half8 kA0 = *(const half8*)(sKb + ((t*128 +       lk*16) ^ ((t&7)<<4)));
            half8 kA1 = *(const half8*)(sKb + ((t*128 + 64 +  lk*16) ^ ((t&7)<<4)));
            f32x4 s = __builtin_amdgcn_mfma_f32_16x16x32_f16(kA0, qB[0], Z4, 0, 0, 0);
            S[st]   = __builtin_amdgcn_mfma_f32_16x16x32_f16(kA1, qB[1], s,  0, 0, 0);
        }
        __builtin_amdgcn_s_setprio(0);

        float a0 = fmaxf(fmaxf(S[0][0], S[0][1]), S[0][2]);
        float a1 = fmaxf(fmaxf(S[0][3], S[1][0]), S[1][1]);
        float a2 = fmaxf(fmaxf(S[1][2], S[1][3]), S[2][0]);
        float a3 = fmaxf(fmaxf(S[2][1], S[2][2]), S[2][3]);
        float a4 = fmaxf(fmaxf(S[3][0], S[3][1]), S[3][2]);
        float pm = fmaxf(fmaxf(fmaxf(a0, a1), a2),
                         fmaxf(fmaxf(a3, a4), S[3][3]));
        pm = fmaxf(pm, __shfl_xor(pm, 16));
        pm = fmaxf(pm, __shfl_xor(pm, 32));

        if (__any(pm > mM + 8.0f)) {
            float mn = fmaxf(mM, pm);
            float fs = exp2f(mM - mn);
            mM = mn;
            #pragma unroll
            for (int cs = 0; cs < 4; ++cs)
                #pragma unroll
                for (int r = 0; r < 4; ++r) O[cs][r] *= fs;
            #pragma unroll
            for (int r = 0; r < 4; ++r) lacc[r] *= fs;
        }

        #pragma unroll
        for (int st = 0; st < 4; ++st)
            #pragma unroll
            for (int r = 0; r < 4; ++r)
                S[st][r] = exp2f(S[st][r] - mM);

        unsigned int pk[4][2];
        #pragma unroll
        for (int st = 0; st < 4; ++st) {
            union { _Float16 h[2]; unsigned int u; } c0, c1;
            c0.h[0] = (_Float16)S[st][0]; c0.h[1] = (_Float16)S[st][1];
            c1.h[0] = (_Float16)S[st][2]; c1.h[1] = (_Float16)S[st][3];
            pk[st][0] = c0.u; pk[st][1] = c1.u;
        }

        int srcA = lr + 32*(lk & 1);
        int sel  = lk >> 1;
        __builtin_amdgcn_s_setprio(1);
        #pragma unroll
        for (int ch2 = 0; ch2 < 2; ++ch2) {
            union { unsigned int u[4]; half8 h; } pb;
            #pragma unroll
            for (int w2 = 0; w2 < 4; ++w2) {
                int src = srcA + 16*(w2 >> 1);
                int lo = __shfl((int)pk[ch2*2 + 0][w2 & 1], src);
                int hi = __shfl((int)pk[ch2*2 + 1][w2 & 1], src);
                pb.u[w2] = (unsigned int)(sel ? hi : lo);
            }
            lacc = __builtin_amdgcn_mfma_f32_16x16x32_f16(ones, pb.h, lacc, 0, 0, 0);
            #pragma unroll
            for (int cs = 0; cs < 4; ++cs) {
                int crow = cs*16 + lr;
                half8 vA = *(const half8*)(sVb + ((crow*128 + ch2*64 + lk*16) ^ ((crow&7)<<4)));
                O[cs] = __builtin_amdgcn_mfma_f32_16x16x32_f16(vA, pb.h, O[cs], 0, 0, 0);
            }
        }
        __builtin_amdgcn_s_setprio(0);

        asm volatile("s_waitcnt vmcnt(0)" ::: "memory");
        __builtin_amdgcn_s_barrier();
    }

    if (lk == 0) {
        ml[q0 + w*16 + lr]       = mM;
        ml[TOK + q0 + w*16 + lr] = lacc[0];
    }

    #pragma unroll
    for (int cs = 0; cs < 4; ++cs)
        #pragma unroll
        for (int r = 0; r < 4; ++r)
            ldsf[(cs*16 + 4*lk + r)*68 + w*16 + lr] = O[cs][r];
    __syncthreads();
    int c = tid >> 2, sg = tid & 3;
    const float* srcr = &ldsf[c*68 + sg*16];
    float* dstr = &part[(size_t)c*TOK + q0 + sg*16];
    #pragma unroll
    for (int j = 0; j < 4; ++j)
        *(float4*)&dstr[j*4] = *(const float4*)&srcr[j*4];
}

// ---------------- recombine KV-split partials (exp2 domain) ----------------
__global__ __launch_bounds__(256) void recombine_kernel(
    const float* __restrict__ ws, float* __restrict__ out)
{
    int gid = blockIdx.x * 256 + threadIdx.x;   // 2 * 4cg * TOK = 73728
    int b   = gid / (4*TOK);
    int rem = gid % (4*TOK);
    int cg  = rem / TOK;
    int t   = rem % TOK;
    const float* mlp = ws + OFF_ML2;

    float m[KSPLIT], l[KSPLIT];
    float M = -INFINITY;
    #pragma unroll
    for (int ks = 0; ks < KSPLIT; ++ks) {
        int slab = b*KSPLIT + ks;
        m[ks] = mlp[(size_t)slab*2*TOK + t];
        l[ks] = mlp[(size_t)slab*2*TOK + TOK + t];
        M = fmaxf(M, m[ks]);
    }
    float wgt[KSPLIT];
    float denom = 0.f;
    #pragma unroll
    for (int ks = 0; ks < KSPLIT; ++ks) {
        wgt[ks] = exp2f(m[ks] - M);
        denom += l[ks] * wgt[ks];
    }
    float inv = 1.f / denom;
    #pragma unroll
    for (int cc = 0; cc < 16; ++cc) {
        int c = cg*16 + cc;
        float acc = 0.f;
        #pragma unroll
        for (int ks = 0; ks < KSPLIT; ++ks) {
            const float* part = part_base_c(ws, b*KSPLIT + ks);
            acc += part[(size_t)c*TOK + t] * wgt[ks];
        }
        out[(size_t)(b*64 + c)*TOK + t] = acc * inv;
    }
}

extern "C" void kernel_launch(void* const* d_in, const int* in_sizes, int n_in,
                              void* d_out, int out_size, void* d_ws, size_t ws_size,
                              hipStream_t stream)
{
    const float* frames = (const float*)d_in[0];
    const float* w1 = (const float*)d_in[1];
    const float* b1 = (const float*)d_in[2];
    const float* w2 = (const float*)d_in[3];
    const float* b2 = (const float*)d_in[4];
    const float* qw = (const float*)d_in[5];
    const float* qb = (const float*)d_in[6];
    const float* kw = (const float*)d_in[7];
    const float* kb = (const float*)d_in[8];
    const float* vw = (const float*)d_in[9];
    const float* vb = (const float*)d_in[10];
    float* ws = (float*)d_ws;
    float* out = (float*)d_out;

    hipLaunchKernelGGL(prep_kernel, dim3(144), dim3(256), 0, stream,
                       w1, b1, w2, b2, qw, qb, kw, kb, vw, vb, ws);
    hipLaunchKernelGGL(conv1_kernel, dim3(144), dim3(256), 0, stream, frames, ws);
    hipLaunchKernelGGL(conv2_kernel, dim3(576), dim3(256), 0, stream, ws);
    hipLaunchKernelGGL(qkvgemm_kernel, dim3(576), dim3(256), 0, stream, ws);
    hipLaunchKernelGGL(attn_kernel, dim3(2*144*KSPLIT), dim3(256), 0, stream, ws);
    hipLaunchKernelGGL(recombine_kernel, dim3(288), dim3(256), 0, stream, ws, out);
}

// Round 15
// 175.448 us; speedup vs baseline: 2.9544x; 1.0017x over previous
//
#include <hip/hip_runtime.h>
#include <hip/hip_bf16.h>

#define TOK 9216   // 96*96 tokens per image
#define KSPLIT 5

typedef _Float16 half8 __attribute__((ext_vector_type(8)));
typedef float f32x4 __attribute__((ext_vector_type(4)));

// global_load_lds: 16B per lane, linear LDS dest (wave-uniform base + lane*16)
#define GLOAD_LDS(g, l) \
    __builtin_amdgcn_global_load_lds((const __attribute__((address_space(1))) void*)(g), \
                                     (__attribute__((address_space(3))) void*)(l), 16, 0, 0)

#define QSCALE 0.18033688011112042f   // 0.125 * log2(e); softmax runs in exp2 domain

// ---------------- workspace layout (in floats) ----------------
#define OFF_F1   0u                      // conv1 out: f16 [img][t][64] (1.18M f32 slots)
#define SZ_F1    (4u*64u*TOK)
#define OFF_FEAT (OFF_F1 + SZ_F1)        // conv2 out: f16 [b][n][t][64] (1.18M f32 slots)
#define SZ_FEAT  (2u*128u*TOK)
#define OFF_Q    (OFF_FEAT + SZ_FEAT)    // (dead f32 regions, kept for slab math)
#define SZ_QKV   (2u*64u*TOK)
#define OFF_K    (OFF_Q + SZ_QKV)
#define OFF_V    (OFF_K + SZ_QKV)
#define OFF_W1   (OFF_V + SZ_QKV)        // [64][9] f32
#define OFF_B1   (OFF_W1 + 576u)
#define OFF_W2T  (OFF_B1 + 64u)          // WCONV f16 [64 co][576 k], k=tap*64+ci
#define OFF_B2   (OFF_W2T + 36864u)
#define OFF_WCAT (OFF_B2 + 64u)          // [192][128] f16, col k = n*64+c (q rows scaled)
#define OFF_BCAT (OFF_WCAT + 24576u)     // [192] f32 (qb scaled)

// f16 QKV overlaid on F1 (f1h dead after conv2). Offsets in f32 units.
#define OFF_QT   OFF_F1                  // [b][t][64] f16, scale folded
#define OFF_KT   (OFF_F1 + 589824u)      // [b][t][64] f16
#define OFF_VH   (OFF_F1 + 1179648u)     // [b][64][t] f16, ends at 1769472

// KV-split partials: 10 slabs of 64*TOK f32 each (589824 floats).
#define OFF_SLAB0 1769472u
#define OFF_ML2   (OFF_FEAT + 9u*589824u)   // [slab][2 (m,l)][TOK] f32

__device__ __forceinline__ const float* part_base_c(const float* ws, int slab) {
    return ws + (slab == 0 ? OFF_SLAB0 : (OFF_FEAT + (unsigned)(slab - 1) * 589824u));
}
__device__ __forceinline__ float* part_base(float* ws, int slab) {
    return ws + (slab == 0 ? OFF_SLAB0 : (OFF_FEAT + (unsigned)(slab - 1) * 589824u));
}

// ---------------- weight prep ----------------
__global__ __launch_bounds__(256) void prep_kernel(
    const float* __restrict__ w1, const float* __restrict__ b1,
    const float* __restrict__ w2, const float* __restrict__ b2,
    const float* __restrict__ qw, const float* __restrict__ qb,
    const float* __restrict__ kw, const float* __restrict__ kb,
    const float* __restrict__ vw, const float* __restrict__ vb,
    float* __restrict__ ws)
{
    int gid = blockIdx.x * 256 + threadIdx.x;
    if (gid < 576) ws[OFF_W1 + gid] = w1[gid];
    if (gid < 64) {
        ws[OFF_B1 + gid] = b1[gid];
        ws[OFF_B2 + gid] = b2[gid];
    }
    if (gid < 36864) {   // WCONV f16: [co][tap*64+ci] <- w2[co][ci][tap]
        int co = gid / 576; int rem = gid % 576;
        int ci = rem / 9;  int tp = rem % 9;
        ((_Float16*)(ws + OFF_W2T))[co*576 + tp*64 + ci] = (_Float16)w2[gid];
    }
    if (gid < 24576) {   // WCAT f16, col k = n*64+c <- source col c*2+n; q rows scaled
        int o = gid >> 7; int kidx = gid & 127;
        int n = kidx >> 6, c = kidx & 63;
        int sc = c*2 + n;
        float v;
        if (o < 64)       v = qw[o*128 + sc] * QSCALE;
        else if (o < 128) v = kw[(o-64)*128 + sc];
        else              v = vw[(o-128)*128 + sc];
        ((_Float16*)(ws + OFF_WCAT))[gid] = (_Float16)v;
    }
    if (gid < 192) {
        float v;
        if (gid < 64)       v = qb[gid] * QSCALE;
        else if (gid < 128) v = kb[gid-64];
        else                v = vb[gid-128];
        ws[OFF_BCAT + gid] = v;
    }
}

// ---------------- conv1: 1->64 ch, 3x3, relu; writes f16 channel-last ----------------
__global__ __launch_bounds__(256) void conv1_kernel(
    const float* __restrict__ x, float* __restrict__ ws)
{
    const float* w1f = ws + OFF_W1;
    const float* b1f = ws + OFF_B1;
    _Float16* f1h = (_Float16*)(ws + OFF_F1);
    int gid = blockIdx.x * 256 + threadIdx.x;   // 4*9216
    int img = gid / TOK;
    int p   = gid % TOK;
    int h = p / 96, w = p % 96;
    float xv[9];
    #pragma unroll
    for (int dh = 0; dh < 3; ++dh)
        #pragma unroll
        for (int dw = 0; dw < 3; ++dw) {
            int r = h + dh - 1, c = w + dw - 1;
            bool ok = (r >= 0) && (r < 96) && (c >= 0) && (c < 96);
            xv[dh*3 + dw] = ok ? x[img*TOK + r*96 + c] : 0.f;
        }
    _Float16* dst = f1h + (size_t)gid * 64;     // [img][p][64], 128B contiguous
    #pragma unroll
    for (int g8 = 0; g8 < 8; ++g8) {
        union { _Float16 h[8]; uint4 u; } pk8;
        #pragma unroll
        for (int j = 0; j < 8; ++j) {
            int co = g8*8 + j;
            float a = b1f[co];
            #pragma unroll
            for (int t = 0; t < 9; ++t) a += w1f[co*9 + t] * xv[t];
            pk8.h[j] = (_Float16)fmaxf(a, 0.f);
        }
        *(uint4*)&dst[g8*8] = pk8.u;
    }
}

// ---------------- conv2 as MFMA im2col GEMM: f1h -> featH2 [img][t][64] ----------------
// grid = 4 img x 144 token-tiles(64); 256 thr = 4 waves x 16 tokens.
// A = im2col patches (rows=tokens, k=tap*64+ci, 16B contiguous in f1h, halo->0),
// B = WCONV (cols=co), D[t][co]; bias C-init; relu on store.
__global__ __launch_bounds__(256) void conv2_kernel(float* __restrict__ ws)
{
    int bid = blockIdx.x;            // 4 img * 144
    int img = bid & 3;
    int tile = bid >> 2;
    int tid = threadIdx.x;
    int lane = tid & 63, w = tid >> 6;
    int lr = lane & 15, lk = lane >> 4;

    const _Float16* f1h = (const _Float16*)(ws + OFF_F1) + (size_t)img*TOK*64;
    const _Float16* Wc  = (const _Float16*)(ws + OFF_W2T);   // [64][576]
    const float* b2f = ws + OFF_B2;

    int t = tile*64 + w*16 + lr;
    int h = t / 96, wc = t % 96;

    half8 z8;
    #pragma unroll
    for (int i = 0; i < 8; ++i) z8[i] = (_Float16)0.f;

    f32x4 acc[4];
    #pragma unroll
    for (int cs = 0; cs < 4; ++cs) {
        float bv = b2f[cs*16 + lr];
        acc[cs] = (f32x4){bv, bv, bv, bv};
    }

    #pragma unroll
    for (int ch = 0; ch < 18; ++ch) {
        int k = ch*32 + lk*8;
        int tap = k >> 6, ci = k & 63;
        int dh = tap / 3, dw = tap % 3;
        int r = h + dh - 1, c = wc + dw - 1;
        half8 af = z8;
        if ((unsigned)r < 96u && (unsigned)c < 96u)
            af = *(const half8*)&f1h[(size_t)(r*96 + c)*64 + ci];
        #pragma unroll
        for (int cs = 0; cs < 4; ++cs) {
            half8 bfr = *(const half8*)&Wc[(size_t)(cs*16 + lr)*576 + k];
            acc[cs] = __builtin_amdgcn_mfma_f32_16x16x32_f16(af, bfr, acc[cs], 0, 0, 0);
        }
    }

    // D: row t = tbase + reg, col co = cs*16 + lr (16-lane-contiguous stores)
    _Float16* featH2 = (_Float16*)(ws + OFF_FEAT) + (size_t)img*TOK*64;
    int tbase = tile*64 + w*16 + 4*lk;
    #pragma unroll
    for (int cs = 0; cs < 4; ++cs)
        #pragma unroll
        for (int r = 0; r < 4; ++r)
            featH2[(size_t)(tbase + r)*64 + cs*16 + lr] = (_Float16)fmaxf(acc[cs][r], 0.f);
}

// ---------------- fused QKV GEMM (MFMA, all-register): featH2 -> QT/KT/VH ----------------
__global__ __launch_bounds__(256) void qkvgemm_kernel(float* __restrict__ ws)
{
    int bid = blockIdx.x;            // 2 * 288
    int b   = bid / 288;
    int tt0 = (bid % 288) * 32;
    int tid = threadIdx.x;
    int lane = tid & 63, w = tid >> 6;
    int lr = lane & 15, lk = lane >> 4;

    const _Float16* fH = (const _Float16*)(ws + OFF_FEAT) + (size_t)b*2*TOK*64;
    const _Float16* W  = (const _Float16*)(ws + OFF_WCAT);
    const float* bc = ws + OFF_BCAT;
    _Float16* QT = (_Float16*)(ws + OFF_QT) + (size_t)b*TOK*64;
    _Float16* KT = (_Float16*)(ws + OFF_KT) + (size_t)b*TOK*64;
    _Float16* VH = (_Float16*)(ws + OFF_VH) + (size_t)b*64*TOK;

    // B frags: k = kc*32 + lk*8 -> plane n = k>>6, ci = k&63 (16B contiguous)
    half8 bf[2][4];
    #pragma unroll
    for (int tt = 0; tt < 2; ++tt)
        #pragma unroll
        for (int kc = 0; kc < 4; ++kc) {
            int k = kc*32 + lk*8;
            bf[tt][kc] = *(const half8*)&fH[(size_t)(k >> 6)*TOK*64
                                            + (size_t)(tt0 + tt*16 + lr)*64 + (k & 63)];
        }

    half8 af[3][4];
    #pragma unroll
    for (int i = 0; i < 3; ++i)
        #pragma unroll
        for (int kc = 0; kc < 4; ++kc)
            af[i][kc] = *(const half8*)&W[(size_t)((w*3 + i)*16 + lr)*128 + kc*32 + lk*8];

    #pragma unroll
    for (int i = 0; i < 3; ++i) {
        int ot = w*3 + i;
        f32x4 a0, a1;
        #pragma unroll
        for (int r = 0; r < 4; ++r) {
            float bv = bc[ot*16 + 4*lk + r];
            a0[r] = bv; a1[r] = bv;
        }
        #pragma unroll
        for (int kc = 0; kc < 4; ++kc) {
            a0 = __builtin_amdgcn_mfma_f32_16x16x32_f16(af[i][kc], bf[0][kc], a0, 0, 0, 0);
            a1 = __builtin_amdgcn_mfma_f32_16x16x32_f16(af[i][kc], bf[1][kc], a1, 0, 0, 0);
        }
        #pragma unroll
        for (int tt = 0; tt < 2; ++tt) {
            f32x4 a = tt ? a1 : a0;
            int t = tt0 + tt*16 + lr;
            if (ot < 4) {
                union { _Float16 h[4]; uint2 u; } p;
                #pragma unroll
                for (int r = 0; r < 4; ++r) p.h[r] = (_Float16)a[r];
                *(uint2*)&QT[(size_t)t*64 + ot*16 + 4*lk] = p.u;
            } else if (ot < 8) {
                union { _Float16 h[4]; uint2 u; } p;
                #pragma unroll
                for (int r = 0; r < 4; ++r) p.h[r] = (_Float16)a[r];
                *(uint2*)&KT[(size_t)t*64 + (ot-4)*16 + 4*lk] = p.u;
            } else {
                #pragma unroll
                for (int r = 0; r < 4; ++r)
                    VH[(size_t)((ot-8)*16 + 4*lk + r)*TOK + t] = (_Float16)a[r];
            }
        }
    }
}

// ---------------- flash attention partial (frozen from round 13) ----------------
__global__ __launch_bounds__(256, 5) void attn_kernel(float* __restrict__ ws)
{
    __shared__ __align__(16) char smem[32768];   // K0 V0 | K1 V1 (dbuf)
    float* ldsf = (float*)smem;                  // epilogue reuse: [64 c][68] f32

    int bid = blockIdx.x;       // 2 * 144 * KSPLIT
    int b   = bid / (144*KSPLIT);
    int rem = bid % (144*KSPLIT);
    int qt  = rem / KSPLIT;
    int ks  = rem % KSPLIT;
    int tid = threadIdx.x;
    int lane = tid & 63, w = tid >> 6;
    int q0 = qt * 64;
    int lr = lane & 15;
    int lk = lane >> 4;

    int kb0 = (ks*144)/KSPLIT, kb1 = ((ks+1)*144)/KSPLIT;
    int nit = kb1 - kb0;
    int slab = b*KSPLIT + ks;

    const _Float16* Qt = (const _Float16*)(ws + OFF_QT) + (size_t)b*TOK*64;
    const _Float16* Kt = (const _Float16*)(ws + OFF_KT) + (size_t)b*TOK*64;
    const _Float16* Vh = (const _Float16*)(ws + OFF_VH) + (size_t)b*64*TOK;
    float* part = part_base(ws, slab);
    float* ml   = ws + OFF_ML2 + (size_t)slab*2*TOK;

    half8 qB[2];
    #pragma unroll
    for (int ch = 0; ch < 2; ++ch)
        qB[ch] = *(const half8*)&Qt[(size_t)(q0 + w*16 + lr)*64 + ch*32 + lk*8];

    const f32x4 Z4 = (f32x4){0.f, 0.f, 0.f, 0.f};
    half8 ones;
    #pragma unroll
    for (int i = 0; i < 8; ++i) ones[i] = (_Float16)1.0f;

    f32x4 O[4];
    #pragma unroll
    for (int cs = 0; cs < 4; ++cs) O[cs] = Z4;
    f32x4 lacc = Z4;
    float mM = -INFINITY;

    int segl = ((lane & 7) ^ ((lane >> 3) & 7)) * 8;
    unsigned rbase = (unsigned)(w*16 + (lane >> 3));
    unsigned kOff = (unsigned)(kb0*64 + rbase)*64u + (unsigned)segl;
    unsigned vOff = rbase*(unsigned)TOK + (unsigned)(kb0*64) + (unsigned)segl;
    unsigned wk0 = (unsigned)(w * 2048);

    {
        char* bK = smem;
        char* bV = smem + 8192;
        GLOAD_LDS(Kt + kOff,           bK + wk0);
        GLOAD_LDS(Kt + kOff + 512,     bK + wk0 + 1024);
        GLOAD_LDS(Vh + vOff,           bV + wk0);
        GLOAD_LDS(Vh + vOff + 8u*TOK,  bV + wk0 + 1024);
    }
    asm volatile("s_waitcnt vmcnt(0)" ::: "memory");
    __builtin_amdgcn_s_barrier();

    for (int it = 0; it < nit; ++it) {
        char* sKb = smem + (it & 1) * 16384;
        char* sVb = sKb + 8192;
        char* sSt = smem + ((it + 1) & 1) * 16384;

        if (it + 1 < nit) {
            unsigned kN = kOff + (unsigned)(it + 1) * 4096u;
            unsigned vN = vOff + (unsigned)(it + 1) * 64u;
            GLOAD_LDS(Kt + kN,           sSt + wk0);
            GLOAD_LDS(Kt + kN + 512,     sSt + wk0 + 1024);
            GLOAD_LDS(Vh + vN,           sSt + 8192 + wk0);
            GLOAD_LDS(Vh + vN + 8u*TOK,  sSt + 8192 + wk0 + 1024);
        }

        f32x4 S[4];
        __builtin_amdgcn_s_setprio(1);
        #pragma unroll
        for (int st = 0; st < 4; ++st) {
            int t = st*16 + lr;
            half8 kA0 = *(const half8*)(sKb + ((t*128 +       lk*16) ^ ((t&7)<<4)));
            half8 kA1 = *(const half8*)(sKb + ((t*128 + 64 +  lk*16) ^ ((t&7)<<4)));
            f32x4 s = __builtin_amdgcn_mfma_f32_16x16x32_f16(kA0, qB[0], Z4, 0, 0, 0);
            S[st]   = __builtin_amdgcn_mfma_f32_16x16x32_f16(kA1, qB[1], s,  0, 0, 0);
        }
        __builtin_amdgcn_s_setprio(0);

        float a0 = fmaxf(fmaxf(S[0][0], S[0][1]), S[0][2]);
        float a1 = fmaxf(fmaxf(S[0][3], S[1][0]), S[1][1]);
        float a2 = fmaxf(fmaxf(S[1][2], S[1][3]), S[2][0]);
        float a3 = fmaxf(fmaxf(S[2][1], S[2][2]), S[2][3]);
        float a4 = fmaxf(fmaxf(S[3][0], S[3][1]), S[3][2]);
        float pm = fmaxf(fmaxf(fmaxf(a0, a1), a2),
                         fmaxf(fmaxf(a3, a4), S[3][3]));
        pm = fmaxf(pm, __shfl_xor(pm, 16));
        pm = fmaxf(pm, __shfl_xor(pm, 32));

        if (__any(pm > mM + 8.0f)) {
            float mn = fmaxf(mM, pm);
            float fs = exp2f(mM - mn);
            mM = mn;
            #pragma unroll
            for (int cs = 0; cs < 4; ++cs)
                #pragma unroll
                for (int r = 0; r < 4; ++r) O[cs][r] *= fs;
            #pragma unroll
            for (int r = 0; r < 4; ++r) lacc[r] *= fs;
        }

        #pragma unroll
        for (int st = 0; st < 4; ++st)
            #pragma unroll
            for (int r = 0; r < 4; ++r)
                S[st][r] = exp2f(S[st][r] - mM);

        unsigned int pk[4][2];
        #pragma unroll
        for (int st = 0; st < 4; ++st) {
            union { _Float16 h[2]; unsigned int u; } c0, c1;
            c0.h[0] = (_Float16)S[st][0]; c0.h[1] = (_Float16)S[st][1];
            c1.h[0] = (_Float16)S[st][2]; c1.h[1] = (_Float16)S[st][3];
            pk[st][0] = c0.u; pk[st][1] = c1.u;
        }

        int srcA = lr + 32*(lk & 1);
        int sel  = lk >> 1;
        __builtin_amdgcn_s_setprio(1);
        #pragma unroll
        for (int ch2 = 0; ch2 < 2; ++ch2) {
            union { unsigned int u[4]; half8 h; } pb;
            #pragma unroll
            for (int w2 = 0; w2 < 4; ++w2) {
                int src = srcA + 16*(w2 >> 1);
                int lo = __shfl((int)pk[ch2*2 + 0][w2 & 1], src);
                int hi = __shfl((int)pk[ch2*2 + 1][w2 & 1], src);
                pb.u[w2] = (unsigned int)(sel ? hi : lo);
            }
            lacc = __builtin_amdgcn_mfma_f32_16x16x32_f16(ones, pb.h, lacc, 0, 0, 0);
            #pragma unroll
            for (int cs = 0; cs < 4; ++cs) {
                int crow = cs*16 + lr;
                half8 vA = *(const half8*)(sVb + ((crow*128 + ch2*64 + lk*16) ^ ((crow&7)<<4)));
                O[cs] = __builtin_amdgcn_mfma_f32_16x16x32_f16(vA, pb.h, O[cs], 0, 0, 0);
            }
        }
        __builtin_amdgcn_s_setprio(0);

        asm volatile("s_waitcnt vmcnt(0)" ::: "memory");
        __builtin_amdgcn_s_barrier();
    }

    if (lk == 0) {
        ml[q0 + w*16 + lr]       = mM;
        ml[TOK + q0 + w*16 + lr] = lacc[0];
    }

    #pragma unroll
    for (int cs = 0; cs < 4; ++cs)
        #pragma unroll
        for (int r = 0; r < 4; ++r)
            ldsf[(cs*16 + 4*lk + r)*68 + w*16 + lr] = O[cs][r];
    __syncthreads();
    int c = tid >> 2, sg = tid & 3;
    const float* srcr = &ldsf[c*68 + sg*16];
    float* dstr = &part[(size_t)c*TOK + q0 + sg*16];
    #pragma unroll
    for (int j = 0; j < 4; ++j)
        *(float4*)&dstr[j*4] = *(const float4*)&srcr[j*4];
}

// ---------------- recombine KV-split partials (exp2 domain) ----------------
__global__ __launch_bounds__(256) void recombine_kernel(
    const float* __restrict__ ws, float* __restrict__ out)
{
    int gid = blockIdx.x * 256 + threadIdx.x;   // 2 * 4cg * TOK = 73728
    int b   = gid / (4*TOK);
    int rem = gid % (4*TOK);
    int cg  = rem / TOK;
    int t   = rem % TOK;
    const float* mlp = ws + OFF_ML2;

    float m[KSPLIT], l[KSPLIT];
    float M = -INFINITY;
    #pragma unroll
    for (int ks = 0; ks < KSPLIT; ++ks) {
        int slab = b*KSPLIT + ks;
        m[ks] = mlp[(size_t)slab*2*TOK + t];
        l[ks] = mlp[(size_t)slab*2*TOK + TOK + t];
        M = fmaxf(M, m[ks]);
    }
    float wgt[KSPLIT];
    float denom = 0.f;
    #pragma unroll
    for (int ks = 0; ks < KSPLIT; ++ks) {
        wgt[ks] = exp2f(m[ks] - M);
        denom += l[ks] * wgt[ks];
    }
    float inv = 1.f / denom;
    #pragma unroll
    for (int cc = 0; cc < 16; ++cc) {
        int c = cg*16 + cc;
        float acc = 0.f;
        #pragma unroll
        for (int ks = 0; ks < KSPLIT; ++ks) {
            const float* part = part_base_c(ws, b*KSPLIT + ks);
            acc += part[(size_t)c*TOK + t] * wgt[ks];
        }
        out[(size_t)(b*64 + c)*TOK + t] = acc * inv;
    }
}

extern "C" void kernel_launch(void* const* d_in, const int* in_sizes, int n_in,
                              void* d_out, int out_size, void* d_ws, size_t ws_size,
                              hipStream_t stream)
{
    const float* frames = (const float*)d_in[0];
    const float* w1 = (const float*)d_in[1];
    const float* b1 = (const float*)d_in[2];
    const float* w2 = (const float*)d_in[3];
    const float* b2 = (const float*)d_in[4];
    const float* qw = (const float*)d_in[5];
    const float* qb = (const float*)d_in[6];
    const float* kw = (const float*)d_in[7];
    const float* kb = (const float*)d_in[8];
    const float* vw = (const float*)d_in[9];
    const float* vb = (const float*)d_in[10];
    float* ws = (float*)d_ws;
    float* out = (float*)d_out;

    hipLaunchKernelGGL(prep_kernel, dim3(144), dim3(256), 0, stream,
                       w1, b1, w2, b2, qw, qb, kw, kb, vw, vb, ws);
    hipLaunchKernelGGL(conv1_kernel, dim3(144), dim3(256), 0, stream, frames, ws);
    hipLaunchKernelGGL(conv2_kernel, dim3(576), dim3(256), 0, stream, ws);
    hipLaunchKernelGGL(qkvgemm_kernel, dim3(576), dim3(256), 0, stream, ws);
    hipLaunchKernelGGL(attn_kernel, dim3(2*144*KSPLIT), dim3(256), 0, stream, ws);
    hipLaunchKernelGGL(recombine_kernel, dim3(288), dim3(256), 0, stream, ws, out);
}

// Round 17
// 174.348 us; speedup vs baseline: 2.9731x; 1.0063x over previous
//
#include <hip/hip_runtime.h>
#include <hip/hip_bf16.h>

#define TOK 9216   // 96*96 tokens per image
#define KSPLIT 5

typedef _Float16 half8 __attribute__((ext_vector_type(8)));
typedef float f32x4 __attribute__((ext_vector_type(4)));

// global_load_lds: 16B per lane, linear LDS dest (wave-uniform base + lane*16)
#define GLOAD_LDS(g, l) \
    __builtin_amdgcn_global_load_lds((const __attribute__((address_space(1))) void*)(g), \
                                     (__attribute__((address_space(3))) void*)(l), 16, 0, 0)

#define QSCALE 0.18033688011112042f   // 0.125 * log2(e); softmax runs in exp2 domain

// ---------------- workspace layout (in floats) ----------------
#define OFF_F1   0u                      // conv1 out: f16 [img][t][64] (1.18M f32 slots)
#define SZ_F1    (4u*64u*TOK)
#define OFF_FEAT (OFF_F1 + SZ_F1)        // conv2 out: f16 [b][n][t][64] (1.18M f32 slots)
#define SZ_FEAT  (2u*128u*TOK)
#define OFF_Q    (OFF_FEAT + SZ_FEAT)    // (dead f32 regions, kept for slab math)
#define SZ_QKV   (2u*64u*TOK)
#define OFF_K    (OFF_Q + SZ_QKV)
#define OFF_V    (OFF_K + SZ_QKV)
#define OFF_W1   (OFF_V + SZ_QKV)        // [64][9] f32
#define OFF_B1   (OFF_W1 + 576u)
#define OFF_W2T  (OFF_B1 + 64u)          // WCONV f16 [64 co][576 k], k=tap*64+ci
#define OFF_B2   (OFF_W2T + 36864u)
#define OFF_WCAT (OFF_B2 + 64u)          // [192][128] f16, col k = n*64+c (q rows scaled)
#define OFF_BCAT (OFF_WCAT + 24576u)     // [192] f32 (qb scaled)

// f16 QKV overlaid on F1 (f1h dead after conv2). Offsets in f32 units.
#define OFF_QT   OFF_F1                  // [b][t][64] f16, scale folded
#define OFF_KT   (OFF_F1 + 589824u)      // [b][t][64] f16
#define OFF_VH   (OFF_F1 + 1179648u)     // [b][64][t] f16, ends at 1769472

// KV-split partials: 10 slabs of 64*TOK f32 each (589824 floats).
#define OFF_SLAB0 1769472u
#define OFF_ML2   (OFF_FEAT + 9u*589824u)   // [slab][2 (m,l)][TOK] f32

__device__ __forceinline__ const float* part_base_c(const float* ws, int slab) {
    return ws + (slab == 0 ? OFF_SLAB0 : (OFF_FEAT + (unsigned)(slab - 1) * 589824u));
}
__device__ __forceinline__ float* part_base(float* ws, int slab) {
    return ws + (slab == 0 ? OFF_SLAB0 : (OFF_FEAT + (unsigned)(slab - 1) * 589824u));
}

// ---------------- weight prep ----------------
__global__ __launch_bounds__(256) void prep_kernel(
    const float* __restrict__ w1, const float* __restrict__ b1,
    const float* __restrict__ w2, const float* __restrict__ b2,
    const float* __restrict__ qw, const float* __restrict__ qb,
    const float* __restrict__ kw, const float* __restrict__ kb,
    const float* __restrict__ vw, const float* __restrict__ vb,
    float* __restrict__ ws)
{
    int gid = blockIdx.x * 256 + threadIdx.x;
    if (gid < 576) ws[OFF_W1 + gid] = w1[gid];
    if (gid < 64) {
        ws[OFF_B1 + gid] = b1[gid];
        ws[OFF_B2 + gid] = b2[gid];
    }
    if (gid < 36864) {   // WCONV f16: [co][tap*64+ci] <- w2[co][ci][tap]
        int co = gid / 576; int rem = gid % 576;
        int ci = rem / 9;  int tp = rem % 9;
        ((_Float16*)(ws + OFF_W2T))[co*576 + tp*64 + ci] = (_Float16)w2[gid];
    }
    if (gid < 24576) {   // WCAT f16, col k = n*64+c <- source col c*2+n; q rows scaled
        int o = gid >> 7; int kidx = gid & 127;
        int n = kidx >> 6, c = kidx & 63;
        int sc = c*2 + n;
        float v;
        if (o < 64)       v = qw[o*128 + sc] * QSCALE;
        else if (o < 128) v = kw[(o-64)*128 + sc];
        else              v = vw[(o-128)*128 + sc];
        ((_Float16*)(ws + OFF_WCAT))[gid] = (_Float16)v;
    }
    if (gid < 192) {
        float v;
        if (gid < 64)       v = qb[gid] * QSCALE;
        else if (gid < 128) v = kb[gid-64];
        else                v = vb[gid-128];
        ws[OFF_BCAT + gid] = v;
    }
}

// ---------------- conv1: 1->64 ch, 3x3, relu; writes f16 channel-last ----------------
__global__ __launch_bounds__(256) void conv1_kernel(
    const float* __restrict__ x, float* __restrict__ ws)
{
    const float* w1f = ws + OFF_W1;
    const float* b1f = ws + OFF_B1;
    _Float16* f1h = (_Float16*)(ws + OFF_F1);
    int gid = blockIdx.x * 256 + threadIdx.x;   // 4*9216
    int img = gid / TOK;
    int p   = gid % TOK;
    int h = p / 96, w = p % 96;
    float xv[9];
    #pragma unroll
    for (int dh = 0; dh < 3; ++dh)
        #pragma unroll
        for (int dw = 0; dw < 3; ++dw) {
            int r = h + dh - 1, c = w + dw - 1;
            bool ok = (r >= 0) && (r < 96) && (c >= 0) && (c < 96);
            xv[dh*3 + dw] = ok ? x[img*TOK + r*96 + c] : 0.f;
        }
    _Float16* dst = f1h + (size_t)gid * 64;     // [img][p][64], 128B contiguous
    #pragma unroll
    for (int g8 = 0; g8 < 8; ++g8) {
        union { _Float16 h[8]; uint4 u; } pk8;
        #pragma unroll
        for (int j = 0; j < 8; ++j) {
            int co = g8*8 + j;
            float a = b1f[co];
            #pragma unroll
            for (int t = 0; t < 9; ++t) a += w1f[co*9 + t] * xv[t];
            pk8.h[j] = (_Float16)fmaxf(a, 0.f);
        }
        *(uint4*)&dst[g8*8] = pk8.u;
    }
}

// ---------------- conv2 as MFMA im2col GEMM: f1h -> featH2 [img][t][64] ----------------
__global__ __launch_bounds__(256) void conv2_kernel(float* __restrict__ ws)
{
    int bid = blockIdx.x;            // 4 img * 144
    int img = bid & 3;
    int tile = bid >> 2;
    int tid = threadIdx.x;
    int lane = tid & 63, w = tid >> 6;
    int lr = lane & 15, lk = lane >> 4;

    const _Float16* f1h = (const _Float16*)(ws + OFF_F1) + (size_t)img*TOK*64;
    const _Float16* Wc  = (const _Float16*)(ws + OFF_W2T);   // [64][576]
    const float* b2f = ws + OFF_B2;

    int t = tile*64 + w*16 + lr;
    int h = t / 96, wc = t % 96;

    half8 z8;
    #pragma unroll
    for (int i = 0; i < 8; ++i) z8[i] = (_Float16)0.f;

    f32x4 acc[4];
    #pragma unroll
    for (int cs = 0; cs < 4; ++cs) {
        float bv = b2f[cs*16 + lr];
        acc[cs] = (f32x4){bv, bv, bv, bv};
    }

    #pragma unroll
    for (int ch = 0; ch < 18; ++ch) {
        int k = ch*32 + lk*8;
        int tap = k >> 6, ci = k & 63;
        int dh = tap / 3, dw = tap % 3;
        int r = h + dh - 1, c = wc + dw - 1;
        half8 af = z8;
        if ((unsigned)r < 96u && (unsigned)c < 96u)
            af = *(const half8*)&f1h[(size_t)(r*96 + c)*64 + ci];
        #pragma unroll
        for (int cs = 0; cs < 4; ++cs) {
            half8 bfr = *(const half8*)&Wc[(size_t)(cs*16 + lr)*576 + k];
            acc[cs] = __builtin_amdgcn_mfma_f32_16x16x32_f16(af, bfr, acc[cs], 0, 0, 0);
        }
    }

    _Float16* featH2 = (_Float16*)(ws + OFF_FEAT) + (size_t)img*TOK*64;
    int tbase = tile*64 + w*16 + 4*lk;
    #pragma unroll
    for (int cs = 0; cs < 4; ++cs)
        #pragma unroll
        for (int r = 0; r < 4; ++r)
            featH2[(size_t)(tbase + r)*64 + cs*16 + lr] = (_Float16)fmaxf(acc[cs][r], 0.f);
}

// ---------------- fused QKV GEMM (MFMA, all-register): featH2 -> QT/KT/VH ----------------
__global__ __launch_bounds__(256) void qkvgemm_kernel(float* __restrict__ ws)
{
    int bid = blockIdx.x;            // 2 * 288
    int b   = bid / 288;
    int tt0 = (bid % 288) * 32;
    int tid = threadIdx.x;
    int lane = tid & 63, w = tid >> 6;
    int lr = lane & 15, lk = lane >> 4;

    const _Float16* fH = (const _Float16*)(ws + OFF_FEAT) + (size_t)b*2*TOK*64;
    const _Float16* W  = (const _Float16*)(ws + OFF_WCAT);
    const float* bc = ws + OFF_BCAT;
    _Float16* QT = (_Float16*)(ws + OFF_QT) + (size_t)b*TOK*64;
    _Float16* KT = (_Float16*)(ws + OFF_KT) + (size_t)b*TOK*64;
    _Float16* VH = (_Float16*)(ws + OFF_VH) + (size_t)b*64*TOK;

    half8 bf[2][4];
    #pragma unroll
    for (int tt = 0; tt < 2; ++tt)
        #pragma unroll
        for (int kc = 0; kc < 4; ++kc) {
            int k = kc*32 + lk*8;
            bf[tt][kc] = *(const half8*)&fH[(size_t)(k >> 6)*TOK*64
                                            + (size_t)(tt0 + tt*16 + lr)*64 + (k & 63)];
        }

    half8 af[3][4];
    #pragma unroll
    for (int i = 0; i < 3; ++i)
        #pragma unroll
        for (int kc = 0; kc < 4; ++kc)
            af[i][kc] = *(const half8*)&W[(size_t)((w*3 + i)*16 + lr)*128 + kc*32 + lk*8];

    #pragma unroll
    for (int i = 0; i < 3; ++i) {
        int ot = w*3 + i;
        f32x4 a0, a1;
        #pragma unroll
        for (int r = 0; r < 4; ++r) {
            float bv = bc[ot*16 + 4*lk + r];
            a0[r] = bv; a1[r] = bv;
        }
        #pragma unroll
        for (int kc = 0; kc < 4; ++kc) {
            a0 = __builtin_amdgcn_mfma_f32_16x16x32_f16(af[i][kc], bf[0][kc], a0, 0, 0, 0);
            a1 = __builtin_amdgcn_mfma_f32_16x16x32_f16(af[i][kc], bf[1][kc], a1, 0, 0, 0);
        }
        #pragma unroll
        for (int tt = 0; tt < 2; ++tt) {
            f32x4 a = tt ? a1 : a0;
            int t = tt0 + tt*16 + lr;
            if (ot < 4) {
                union { _Float16 h[4]; uint2 u; } p;
                #pragma unroll
                for (int r = 0; r < 4; ++r) p.h[r] = (_Float16)a[r];
                *(uint2*)&QT[(size_t)t*64 + ot*16 + 4*lk] = p.u;
            } else if (ot < 8) {
                union { _Float16 h[4]; uint2 u; } p;
                #pragma unroll
                for (int r = 0; r < 4; ++r) p.h[r] = (_Float16)a[r];
                *(uint2*)&KT[(size_t)t*64 + (ot-4)*16 + 4*lk] = p.u;
            } else {
                #pragma unroll
                for (int r = 0; r < 4; ++r)
                    VH[(size_t)((ot-8)*16 + 4*lk + r)*TOK + t] = (_Float16)a[r];
            }
        }
    }
}

// ---------------- flash attention partial: KVBLK=32, LDS 17.4KB, 8 blocks/CU ----------------
// grid = 2b x 144qt x KSPLIT; 256 thr = 4 waves x 16 q-rows.
// K LDS [32 kt][64 d] swz ^((row&7)<<4); V LDS [64 d][32 kt] swz ^((row&3)<<4).
// gload_lds linear dest + inverse-swizzled global source; 1 barrier/iter, counted-drain.
__global__ __launch_bounds__(256, 8) void attn_kernel(float* __restrict__ ws)
{
    __shared__ __align__(16) char smem[17408];   // K0|K1|V0|V1 (16KB) ; epilogue f32 [64][68]
    float* ldsf = (float*)smem;

    int bid = blockIdx.x;       // 2 * 144 * KSPLIT
    int b   = bid / (144*KSPLIT);
    int rem = bid % (144*KSPLIT);
    int qt  = rem / KSPLIT;
    int ks  = rem % KSPLIT;
    int tid = threadIdx.x;
    int lane = tid & 63, w = tid >> 6;
    int q0 = qt * 64;
    int lr = lane & 15;
    int lk = lane >> 4;

    int kb0 = (ks*288)/KSPLIT, kb1 = ((ks+1)*288)/KSPLIT;   // 32-wide kt tiles
    int nit = kb1 - kb0;
    int slab = b*KSPLIT + ks;

    const _Float16* Qt = (const _Float16*)(ws + OFF_QT) + (size_t)b*TOK*64;
    const _Float16* Kt = (const _Float16*)(ws + OFF_KT) + (size_t)b*TOK*64;
    const _Float16* Vh = (const _Float16*)(ws + OFF_VH) + (size_t)b*64*TOK;
    float* part = part_base(ws, slab);
    float* ml   = ws + OFF_ML2 + (size_t)slab*2*TOK;

    half8 qB[2];
    #pragma unroll
    for (int ch = 0; ch < 2; ++ch)
        qB[ch] = *(const half8*)&Qt[(size_t)(q0 + w*16 + lr)*64 + ch*32 + lk*8];

    const f32x4 Z4 = (f32x4){0.f, 0.f, 0.f, 0.f};
    half8 ones;
    #pragma unroll
    for (int i = 0; i < 8; ++i) ones[i] = (_Float16)1.0f;

    f32x4 O[4];
    #pragma unroll
    for (int cs = 0; cs < 4; ++cs) O[cs] = Z4;
    f32x4 lacc = Z4;
    float mM = -INFINITY;

    // staging geometry (rule #21: linear dest, inverse-swizzled source)
    int ksegl = ((lane & 7) ^ ((lane >> 3) & 7)) * 8;       // K: 8 segs/row of 128B
    int vsegl = ((lane & 3) ^ ((lane >> 2) & 3)) * 8;       // V: 4 segs/row of 64B
    unsigned kOff = (unsigned)(kb0*32 + w*8 + (lane >> 3))*64u + (unsigned)ksegl;   // +2048/iter
    unsigned vOff = (unsigned)(w*16 + (lane >> 2))*(unsigned)TOK
                    + (unsigned)(kb0*32) + (unsigned)vsegl;                          // +32/iter
    unsigned wbase = (unsigned)(w * 1024);

    // prologue: stage tile kb0 into buf0
    GLOAD_LDS(Kt + kOff, smem +        wbase);
    GLOAD_LDS(Vh + vOff, smem + 8192 + wbase);
    asm volatile("s_waitcnt vmcnt(0)" ::: "memory");
    __builtin_amdgcn_s_barrier();

    for (int it = 0; it < nit; ++it) {
        char* sKb = smem +        (it & 1) * 4096;
        char* sVb = smem + 8192 + (it & 1) * 4096;

        if (it + 1 < nit) {
            unsigned kN = kOff + (unsigned)(it + 1) * 2048u;
            unsigned vN = vOff + (unsigned)(it + 1) * 32u;
            GLOAD_LDS(Kt + kN, smem +        ((it + 1) & 1) * 4096 + wbase);
            GLOAD_LDS(Vh + vN, smem + 8192 + ((it + 1) & 1) * 4096 + wbase);
        }

        // ---- QK^T swapped: S^T[kt 32][q 16]; lane q=lr, kt = st*16 + 4*lk + r ----
        f32x4 S[2];
        __builtin_amdgcn_s_setprio(1);
        #pragma unroll
        for (int st = 0; st < 2; ++st) {
            int t = st*16 + lr;
            half8 kA0 = *(const half8*)(sKb + ((t*128 +      lk*16) ^ ((t&7)<<4)));
            half8 kA1 = *(const half8*)(sKb + ((t*128 + 64 + lk*16) ^ ((t&7)<<4)));
            f32x4 s = __builtin_amdgcn_mfma_f32_16x16x32_f16(kA0, qB[0], Z4, 0, 0, 0);
            S[st]   = __builtin_amdgcn_mfma_f32_16x16x32_f16(kA1, qB[1], s,  0, 0, 0);
        }
        __builtin_amdgcn_s_setprio(0);

        // ---- row max (8 vals) ----
        float m0 = fmaxf(fmaxf(S[0][0], S[0][1]), fmaxf(S[0][2], S[0][3]));
        float m1 = fmaxf(fmaxf(S[1][0], S[1][1]), fmaxf(S[1][2], S[1][3]));
        float pm = fmaxf(m0, m1);
        pm = fmaxf(pm, __shfl_xor(pm, 16));
        pm = fmaxf(pm, __shfl_xor(pm, 32));

        // ---- defer-max THR=8 (exp2 domain) ----
        if (__any(pm > mM + 8.0f)) {
            float mn = fmaxf(mM, pm);
            float fs = exp2f(mM - mn);
            mM = mn;
            #pragma unroll
            for (int cs = 0; cs < 4; ++cs)
                #pragma unroll
                for (int r = 0; r < 4; ++r) O[cs][r] *= fs;
            #pragma unroll
            for (int r = 0; r < 4; ++r) lacc[r] *= fs;
        }

        // ---- p = exp2(S - mM), pack pairs via cvt_pkrtz (bit_cast result directly) ----
        #pragma unroll
        for (int st = 0; st < 2; ++st)
            #pragma unroll
            for (int r = 0; r < 4; ++r)
                S[st][r] = exp2f(S[st][r] - mM);

        unsigned int pk2[2][2];
        #pragma unroll
        for (int st = 0; st < 2; ++st) {
            pk2[st][0] = __builtin_bit_cast(unsigned int,
                             __builtin_amdgcn_cvt_pkrtz(S[st][0], S[st][1]));
            pk2[st][1] = __builtin_bit_cast(unsigned int,
                             __builtin_amdgcn_cvt_pkrtz(S[st][2], S[st][3]));
        }

        // ---- pb: lane (lr,lk) word w2 <- lane lr+32*(lk&1)+16*(w2>>1), reg pk2[lk>>1][w2&1] ----
        int srcA = lr + 32*(lk & 1);
        int sel  = lk >> 1;
        union { unsigned int u[4]; half8 h; } pb;
        #pragma unroll
        for (int w2 = 0; w2 < 4; ++w2) {
            int src = srcA + 16*(w2 >> 1);
            int lo = __shfl((int)pk2[0][w2 & 1], src);
            int hi = __shfl((int)pk2[1][w2 & 1], src);
            pb.u[w2] = (unsigned int)(sel ? hi : lo);
        }

        // ---- PV swapped + l via ones-row MFMA ----
        __builtin_amdgcn_s_setprio(1);
        lacc = __builtin_amdgcn_mfma_f32_16x16x32_f16(ones, pb.h, lacc, 0, 0, 0);
        #pragma unroll
        for (int cs = 0; cs < 4; ++cs) {
            int crow = cs*16 + lr;
            half8 vA = *(const half8*)(sVb + ((crow*64 + lk*16) ^ ((crow&3)<<4)));
            O[cs] = __builtin_amdgcn_mfma_f32_16x16x32_f16(vA, pb.h, O[cs], 0, 0, 0);
        }
        __builtin_amdgcn_s_setprio(0);

        asm volatile("s_waitcnt vmcnt(0)" ::: "memory");
        __builtin_amdgcn_s_barrier();
    }

    if (lk == 0) {
        ml[q0 + w*16 + lr]       = mM;
        ml[TOK + q0 + w*16 + lr] = lacc[0];
    }

    // ---- epilogue: O^T already [c][q]; stage to LDS, coalesced partial writes ----
    #pragma unroll
    for (int cs = 0; cs < 4; ++cs)
        #pragma unroll
        for (int r = 0; r < 4; ++r)
            ldsf[(cs*16 + 4*lk + r)*68 + w*16 + lr] = O[cs][r];
    __syncthreads();
    int c = tid >> 2, sg = tid & 3;
    const float* srcr = &ldsf[c*68 + sg*16];
    float* dstr = &part[(size_t)c*TOK + q0 + sg*16];
    #pragma unroll
    for (int j = 0; j < 4; ++j)
        *(float4*)&dstr[j*4] = *(const float4*)&srcr[j*4];
}

// ---------------- recombine KV-split partials (exp2 domain) ----------------
__global__ __launch_bounds__(256) void recombine_kernel(
    const float* __restrict__ ws, float* __restrict__ out)
{
    int gid = blockIdx.x * 256 + threadIdx.x;   // 2 * 4cg * TOK = 73728
    int b   = gid / (4*TOK);
    int rem = gid % (4*TOK);
    int cg  = rem / TOK;
    int t   = rem % TOK;
    const float* mlp = ws + OFF_ML2;

    float m[KSPLIT], l[KSPLIT];
    float M = -INFINITY;
    #pragma unroll
    for (int ks = 0; ks < KSPLIT; ++ks) {
        int slab = b*KSPLIT + ks;
        m[ks] = mlp[(size_t)slab*2*TOK + t];
        l[ks] = mlp[(size_t)slab*2*TOK + TOK + t];
        M = fmaxf(M, m[ks]);
    }
    float wgt[KSPLIT];
    float denom = 0.f;
    #pragma unroll
    for (int ks = 0; ks < KSPLIT; ++ks) {
        wgt[ks] = exp2f(m[ks] - M);
        denom += l[ks] * wgt[ks];
    }
    float inv = 1.f / denom;
    #pragma unroll
    for (int cc = 0; cc < 16; ++cc) {
        int c = cg*16 + cc;
        float acc = 0.f;
        #pragma unroll
        for (int ks = 0; ks < KSPLIT; ++ks) {
            const float* part = part_base_c(ws, b*KSPLIT + ks);
            acc += part[(size_t)c*TOK + t] * wgt[ks];
        }
        out[(size_t)(b*64 + c)*TOK + t] = acc * inv;
    }
}

extern "C" void kernel_launch(void* const* d_in, const int* in_sizes, int n_in,
                              void* d_out, int out_size, void* d_ws, size_t ws_size,
                              hipStream_t stream)
{
    const float* frames = (const float*)d_in[0];
    const float* w1 = (const float*)d_in[1];
    const float* b1 = (const float*)d_in[2];
    const float* w2 = (const float*)d_in[3];
    const float* b2 = (const float*)d_in[4];
    const float* qw = (const float*)d_in[5];
    const float* qb = (const float*)d_in[6];
    const float* kw = (const float*)d_in[7];
    const float* kb = (const float*)d_in[8];
    const float* vw = (const float*)d_in[9];
    const float* vb = (const float*)d_in[10];
    float* ws = (float*)d_ws;
    float* out = (float*)d_out;

    hipLaunchKernelGGL(prep_kernel, dim3(144), dim3(256), 0, stream,
                       w1, b1, w2, b2, qw, qb, kw, kb, vw, vb, ws);
    hipLaunchKernelGGL(conv1_kernel, dim3(144), dim3(256), 0, stream, frames, ws);
    hipLaunchKernelGGL(conv2_kernel, dim3(576), dim3(256), 0, stream, ws);
    hipLaunchKernelGGL(qkvgemm_kernel, dim3(576), dim3(256), 0, stream, ws);
    hipLaunchKernelGGL(attn_kernel, dim3(2*144*KSPLIT), dim3(256), 0, stream, ws);
    hipLaunchKernelGGL(recombine_kernel, dim3(288), dim3(256), 0, stream, ws, out);
}

// Round 18
// 169.986 us; speedup vs baseline: 3.0493x; 1.0257x over previous
//
#include <hip/hip_runtime.h>
#include <hip/hip_bf16.h>

#define TOK 9216   // 96*96 tokens per image
#define KSPLIT 5

typedef _Float16 half8 __attribute__((ext_vector_type(8)));
typedef float f32x4 __attribute__((ext_vector_type(4)));

// global_load_lds: 16B per lane, linear LDS dest (wave-uniform base + lane*16)
#define GLOAD_LDS(g, l) \
    __builtin_amdgcn_global_load_lds((const __attribute__((address_space(1))) void*)(g), \
                                     (__attribute__((address_space(3))) void*)(l), 16, 0, 0)

#define QSCALE 0.18033688011112042f   // 0.125 * log2(e); softmax runs in exp2 domain

// ---------------- workspace layout (in floats) ----------------
#define OFF_F1   0u                      // conv1 out: f16 [img][t][64] (1.18M f32 slots)
#define SZ_F1    (4u*64u*TOK)
#define OFF_FEAT (OFF_F1 + SZ_F1)        // conv2 out: f16 [img][t][64]
#define SZ_FEAT  (2u*128u*TOK)
#define OFF_W1   (OFF_FEAT + SZ_FEAT + 3u*2u*64u*TOK)   // (dead regions preserved)
#define OFF_B1   (OFF_W1 + 576u)
#define OFF_W2T  (OFF_B1 + 64u)          // WCONV f16 [64 co][576 k], k=tap*64+ci
#define OFF_B2   (OFF_W2T + 36864u)
#define OFF_WCAT (OFF_B2 + 64u)          // [192][128] f16, col k = n*64+c (q rows scaled)
#define OFF_BCAT (OFF_WCAT + 24576u)     // [192] f32 (qb scaled)

// f16 QKV overlaid on F1 (f1h dead after conv2). Offsets in f32 units.
#define OFF_QT   OFF_F1                  // [b][t][64] f16, scale folded
#define OFF_KT   (OFF_F1 + 589824u)      // [b][t][64] f16
#define OFF_VH   (OFF_F1 + 1179648u)     // [b][64][t] f16, ends at 1769472

// KV-split partials: 10 slabs of 64*TOK f32 each (589824 floats).
#define OFF_SLAB0 1769472u
#define OFF_ML2   (OFF_FEAT + 9u*589824u)   // [slab][2 (m,l)][TOK] f32

__device__ __forceinline__ const float* part_base_c(const float* ws, int slab) {
    return ws + (slab == 0 ? OFF_SLAB0 : (OFF_FEAT + (unsigned)(slab - 1) * 589824u));
}
__device__ __forceinline__ float* part_base(float* ws, int slab) {
    return ws + (slab == 0 ? OFF_SLAB0 : (OFF_FEAT + (unsigned)(slab - 1) * 589824u));
}

// ---------------- conv1 (+ merged weight prep): 1->64 ch, 3x3, relu; f16 channel-last ----
__global__ __launch_bounds__(256) void conv1_kernel(
    const float* __restrict__ x,
    const float* __restrict__ w1, const float* __restrict__ b1,
    const float* __restrict__ w2, const float* __restrict__ b2,
    const float* __restrict__ qw, const float* __restrict__ qb,
    const float* __restrict__ kw, const float* __restrict__ kb,
    const float* __restrict__ vw, const float* __restrict__ vb,
    float* __restrict__ ws)
{
    int gid = blockIdx.x * 256 + threadIdx.x;   // 144*256 = 36864

    // ---- merged prep (weights for conv2 / qkvgemm) ----
    if (gid < 64) ws[OFF_B2 + gid] = b2[gid];
    if (gid < 36864) {   // WCONV f16: [co][tap*64+ci] <- w2[co][ci][tap]
        int co = gid / 576; int rem = gid % 576;
        int ci = rem / 9;  int tp = rem % 9;
        ((_Float16*)(ws + OFF_W2T))[co*576 + tp*64 + ci] = (_Float16)w2[gid];
    }
    if (gid < 24576) {   // WCAT f16, col k = n*64+c <- source col c*2+n; q rows scaled
        int o = gid >> 7; int kidx = gid & 127;
        int n = kidx >> 6, c = kidx & 63;
        int sc = c*2 + n;
        float v;
        if (o < 64)       v = qw[o*128 + sc] * QSCALE;
        else if (o < 128) v = kw[(o-64)*128 + sc];
        else              v = vw[(o-128)*128 + sc];
        ((_Float16*)(ws + OFF_WCAT))[gid] = (_Float16)v;
    }
    if (gid < 192) {
        float v;
        if (gid < 64)       v = qb[gid] * QSCALE;
        else if (gid < 128) v = kb[gid-64];
        else                v = vb[gid-128];
        ws[OFF_BCAT + gid] = v;
    }

    // ---- conv1 (reads w1/b1 raw) ----
    _Float16* f1h = (_Float16*)(ws + OFF_F1);
    int img = gid / TOK;
    int p   = gid % TOK;
    int h = p / 96, w = p % 96;
    float xv[9];
    #pragma unroll
    for (int dh = 0; dh < 3; ++dh)
        #pragma unroll
        for (int dw = 0; dw < 3; ++dw) {
            int r = h + dh - 1, c = w + dw - 1;
            bool ok = (r >= 0) && (r < 96) && (c >= 0) && (c < 96);
            xv[dh*3 + dw] = ok ? x[img*TOK + r*96 + c] : 0.f;
        }
    _Float16* dst = f1h + (size_t)gid * 64;     // [img][p][64], 128B contiguous
    #pragma unroll
    for (int g8 = 0; g8 < 8; ++g8) {
        union { _Float16 h[8]; uint4 u; } pk8;
        #pragma unroll
        for (int j = 0; j < 8; ++j) {
            int co = g8*8 + j;
            float a = b1[co];
            #pragma unroll
            for (int t = 0; t < 9; ++t) a += w1[co*9 + t] * xv[t];
            pk8.h[j] = (_Float16)fmaxf(a, 0.f);
        }
        *(uint4*)&dst[g8*8] = pk8.u;
    }
}

// ---------------- conv2 as MFMA im2col GEMM: f1h -> featH2 [img][t][64] ----------------
__global__ __launch_bounds__(256) void conv2_kernel(float* __restrict__ ws)
{
    int bid = blockIdx.x;            // 4 img * 144
    int img = bid & 3;
    int tile = bid >> 2;
    int tid = threadIdx.x;
    int lane = tid & 63, w = tid >> 6;
    int lr = lane & 15, lk = lane >> 4;

    const _Float16* f1h = (const _Float16*)(ws + OFF_F1) + (size_t)img*TOK*64;
    const _Float16* Wc  = (const _Float16*)(ws + OFF_W2T);   // [64][576]
    const float* b2f = ws + OFF_B2;

    int t = tile*64 + w*16 + lr;
    int h = t / 96, wc = t % 96;

    half8 z8;
    #pragma unroll
    for (int i = 0; i < 8; ++i) z8[i] = (_Float16)0.f;

    f32x4 acc[4];
    #pragma unroll
    for (int cs = 0; cs < 4; ++cs) {
        float bv = b2f[cs*16 + lr];
        acc[cs] = (f32x4){bv, bv, bv, bv};
    }

    #pragma unroll
    for (int ch = 0; ch < 18; ++ch) {
        int k = ch*32 + lk*8;
        int tap = k >> 6, ci = k & 63;
        int dh = tap / 3, dw = tap % 3;
        int r = h + dh - 1, c = wc + dw - 1;
        half8 af = z8;
        if ((unsigned)r < 96u && (unsigned)c < 96u)
            af = *(const half8*)&f1h[(size_t)(r*96 + c)*64 + ci];
        #pragma unroll
        for (int cs = 0; cs < 4; ++cs) {
            half8 bfr = *(const half8*)&Wc[(size_t)(cs*16 + lr)*576 + k];
            acc[cs] = __builtin_amdgcn_mfma_f32_16x16x32_f16(af, bfr, acc[cs], 0, 0, 0);
        }
    }

    _Float16* featH2 = (_Float16*)(ws + OFF_FEAT) + (size_t)img*TOK*64;
    int tbase = tile*64 + w*16 + 4*lk;
    #pragma unroll
    for (int cs = 0; cs < 4; ++cs)
        #pragma unroll
        for (int r = 0; r < 4; ++r)
            featH2[(size_t)(tbase + r)*64 + cs*16 + lr] = (_Float16)fmaxf(acc[cs][r], 0.f);
}

// ---------------- fused QKV GEMM (MFMA, all-register): featH2 -> QT/KT/VH ----------------
__global__ __launch_bounds__(256) void qkvgemm_kernel(float* __restrict__ ws)
{
    int bid = blockIdx.x;            // 2 * 288
    int b   = bid / 288;
    int tt0 = (bid % 288) * 32;
    int tid = threadIdx.x;
    int lane = tid & 63, w = tid >> 6;
    int lr = lane & 15, lk = lane >> 4;

    const _Float16* fH = (const _Float16*)(ws + OFF_FEAT) + (size_t)b*2*TOK*64;
    const _Float16* W  = (const _Float16*)(ws + OFF_WCAT);
    const float* bc = ws + OFF_BCAT;
    _Float16* QT = (_Float16*)(ws + OFF_QT) + (size_t)b*TOK*64;
    _Float16* KT = (_Float16*)(ws + OFF_KT) + (size_t)b*TOK*64;
    _Float16* VH = (_Float16*)(ws + OFF_VH) + (size_t)b*64*TOK;

    half8 bf[2][4];
    #pragma unroll
    for (int tt = 0; tt < 2; ++tt)
        #pragma unroll
        for (int kc = 0; kc < 4; ++kc) {
            int k = kc*32 + lk*8;
            bf[tt][kc] = *(const half8*)&fH[(size_t)(k >> 6)*TOK*64
                                            + (size_t)(tt0 + tt*16 + lr)*64 + (k & 63)];
        }

    half8 af[3][4];
    #pragma unroll
    for (int i = 0; i < 3; ++i)
        #pragma unroll
        for (int kc = 0; kc < 4; ++kc)
            af[i][kc] = *(const half8*)&W[(size_t)((w*3 + i)*16 + lr)*128 + kc*32 + lk*8];

    #pragma unroll
    for (int i = 0; i < 3; ++i) {
        int ot = w*3 + i;
        f32x4 a0, a1;
        #pragma unroll
        for (int r = 0; r < 4; ++r) {
            float bv = bc[ot*16 + 4*lk + r];
            a0[r] = bv; a1[r] = bv;
        }
        #pragma unroll
        for (int kc = 0; kc < 4; ++kc) {
            a0 = __builtin_amdgcn_mfma_f32_16x16x32_f16(af[i][kc], bf[0][kc], a0, 0, 0, 0);
            a1 = __builtin_amdgcn_mfma_f32_16x16x32_f16(af[i][kc], bf[1][kc], a1, 0, 0, 0);
        }
        #pragma unroll
        for (int tt = 0; tt < 2; ++tt) {
            f32x4 a = tt ? a1 : a0;
            int t = tt0 + tt*16 + lr;
            if (ot < 4) {
                union { _Float16 h[4]; uint2 u; } p;
                #pragma unroll
                for (int r = 0; r < 4; ++r) p.h[r] = (_Float16)a[r];
                *(uint2*)&QT[(size_t)t*64 + ot*16 + 4*lk] = p.u;
            } else if (ot < 8) {
                union { _Float16 h[4]; uint2 u; } p;
                #pragma unroll
                for (int r = 0; r < 4; ++r) p.h[r] = (_Float16)a[r];
                *(uint2*)&KT[(size_t)t*64 + (ot-4)*16 + 4*lk] = p.u;
            } else {
                #pragma unroll
                for (int r = 0; r < 4; ++r)
                    VH[(size_t)((ot-8)*16 + 4*lk + r)*TOK + t] = (_Float16)a[r];
            }
        }
    }
}

// ---------------- flash attention partial: 8 waves x 128q, KVBLK=32 ----------------
// grid = 2b x 72qt x KSPLIT; 512 thr. Waves 0-3 stage K, 4-7 stage V (1 gload each).
// K LDS [32 kt][64 d] swz ^((row&7)<<4); V LDS [64 d][32 kt] swz ^((row&3)<<4).
__global__ __launch_bounds__(512, 8) void attn_kernel(float* __restrict__ ws)
{
    __shared__ __align__(16) char smem[17408];   // K0|K1|V0|V1 (16KB); epilogue f32 [64][68]
    float* ldsf = (float*)smem;

    int bid = blockIdx.x;       // 2 * 72 * KSPLIT = 720
    int b   = bid / (72*KSPLIT);
    int rem = bid % (72*KSPLIT);
    int qt  = rem / KSPLIT;
    int ks  = rem % KSPLIT;
    int tid = threadIdx.x;
    int lane = tid & 63, w = tid >> 6;          // 8 waves
    int q0 = qt * 128;
    int lr = lane & 15;
    int lk = lane >> 4;

    int kb0 = (ks*288)/KSPLIT, kb1 = ((ks+1)*288)/KSPLIT;   // 32-wide kt tiles
    int nit = kb1 - kb0;
    int slab = b*KSPLIT + ks;

    const _Float16* Qt = (const _Float16*)(ws + OFF_QT) + (size_t)b*TOK*64;
    const _Float16* Kt = (const _Float16*)(ws + OFF_KT) + (size_t)b*TOK*64;
    const _Float16* Vh = (const _Float16*)(ws + OFF_VH) + (size_t)b*64*TOK;
    float* part = part_base(ws, slab);
    float* ml   = ws + OFF_ML2 + (size_t)slab*2*TOK;

    half8 qB[2];
    #pragma unroll
    for (int ch = 0; ch < 2; ++ch)
        qB[ch] = *(const half8*)&Qt[(size_t)(q0 + w*16 + lr)*64 + ch*32 + lk*8];

    const f32x4 Z4 = (f32x4){0.f, 0.f, 0.f, 0.f};
    half8 ones;
    #pragma unroll
    for (int i = 0; i < 8; ++i) ones[i] = (_Float16)1.0f;

    f32x4 O[4];
    #pragma unroll
    for (int cs = 0; cs < 4; ++cs) O[cs] = Z4;
    f32x4 lacc = Z4;
    float mM = -INFINITY;

    // staging geometry (rule #21: linear dest, inverse-swizzled source)
    int ksegl = ((lane & 7) ^ ((lane >> 3) & 7)) * 8;       // K: 8 segs/row of 128B
    int vsegl = ((lane & 3) ^ ((lane >> 2) & 3)) * 8;       // V: 4 segs/row of 64B
    int wq = w & 3;
    unsigned kOff = (unsigned)(kb0*32 + wq*8 + (lane >> 3))*64u + (unsigned)ksegl;   // +2048/iter
    unsigned vOff = (unsigned)(wq*16 + (lane >> 2))*(unsigned)TOK
                    + (unsigned)(kb0*32) + (unsigned)vsegl;                           // +32/iter
    unsigned wbase = (unsigned)(wq * 1024);

    // prologue: stage tile kb0 into buf0 (waves 0-3: K, waves 4-7: V)
    if (w < 4) GLOAD_LDS(Kt + kOff, smem + wbase);
    else       GLOAD_LDS(Vh + vOff, smem + 8192 + wbase);
    asm volatile("s_waitcnt vmcnt(0)" ::: "memory");
    __builtin_amdgcn_s_barrier();

    for (int it = 0; it < nit; ++it) {
        char* sKb = smem +        (it & 1) * 4096;
        char* sVb = smem + 8192 + (it & 1) * 4096;

        if (it + 1 < nit) {
            unsigned bufo = (unsigned)(((it + 1) & 1) * 4096) + wbase;
            if (w < 4) GLOAD_LDS(Kt + kOff + (unsigned)(it + 1) * 2048u, smem + bufo);
            else       GLOAD_LDS(Vh + vOff + (unsigned)(it + 1) * 32u,   smem + 8192 + bufo);
        }

        // ---- QK^T swapped: S^T[kt 32][q 16]; lane q=lr, kt = st*16 + 4*lk + r ----
        f32x4 S[2];
        __builtin_amdgcn_s_setprio(1);
        #pragma unroll
        for (int st = 0; st < 2; ++st) {
            int t = st*16 + lr;
            half8 kA0 = *(const half8*)(sKb + ((t*128 +      lk*16) ^ ((t&7)<<4)));
            half8 kA1 = *(const half8*)(sKb + ((t*128 + 64 + lk*16) ^ ((t&7)<<4)));
            f32x4 s = __builtin_amdgcn_mfma_f32_16x16x32_f16(kA0, qB[0], Z4, 0, 0, 0);
            S[st]   = __builtin_amdgcn_mfma_f32_16x16x32_f16(kA1, qB[1], s,  0, 0, 0);
        }
        __builtin_amdgcn_s_setprio(0);

        // ---- row max ----
        float m0 = fmaxf(fmaxf(S[0][0], S[0][1]), fmaxf(S[0][2], S[0][3]));
        float m1 = fmaxf(fmaxf(S[1][0], S[1][1]), fmaxf(S[1][2], S[1][3]));
        float pm = fmaxf(m0, m1);
        pm = fmaxf(pm, __shfl_xor(pm, 16));
        pm = fmaxf(pm, __shfl_xor(pm, 32));

        // ---- defer-max THR=8 (exp2 domain) ----
        if (__any(pm > mM + 8.0f)) {
            float mn = fmaxf(mM, pm);
            float fs = exp2f(mM - mn);
            mM = mn;
            #pragma unroll
            for (int cs = 0; cs < 4; ++cs)
                #pragma unroll
                for (int r = 0; r < 4; ++r) O[cs][r] *= fs;
            #pragma unroll
            for (int r = 0; r < 4; ++r) lacc[r] *= fs;
        }

        // ---- p = exp2(S - mM), pack pairs ----
        #pragma unroll
        for (int st = 0; st < 2; ++st)
            #pragma unroll
            for (int r = 0; r < 4; ++r)
                S[st][r] = exp2f(S[st][r] - mM);

        unsigned int pk2[2][2];
        #pragma unroll
        for (int st = 0; st < 2; ++st) {
            pk2[st][0] = __builtin_bit_cast(unsigned int,
                             __builtin_amdgcn_cvt_pkrtz(S[st][0], S[st][1]));
            pk2[st][1] = __builtin_bit_cast(unsigned int,
                             __builtin_amdgcn_cvt_pkrtz(S[st][2], S[st][3]));
        }

        // ---- pb redistribution ----
        int srcA = lr + 32*(lk & 1);
        int sel  = lk >> 1;
        union { unsigned int u[4]; half8 h; } pb;
        #pragma unroll
        for (int w2 = 0; w2 < 4; ++w2) {
            int src = srcA + 16*(w2 >> 1);
            int lo = __shfl((int)pk2[0][w2 & 1], src);
            int hi = __shfl((int)pk2[1][w2 & 1], src);
            pb.u[w2] = (unsigned int)(sel ? hi : lo);
        }

        // ---- PV swapped + l via ones-row MFMA ----
        __builtin_amdgcn_s_setprio(1);
        lacc = __builtin_amdgcn_mfma_f32_16x16x32_f16(ones, pb.h, lacc, 0, 0, 0);
        #pragma unroll
        for (int cs = 0; cs < 4; ++cs) {
            int crow = cs*16 + lr;
            half8 vA = *(const half8*)(sVb + ((crow*64 + lk*16) ^ ((crow&3)<<4)));
            O[cs] = __builtin_amdgcn_mfma_f32_16x16x32_f16(vA, pb.h, O[cs], 0, 0, 0);
        }
        __builtin_amdgcn_s_setprio(0);

        asm volatile("s_waitcnt vmcnt(0)" ::: "memory");
        __builtin_amdgcn_s_barrier();
    }

    if (lk == 0) {
        ml[q0 + w*16 + lr]       = mM;
        ml[TOK + q0 + w*16 + lr] = lacc[0];
    }

    // ---- epilogue: two 64-q halves through 17.4KB ldsf ----
    #pragma unroll
    for (int h = 0; h < 2; ++h) {
        if ((w >> 2) == h) {
            #pragma unroll
            for (int cs = 0; cs < 4; ++cs)
                #pragma unroll
                for (int r = 0; r < 4; ++r)
                    ldsf[(cs*16 + 4*lk + r)*68 + wq*16 + lr] = O[cs][r];
        }
        __syncthreads();
        int c = tid >> 3, qs = (tid & 7) * 8;
        const float* srcr = &ldsf[c*68 + qs];
        float* dstr = &part[(size_t)c*TOK + q0 + h*64 + qs];
        *(float4*)&dstr[0] = *(const float4*)&srcr[0];
        *(float4*)&dstr[4] = *(const float4*)&srcr[4];
        __syncthreads();
    }
}

// ---------------- recombine KV-split partials (exp2 domain, float4 over t) ----------------
__global__ __launch_bounds__(256) void recombine_kernel(
    const float* __restrict__ ws, float* __restrict__ out)
{
    int gid = blockIdx.x * 256 + threadIdx.x;   // 72*256 = 18432
    int b   = gid / 9216;
    int rem = gid % 9216;
    int cg  = rem / 2304;
    int t   = (rem % 2304) * 4;
    const float* mlp = ws + OFF_ML2;

    float4 m4[KSPLIT], l4[KSPLIT];
    float4 M = {-INFINITY, -INFINITY, -INFINITY, -INFINITY};
    #pragma unroll
    for (int ks = 0; ks < KSPLIT; ++ks) {
        int slab = b*KSPLIT + ks;
        m4[ks] = *(const float4*)&mlp[(size_t)slab*2*TOK + t];
        l4[ks] = *(const float4*)&mlp[(size_t)slab*2*TOK + TOK + t];
        M.x = fmaxf(M.x, m4[ks].x); M.y = fmaxf(M.y, m4[ks].y);
        M.z = fmaxf(M.z, m4[ks].z); M.w = fmaxf(M.w, m4[ks].w);
    }
    float4 wgt[KSPLIT];
    float4 den = {0.f, 0.f, 0.f, 0.f};
    #pragma unroll
    for (int ks = 0; ks < KSPLIT; ++ks) {
        wgt[ks].x = exp2f(m4[ks].x - M.x); wgt[ks].y = exp2f(m4[ks].y - M.y);
        wgt[ks].z = exp2f(m4[ks].z - M.z); wgt[ks].w = exp2f(m4[ks].w - M.w);
        den.x += l4[ks].x * wgt[ks].x; den.y += l4[ks].y * wgt[ks].y;
        den.z += l4[ks].z * wgt[ks].z; den.w += l4[ks].w * wgt[ks].w;
    }
    float4 inv = {1.f/den.x, 1.f/den.y, 1.f/den.z, 1.f/den.w};
    #pragma unroll
    for (int cc = 0; cc < 16; ++cc) {
        int c = cg*16 + cc;
        float4 acc = {0.f, 0.f, 0.f, 0.f};
        #pragma unroll
        for (int ks = 0; ks < KSPLIT; ++ks) {
            const float* part = part_base_c(ws, b*KSPLIT + ks);
            float4 p4 = *(const float4*)&part[(size_t)c*TOK + t];
            acc.x += p4.x * wgt[ks].x; acc.y += p4.y * wgt[ks].y;
            acc.z += p4.z * wgt[ks].z; acc.w += p4.w * wgt[ks].w;
        }
        float4 o4 = {acc.x*inv.x, acc.y*inv.y, acc.z*inv.z, acc.w*inv.w};
        *(float4*)&out[(size_t)(b*64 + c)*TOK + t] = o4;
    }
}

extern "C" void kernel_launch(void* const* d_in, const int* in_sizes, int n_in,
                              void* d_out, int out_size, void* d_ws, size_t ws_size,
                              hipStream_t stream)
{
    const float* frames = (const float*)d_in[0];
    const float* w1 = (const float*)d_in[1];
    const float* b1 = (const float*)d_in[2];
    const float* w2 = (const float*)d_in[3];
    const float* b2 = (const float*)d_in[4];
    const float* qw = (const float*)d_in[5];
    const float* qb = (const float*)d_in[6];
    const float* kw = (const float*)d_in[7];
    const float* kb = (const float*)d_in[8];
    const float* vw = (const float*)d_in[9];
    const float* vb = (const float*)d_in[10];
    float* ws = (float*)d_ws;
    float* out = (float*)d_out;

    hipLaunchKernelGGL(conv1_kernel, dim3(144), dim3(256), 0, stream,
                       frames, w1, b1, w2, b2, qw, qb, kw, kb, vw, vb, ws);
    hipLaunchKernelGGL(conv2_kernel, dim3(576), dim3(256), 0, stream, ws);
    hipLaunchKernelGGL(qkvgemm_kernel, dim3(576), dim3(256), 0, stream, ws);
    hipLaunchKernelGGL(attn_kernel, dim3(2*72*KSPLIT), dim3(512), 0, stream, ws);
    hipLaunchKernelGGL(recombine_kernel, dim3(72), dim3(256), 0, stream, ws, out);
}

// Round 19
// 157.387 us; speedup vs baseline: 3.2934x; 1.0801x over previous
//
#include <hip/hip_runtime.h>
#include <hip/hip_bf16.h>

#define TOK 9216   // 96*96 tokens per image
#define KSPLIT 5

typedef _Float16 half8 __attribute__((ext_vector_type(8)));
typedef float f32x4 __attribute__((ext_vector_type(4)));

// global_load_lds: 16B per lane, linear LDS dest (wave-uniform base + lane*16)
#define GLOAD_LDS(g, l) \
    __builtin_amdgcn_global_load_lds((const __attribute__((address_space(1))) void*)(g), \
                                     (__attribute__((address_space(3))) void*)(l), 16, 0, 0)

#define QSCALE 0.18033688011112042f   // 0.125 * log2(e); softmax runs in exp2 domain

// ---------------- workspace layout (in floats) ----------------
#define OFF_F1   0u                      // conv1 out: f16 [img][t][64] (1.18M f32 slots)
#define SZ_F1    (4u*64u*TOK)
#define OFF_FEAT (OFF_F1 + SZ_F1)        // conv2 out: f16 [img][t][64]
#define SZ_FEAT  (2u*128u*TOK)
#define OFF_W1   (OFF_FEAT + SZ_FEAT + 3u*2u*64u*TOK)   // (dead regions preserved)
#define OFF_B1   (OFF_W1 + 576u)
#define OFF_W2T  (OFF_B1 + 64u)          // WCONV f16 [64 co][576 k], k=tap*64+ci
#define OFF_B2   (OFF_W2T + 36864u)
#define OFF_WCAT (OFF_B2 + 64u)          // [192][128] f16, col k = n*64+c (q rows scaled)
#define OFF_BCAT (OFF_WCAT + 24576u)     // [192] f32 (qb scaled)

// f16 QKV overlaid on F1 (f1h dead after conv2). Offsets in f32 units.
#define OFF_QT   OFF_F1                  // [b][t][64] f16, scale folded
#define OFF_KT   (OFF_F1 + 589824u)      // [b][t][64] f16
#define OFF_VH   (OFF_F1 + 1179648u)     // [b][64][t] f16, ends at 1769472

// KV-split partials: 10 slabs of 64*TOK f32 each (589824 floats).
#define OFF_SLAB0 1769472u
#define OFF_ML2   (OFF_FEAT + 9u*589824u)   // [slab][2 (m,l)][TOK] f32

__device__ __forceinline__ const float* part_base_c(const float* ws, int slab) {
    return ws + (slab == 0 ? OFF_SLAB0 : (OFF_FEAT + (unsigned)(slab - 1) * 589824u));
}
__device__ __forceinline__ float* part_base(float* ws, int slab) {
    return ws + (slab == 0 ? OFF_SLAB0 : (OFF_FEAT + (unsigned)(slab - 1) * 589824u));
}

// ---------------- conv1 (+ merged weight prep): 1->64 ch, 3x3, relu; f16 channel-last ----
__global__ __launch_bounds__(256) void conv1_kernel(
    const float* __restrict__ x,
    const float* __restrict__ w1, const float* __restrict__ b1,
    const float* __restrict__ w2, const float* __restrict__ b2,
    const float* __restrict__ qw, const float* __restrict__ qb,
    const float* __restrict__ kw, const float* __restrict__ kb,
    const float* __restrict__ vw, const float* __restrict__ vb,
    float* __restrict__ ws)
{
    int gid = blockIdx.x * 256 + threadIdx.x;   // 144*256 = 36864

    // ---- merged prep (weights for conv2 / qkvgemm) ----
    if (gid < 64) ws[OFF_B2 + gid] = b2[gid];
    if (gid < 36864) {   // WCONV f16: [co][tap*64+ci] <- w2[co][ci][tap]
        int co = gid / 576; int rem = gid % 576;
        int ci = rem / 9;  int tp = rem % 9;
        ((_Float16*)(ws + OFF_W2T))[co*576 + tp*64 + ci] = (_Float16)w2[gid];
    }
    if (gid < 24576) {   // WCAT f16, col k = n*64+c <- source col c*2+n; q rows scaled
        int o = gid >> 7; int kidx = gid & 127;
        int n = kidx >> 6, c = kidx & 63;
        int sc = c*2 + n;
        float v;
        if (o < 64)       v = qw[o*128 + sc] * QSCALE;
        else if (o < 128) v = kw[(o-64)*128 + sc];
        else              v = vw[(o-128)*128 + sc];
        ((_Float16*)(ws + OFF_WCAT))[gid] = (_Float16)v;
    }
    if (gid < 192) {
        float v;
        if (gid < 64)       v = qb[gid] * QSCALE;
        else if (gid < 128) v = kb[gid-64];
        else                v = vb[gid-128];
        ws[OFF_BCAT + gid] = v;
    }

    // ---- conv1 (reads w1/b1 raw) ----
    _Float16* f1h = (_Float16*)(ws + OFF_F1);
    int img = gid / TOK;
    int p   = gid % TOK;
    int h = p / 96, w = p % 96;
    float xv[9];
    #pragma unroll
    for (int dh = 0; dh < 3; ++dh)
        #pragma unroll
        for (int dw = 0; dw < 3; ++dw) {
            int r = h + dh - 1, c = w + dw - 1;
            bool ok = (r >= 0) && (r < 96) && (c >= 0) && (c < 96);
            xv[dh*3 + dw] = ok ? x[img*TOK + r*96 + c] : 0.f;
        }
    _Float16* dst = f1h + (size_t)gid * 64;     // [img][p][64], 128B contiguous
    #pragma unroll
    for (int g8 = 0; g8 < 8; ++g8) {
        union { _Float16 h[8]; uint4 u; } pk8;
        #pragma unroll
        for (int j = 0; j < 8; ++j) {
            int co = g8*8 + j;
            float a = b1[co];
            #pragma unroll
            for (int t = 0; t < 9; ++t) a += w1[co*9 + t] * xv[t];
            pk8.h[j] = (_Float16)fmaxf(a, 0.f);
        }
        *(uint4*)&dst[g8*8] = pk8.u;
    }
}

// ---------------- conv2 as MFMA im2col GEMM: f1h -> featH2 [img][t][64] ----------------
__global__ __launch_bounds__(256) void conv2_kernel(float* __restrict__ ws)
{
    int bid = blockIdx.x;            // 4 img * 144
    int img = bid & 3;
    int tile = bid >> 2;
    int tid = threadIdx.x;
    int lane = tid & 63, w = tid >> 6;
    int lr = lane & 15, lk = lane >> 4;

    const _Float16* f1h = (const _Float16*)(ws + OFF_F1) + (size_t)img*TOK*64;
    const _Float16* Wc  = (const _Float16*)(ws + OFF_W2T);   // [64][576]
    const float* b2f = ws + OFF_B2;

    int t = tile*64 + w*16 + lr;
    int h = t / 96, wc = t % 96;

    half8 z8;
    #pragma unroll
    for (int i = 0; i < 8; ++i) z8[i] = (_Float16)0.f;

    f32x4 acc[4];
    #pragma unroll
    for (int cs = 0; cs < 4; ++cs) {
        float bv = b2f[cs*16 + lr];
        acc[cs] = (f32x4){bv, bv, bv, bv};
    }

    #pragma unroll
    for (int ch = 0; ch < 18; ++ch) {
        int k = ch*32 + lk*8;
        int tap = k >> 6, ci = k & 63;
        int dh = tap / 3, dw = tap % 3;
        int r = h + dh - 1, c = wc + dw - 1;
        half8 af = z8;
        if ((unsigned)r < 96u && (unsigned)c < 96u)
            af = *(const half8*)&f1h[(size_t)(r*96 + c)*64 + ci];
        #pragma unroll
        for (int cs = 0; cs < 4; ++cs) {
            half8 bfr = *(const half8*)&Wc[(size_t)(cs*16 + lr)*576 + k];
            acc[cs] = __builtin_amdgcn_mfma_f32_16x16x32_f16(af, bfr, acc[cs], 0, 0, 0);
        }
    }

    _Float16* featH2 = (_Float16*)(ws + OFF_FEAT) + (size_t)img*TOK*64;
    int tbase = tile*64 + w*16 + 4*lk;
    #pragma unroll
    for (int cs = 0; cs < 4; ++cs)
        #pragma unroll
        for (int r = 0; r < 4; ++r)
            featH2[(size_t)(tbase + r)*64 + cs*16 + lr] = (_Float16)fmaxf(acc[cs][r], 0.f);
}

// ---------------- fused QKV GEMM (MFMA, all-register): featH2 -> QT/KT/VH ----------------
__global__ __launch_bounds__(256) void qkvgemm_kernel(float* __restrict__ ws)
{
    int bid = blockIdx.x;            // 2 * 288
    int b   = bid / 288;
    int tt0 = (bid % 288) * 32;
    int tid = threadIdx.x;
    int lane = tid & 63, w = tid >> 6;
    int lr = lane & 15, lk = lane >> 4;

    const _Float16* fH = (const _Float16*)(ws + OFF_FEAT) + (size_t)b*2*TOK*64;
    const _Float16* W  = (const _Float16*)(ws + OFF_WCAT);
    const float* bc = ws + OFF_BCAT;
    _Float16* QT = (_Float16*)(ws + OFF_QT) + (size_t)b*TOK*64;
    _Float16* KT = (_Float16*)(ws + OFF_KT) + (size_t)b*TOK*64;
    _Float16* VH = (_Float16*)(ws + OFF_VH) + (size_t)b*64*TOK;

    half8 bf[2][4];
    #pragma unroll
    for (int tt = 0; tt < 2; ++tt)
        #pragma unroll
        for (int kc = 0; kc < 4; ++kc) {
            int k = kc*32 + lk*8;
            bf[tt][kc] = *(const half8*)&fH[(size_t)(k >> 6)*TOK*64
                                            + (size_t)(tt0 + tt*16 + lr)*64 + (k & 63)];
        }

    half8 af[3][4];
    #pragma unroll
    for (int i = 0; i < 3; ++i)
        #pragma unroll
        for (int kc = 0; kc < 4; ++kc)
            af[i][kc] = *(const half8*)&W[(size_t)((w*3 + i)*16 + lr)*128 + kc*32 + lk*8];

    #pragma unroll
    for (int i = 0; i < 3; ++i) {
        int ot = w*3 + i;
        f32x4 a0, a1;
        #pragma unroll
        for (int r = 0; r < 4; ++r) {
            float bv = bc[ot*16 + 4*lk + r];
            a0[r] = bv; a1[r] = bv;
        }
        #pragma unroll
        for (int kc = 0; kc < 4; ++kc) {
            a0 = __builtin_amdgcn_mfma_f32_16x16x32_f16(af[i][kc], bf[0][kc], a0, 0, 0, 0);
            a1 = __builtin_amdgcn_mfma_f32_16x16x32_f16(af[i][kc], bf[1][kc], a1, 0, 0, 0);
        }
        #pragma unroll
        for (int tt = 0; tt < 2; ++tt) {
            f32x4 a = tt ? a1 : a0;
            int t = tt0 + tt*16 + lr;
            if (ot < 4) {
                union { _Float16 h[4]; uint2 u; } p;
                #pragma unroll
                for (int r = 0; r < 4; ++r) p.h[r] = (_Float16)a[r];
                *(uint2*)&QT[(size_t)t*64 + ot*16 + 4*lk] = p.u;
            } else if (ot < 8) {
                union { _Float16 h[4]; uint2 u; } p;
                #pragma unroll
                for (int r = 0; r < 4; ++r) p.h[r] = (_Float16)a[r];
                *(uint2*)&KT[(size_t)t*64 + (ot-4)*16 + 4*lk] = p.u;
            } else {
                #pragma unroll
                for (int r = 0; r < 4; ++r)
                    VH[(size_t)((ot-8)*16 + 4*lk + r)*TOK + t] = (_Float16)a[r];
            }
        }
    }
}

// ---------------- flash attention partial: 8 waves x 128q, KVBLK=64 ----------------
// grid = 2b x 72qt x KSPLIT; 512 thr. Each wave stages 8 K-rows + 8 V-rows (2 gloads).
// K LDS [64 kt][64 d] swz ^((row&7)<<4); V LDS [64 d][64 kt] swz ^((row&7)<<4)
// (both 128B rows, conflict-free). 1 barrier/iter, counted-drain, dbuf.
__global__ __launch_bounds__(512, 6) void attn_kernel(float* __restrict__ ws)
{
    __shared__ __align__(16) char smem[32768];   // K0|K1|V0|V1 (4x8KB); epilogue f32 [64][68]
    float* ldsf = (float*)smem;

    int bid = blockIdx.x;       // 2 * 72 * KSPLIT = 720
    int b   = bid / (72*KSPLIT);
    int rem = bid % (72*KSPLIT);
    int qt  = rem / KSPLIT;
    int ks  = rem % KSPLIT;
    int tid = threadIdx.x;
    int lane = tid & 63, w = tid >> 6;          // 8 waves
    int wq = w & 3;
    int q0 = qt * 128;
    int lr = lane & 15;
    int lk = lane >> 4;

    int kb0 = (ks*144)/KSPLIT, kb1 = ((ks+1)*144)/KSPLIT;   // 64-wide kt tiles
    int nit = kb1 - kb0;
    int slab = b*KSPLIT + ks;

    const _Float16* Qt = (const _Float16*)(ws + OFF_QT) + (size_t)b*TOK*64;
    const _Float16* Kt = (const _Float16*)(ws + OFF_KT) + (size_t)b*TOK*64;
    const _Float16* Vh = (const _Float16*)(ws + OFF_VH) + (size_t)b*64*TOK;
    float* part = part_base(ws, slab);
    float* ml   = ws + OFF_ML2 + (size_t)slab*2*TOK;

    half8 qB[2];
    #pragma unroll
    for (int ch = 0; ch < 2; ++ch)
        qB[ch] = *(const half8*)&Qt[(size_t)(q0 + w*16 + lr)*64 + ch*32 + lk*8];

    const f32x4 Z4 = (f32x4){0.f, 0.f, 0.f, 0.f};
    half8 ones;
    #pragma unroll
    for (int i = 0; i < 8; ++i) ones[i] = (_Float16)1.0f;

    f32x4 O[4];
    #pragma unroll
    for (int cs = 0; cs < 4; ++cs) O[cs] = Z4;
    f32x4 lacc = Z4;
    float mM = -INFINITY;

    // staging geometry (rule #21: linear dest, inverse-swizzled source).
    // Each wave stages rows w*8 .. w*8+7 of BOTH K (128B rows) and V (128B rows).
    int segl = ((lane & 7) ^ ((lane >> 3) & 7)) * 8;        // 16B seg within 128B row
    int rrow = w*8 + (lane >> 3);                           // 0..63
    unsigned kOff = (unsigned)(kb0*64 + rrow)*64u + (unsigned)segl;   // +4096/iter
    unsigned vOff = (unsigned)rrow*(unsigned)TOK + (unsigned)(kb0*64) + (unsigned)segl; // +64/iter
    unsigned wbase = (unsigned)(w * 1024);

    // prologue: stage tile kb0 into buf0
    GLOAD_LDS(Kt + kOff, smem +         wbase);
    GLOAD_LDS(Vh + vOff, smem + 16384 + wbase);
    asm volatile("s_waitcnt vmcnt(0)" ::: "memory");
    __builtin_amdgcn_s_barrier();

    for (int it = 0; it < nit; ++it) {
        char* sKb = smem +         (it & 1) * 8192;
        char* sVb = smem + 16384 + (it & 1) * 8192;

        if (it + 1 < nit) {
            unsigned bufo = (unsigned)(((it + 1) & 1) * 8192) + wbase;
            GLOAD_LDS(Kt + kOff + (unsigned)(it + 1) * 4096u, smem + bufo);
            GLOAD_LDS(Vh + vOff + (unsigned)(it + 1) * 64u,   smem + 16384 + bufo);
        }

        // ---- QK^T swapped: S^T[kt 64][q 16]; lane q=lr, kt = st*16 + 4*lk + r ----
        f32x4 S[4];
        __builtin_amdgcn_s_setprio(1);
        #pragma unroll
        for (int st = 0; st < 4; ++st) {
            int t = st*16 + lr;
            half8 kA0 = *(const half8*)(sKb + ((t*128 +      lk*16) ^ ((t&7)<<4)));
            half8 kA1 = *(const half8*)(sKb + ((t*128 + 64 + lk*16) ^ ((t&7)<<4)));
            f32x4 s = __builtin_amdgcn_mfma_f32_16x16x32_f16(kA0, qB[0], Z4, 0, 0, 0);
            S[st]   = __builtin_amdgcn_mfma_f32_16x16x32_f16(kA1, qB[1], s,  0, 0, 0);
        }
        __builtin_amdgcn_s_setprio(0);

        // ---- row max via max3-friendly tree (16 vals) ----
        float a0 = fmaxf(fmaxf(S[0][0], S[0][1]), S[0][2]);
        float a1 = fmaxf(fmaxf(S[0][3], S[1][0]), S[1][1]);
        float a2 = fmaxf(fmaxf(S[1][2], S[1][3]), S[2][0]);
        float a3 = fmaxf(fmaxf(S[2][1], S[2][2]), S[2][3]);
        float a4 = fmaxf(fmaxf(S[3][0], S[3][1]), S[3][2]);
        float pm = fmaxf(fmaxf(fmaxf(a0, a1), a2),
                         fmaxf(fmaxf(a3, a4), S[3][3]));
        pm = fmaxf(pm, __shfl_xor(pm, 16));
        pm = fmaxf(pm, __shfl_xor(pm, 32));

        // ---- defer-max THR=8 (exp2 domain) ----
        if (__any(pm > mM + 8.0f)) {
            float mn = fmaxf(mM, pm);
            float fs = exp2f(mM - mn);
            mM = mn;
            #pragma unroll
            for (int cs = 0; cs < 4; ++cs)
                #pragma unroll
                for (int r = 0; r < 4; ++r) O[cs][r] *= fs;
            #pragma unroll
            for (int r = 0; r < 4; ++r) lacc[r] *= fs;
        }

        // ---- p = exp2(S - mM), pack pairs via cvt_pkrtz ----
        #pragma unroll
        for (int st = 0; st < 4; ++st)
            #pragma unroll
            for (int r = 0; r < 4; ++r)
                S[st][r] = exp2f(S[st][r] - mM);

        unsigned int pk2[4][2];
        #pragma unroll
        for (int st = 0; st < 4; ++st) {
            pk2[st][0] = __builtin_bit_cast(unsigned int,
                             __builtin_amdgcn_cvt_pkrtz(S[st][0], S[st][1]));
            pk2[st][1] = __builtin_bit_cast(unsigned int,
                             __builtin_amdgcn_cvt_pkrtz(S[st][2], S[st][3]));
        }

        // ---- PV swapped + l via ones-row MFMA; pb per ch2 (r13-verified formula) ----
        int srcA = lr + 32*(lk & 1);
        int sel  = lk >> 1;
        __builtin_amdgcn_s_setprio(1);
        #pragma unroll
        for (int ch2 = 0; ch2 < 2; ++ch2) {
            union { unsigned int u[4]; half8 h; } pb;
            #pragma unroll
            for (int w2 = 0; w2 < 4; ++w2) {
                int src = srcA + 16*(w2 >> 1);
                int lo = __shfl((int)pk2[ch2*2 + 0][w2 & 1], src);
                int hi = __shfl((int)pk2[ch2*2 + 1][w2 & 1], src);
                pb.u[w2] = (unsigned int)(sel ? hi : lo);
            }
            lacc = __builtin_amdgcn_mfma_f32_16x16x32_f16(ones, pb.h, lacc, 0, 0, 0);
            #pragma unroll
            for (int cs = 0; cs < 4; ++cs) {
                int crow = cs*16 + lr;
                half8 vA = *(const half8*)(sVb + ((crow*128 + ch2*64 + lk*16) ^ ((crow&7)<<4)));
                O[cs] = __builtin_amdgcn_mfma_f32_16x16x32_f16(vA, pb.h, O[cs], 0, 0, 0);
            }
        }
        __builtin_amdgcn_s_setprio(0);

        asm volatile("s_waitcnt vmcnt(0)" ::: "memory");
        __builtin_amdgcn_s_barrier();
    }

    if (lk == 0) {
        ml[q0 + w*16 + lr]       = mM;
        ml[TOK + q0 + w*16 + lr] = lacc[0];
    }

    // ---- epilogue: two 64-q halves through ldsf ----
    #pragma unroll
    for (int h = 0; h < 2; ++h) {
        if ((w >> 2) == h) {
            #pragma unroll
            for (int cs = 0; cs < 4; ++cs)
                #pragma unroll
                for (int r = 0; r < 4; ++r)
                    ldsf[(cs*16 + 4*lk + r)*68 + wq*16 + lr] = O[cs][r];
        }
        __syncthreads();
        int c = tid >> 3, qs = (tid & 7) * 8;
        const float* srcr = &ldsf[c*68 + qs];
        float* dstr = &part[(size_t)c*TOK + q0 + h*64 + qs];
        *(float4*)&dstr[0] = *(const float4*)&srcr[0];
        *(float4*)&dstr[4] = *(const float4*)&srcr[4];
        __syncthreads();
    }
}

// ---------------- recombine KV-split partials (exp2 domain, float4 over t) ----------------
__global__ __launch_bounds__(256) void recombine_kernel(
    const float* __restrict__ ws, float* __restrict__ out)
{
    int gid = blockIdx.x * 256 + threadIdx.x;   // 72*256 = 18432
    int b   = gid / 9216;
    int rem = gid % 9216;
    int cg  = rem / 2304;
    int t   = (rem % 2304) * 4;
    const float* mlp = ws + OFF_ML2;

    float4 m4[KSPLIT], l4[KSPLIT];
    float4 M = {-INFINITY, -INFINITY, -INFINITY, -INFINITY};
    #pragma unroll
    for (int ks = 0; ks < KSPLIT; ++ks) {
        int slab = b*KSPLIT + ks;
        m4[ks] = *(const float4*)&mlp[(size_t)slab*2*TOK + t];
        l4[ks] = *(const float4*)&mlp[(size_t)slab*2*TOK + TOK + t];
        M.x = fmaxf(M.x, m4[ks].x); M.y = fmaxf(M.y, m4[ks].y);
        M.z = fmaxf(M.z, m4[ks].z); M.w = fmaxf(M.w, m4[ks].w);
    }
    float4 wgt[KSPLIT];
    float4 den = {0.f, 0.f, 0.f, 0.f};
    #pragma unroll
    for (int ks = 0; ks < KSPLIT; ++ks) {
        wgt[ks].x = exp2f(m4[ks].x - M.x); wgt[ks].y = exp2f(m4[ks].y - M.y);
        wgt[ks].z = exp2f(m4[ks].z - M.z); wgt[ks].w = exp2f(m4[ks].w - M.w);
        den.x += l4[ks].x * wgt[ks].x; den.y += l4[ks].y * wgt[ks].y;
        den.z += l4[ks].z * wgt[ks].z; den.w += l4[ks].w * wgt[ks].w;
    }
    float4 inv = {1.f/den.x, 1.f/den.y, 1.f/den.z, 1.f/den.w};
    #pragma unroll
    for (int cc = 0; cc < 16; ++cc) {
        int c = cg*16 + cc;
        float4 acc = {0.f, 0.f, 0.f, 0.f};
        #pragma unroll
        for (int ks = 0; ks < KSPLIT; ++ks) {
            const float* part = part_base_c(ws, b*KSPLIT + ks);
            float4 p4 = *(const float4*)&part[(size_t)c*TOK + t];
            acc.x += p4.x * wgt[ks].x; acc.y += p4.y * wgt[ks].y;
            acc.z += p4.z * wgt[ks].z; acc.w += p4.w * wgt[ks].w;
        }
        float4 o4 = {acc.x*inv.x, acc.y*inv.y, acc.z*inv.z, acc.w*inv.w};
        *(float4*)&out[(size_t)(b*64 + c)*TOK + t] = o4;
    }
}

extern "C" void kernel_launch(void* const* d_in, const int* in_sizes, int n_in,
                              void* d_out, int out_size, void* d_ws, size_t ws_size,
                              hipStream_t stream)
{
    const float* frames = (const float*)d_in[0];
    const float* w1 = (const float*)d_in[1];
    const float* b1 = (const float*)d_in[2];
    const float* w2 = (const float*)d_in[3];
    const float* b2 = (const float*)d_in[4];
    const float* qw = (const float*)d_in[5];
    const float* qb = (const float*)d_in[6];
    const float* kw = (const float*)d_in[7];
    const float* kb = (const float*)d_in[8];
    const float* vw = (const float*)d_in[9];
    const float* vb = (const float*)d_in[10];
    float* ws = (float*)d_ws;
    float* out = (float*)d_out;

    hipLaunchKernelGGL(conv1_kernel, dim3(144), dim3(256), 0, stream,
                       frames, w1, b1, w2, b2, qw, qb, kw, kb, vw, vb, ws);
    hipLaunchKernelGGL(conv2_kernel, dim3(576), dim3(256), 0, stream, ws);
    hipLaunchKernelGGL(qkvgemm_kernel, dim3(576), dim3(256), 0, stream, ws);
    hipLaunchKernelGGL(attn_kernel, dim3(2*72*KSPLIT), dim3(512), 0, stream, ws);
    hipLaunchKernelGGL(recombine_kernel, dim3(72), dim3(256), 0, stream, ws, out);
}

// Round 21
// 156.898 us; speedup vs baseline: 3.3037x; 1.0031x over previous
//
#include <hip/hip_runtime.h>
#include <hip/hip_bf16.h>

#define TOK 9216   // 96*96 tokens per image
#define KSPLIT 5

typedef _Float16 half8 __attribute__((ext_vector_type(8)));
typedef float f32x4 __attribute__((ext_vector_type(4)));

// global_load_lds: 16B per lane, linear LDS dest (wave-uniform base + lane*16)
#define GLOAD_LDS(g, l) \
    __builtin_amdgcn_global_load_lds((const __attribute__((address_space(1))) void*)(g), \
                                     (__attribute__((address_space(3))) void*)(l), 16, 0, 0)

#define QSCALE 0.18033688011112042f   // 0.125 * log2(e); softmax runs in exp2 domain

// ---------------- workspace layout (in floats) ----------------
// [0, 2359296)        F1: conv1 out f16 [img][t][64]   (dead after conv2qkv ph1)
// [2359296, 4718592)  FEAT region (feat now LDS-internal; dead)
// [4718592, 6488064)  QT | KT | VH  (f16; written conv2qkv ph2, read attn)
// [0, 4718592)        slabs 0-7 (attn partials; F1+FEAT dead by then)
// [6488064, 7667712)  slabs 8-9
// [7667712, 7852032)  ML2
// [8257536, ...)      weights (W2T/B2/WCAT/BCAT)
#define OFF_F1   0u
#define SZ_F1    (4u*64u*TOK)            // 2359296
#define OFF_FEAT (OFF_F1 + SZ_F1)
#define SZ_FEAT  (2u*128u*TOK)           // 2359296
#define OFF_W1   (OFF_FEAT + SZ_FEAT + 3u*2u*64u*TOK)   // 8257536
#define OFF_B1   (OFF_W1 + 576u)
#define OFF_W2T  (OFF_B1 + 64u)          // WCONV f16 [64 co][576 k], k=tap*64+ci
#define OFF_B2   (OFF_W2T + 36864u)
#define OFF_WCAT (OFF_B2 + 64u)          // [192][128] f16, col k = n*64+c (q rows scaled)
#define OFF_BCAT (OFF_WCAT + 24576u)     // [192] f32 (qb scaled)

// QKV in their own region — NO overlap with F1 (fixes r20 cross-block race).
#define OFF_QT   4718592u                // [b][t][64] f16, scale folded
#define OFF_KT   5308416u                // [b][t][64] f16
#define OFF_VH   5898240u                // [b][64][t] f16, ends at 6488064

#define OFF_ML2  (OFF_FEAT + 9u*589824u) // 7667712: [slab][2 (m,l)][TOK] f32

__device__ __forceinline__ const float* part_base_c(const float* ws, int slab) {
    return ws + (slab < 8 ? (unsigned)slab * 589824u
                          : 6488064u + (unsigned)(slab - 8) * 589824u);
}
__device__ __forceinline__ float* part_base(float* ws, int slab) {
    return ws + (slab < 8 ? (unsigned)slab * 589824u
                          : 6488064u + (unsigned)(slab - 8) * 589824u);
}

// ---------------- conv1 (+ merged weight prep): 1->64 ch, 3x3, relu; f16 channel-last ----
// grid 288x256: 2 threads per pixel (32 channels each).
__global__ __launch_bounds__(256) void conv1_kernel(
    const float* __restrict__ x,
    const float* __restrict__ w1, const float* __restrict__ b1,
    const float* __restrict__ w2, const float* __restrict__ b2,
    const float* __restrict__ qw, const float* __restrict__ qb,
    const float* __restrict__ kw, const float* __restrict__ kb,
    const float* __restrict__ vw, const float* __restrict__ vb,
    float* __restrict__ ws)
{
    int gid = blockIdx.x * 256 + threadIdx.x;   // 288*256 = 73728

    // ---- merged prep (each element written by exactly one thread) ----
    if (gid < 64) ws[OFF_B2 + gid] = b2[gid];
    if (gid < 36864) {   // WCONV f16: [co][tap*64+ci] <- w2[co][ci][tap]
        int co = gid / 576; int rem = gid % 576;
        int ci = rem / 9;  int tp = rem % 9;
        ((_Float16*)(ws + OFF_W2T))[co*576 + tp*64 + ci] = (_Float16)w2[gid];
    }
    if (gid < 24576) {   // WCAT f16, col k = n*64+c <- source col c*2+n; q rows scaled
        int o = gid >> 7; int kidx = gid & 127;
        int n = kidx >> 6, c = kidx & 63;
        int sc = c*2 + n;
        float v;
        if (o < 64)       v = qw[o*128 + sc] * QSCALE;
        else if (o < 128) v = kw[(o-64)*128 + sc];
        else              v = vw[(o-128)*128 + sc];
        ((_Float16*)(ws + OFF_WCAT))[gid] = (_Float16)v;
    }
    if (gid < 192) {
        float v;
        if (gid < 64)       v = qb[gid] * QSCALE;
        else if (gid < 128) v = kb[gid-64];
        else                v = vb[gid-128];
        ws[OFF_BCAT + gid] = v;
    }

    // ---- conv1: 2 threads/pixel ----
    _Float16* f1h = (_Float16*)(ws + OFF_F1);
    int px = gid >> 1, half = gid & 1;
    int img = px / TOK;
    int p   = px % TOK;
    int h = p / 96, w = p % 96;
    float xv[9];
    #pragma unroll
    for (int dh = 0; dh < 3; ++dh)
        #pragma unroll
        for (int dw = 0; dw < 3; ++dw) {
            int r = h + dh - 1, c = w + dw - 1;
            bool ok = (r >= 0) && (r < 96) && (c >= 0) && (c < 96);
            xv[dh*3 + dw] = ok ? x[img*TOK + r*96 + c] : 0.f;
        }
    _Float16* dst = f1h + (size_t)px * 64 + half * 32;
    #pragma unroll
    for (int g8 = 0; g8 < 4; ++g8) {
        union { _Float16 h[8]; uint4 u; } pk8;
        #pragma unroll
        for (int j = 0; j < 8; ++j) {
            int co = half*32 + g8*8 + j;
            float a = b1[co];
            #pragma unroll
            for (int t = 0; t < 9; ++t) a += w1[co*9 + t] * xv[t];
            pk8.h[j] = (_Float16)fmaxf(a, 0.f);
        }
        *(uint4*)&dst[g8*8] = pk8.u;
    }
}

// ---------------- fused conv2 + QKV GEMM: f1h -> (LDS feat) -> QT/KT/VH ----------------
// grid = 2b x 144 token-tiles(64); 256 thr = 4 waves.
// Phase 1: conv2 im2col MFMA for both frames; D -> swizzled LDS tile [64 t][128 k] f16.
// Phase 2: qkv GEMM, B-frags from LDS; outputs to QT/KT/VH (disjoint from F1 -> race-free).
__global__ __launch_bounds__(256) void conv2qkv_kernel(float* __restrict__ ws)
{
    __shared__ __align__(16) char fT[16384];   // [64 t][128 k] f16, byte ^ ((t&7)<<4)

    int bid = blockIdx.x;            // 2b * 144
    int b   = bid / 144;
    int tile = bid % 144;
    int tid = threadIdx.x;
    int lane = tid & 63, w = tid >> 6;
    int lr = lane & 15, lk = lane >> 4;

    const _Float16* Wc  = (const _Float16*)(ws + OFF_W2T);   // [64][576]
    const float* b2f = ws + OFF_B2;

    int t = tile*64 + w*16 + lr;
    int h = t / 96, wc = t % 96;

    half8 z8;
    #pragma unroll
    for (int i = 0; i < 8; ++i) z8[i] = (_Float16)0.f;

    // ---- phase 1: conv2 for n = 0,1 ----
    #pragma unroll
    for (int n = 0; n < 2; ++n) {
        const _Float16* f1h = (const _Float16*)(ws + OFF_F1) + (size_t)(b*2 + n)*TOK*64;
        f32x4 acc[4];
        #pragma unroll
        for (int cs = 0; cs < 4; ++cs) {
            float bv = b2f[cs*16 + lr];
            acc[cs] = (f32x4){bv, bv, bv, bv};
        }
        #pragma unroll
        for (int ch = 0; ch < 18; ++ch) {
            int k = ch*32 + lk*8;
            int tap = k >> 6, ci = k & 63;
            int dh = tap / 3, dw = tap % 3;
            int r = h + dh - 1, c = wc + dw - 1;
            half8 af = z8;
            if ((unsigned)r < 96u && (unsigned)c < 96u)
                af = *(const half8*)&f1h[(size_t)(r*96 + c)*64 + ci];
            #pragma unroll
            for (int cs = 0; cs < 4; ++cs) {
                half8 bfr = *(const half8*)&Wc[(size_t)(cs*16 + lr)*576 + k];
                acc[cs] = __builtin_amdgcn_mfma_f32_16x16x32_f16(af, bfr, acc[cs], 0, 0, 0);
            }
        }
        // D -> LDS: row t_loc = w*16+4*lk+r, col = n*64 + cs*16 + lr (swizzled)
        #pragma unroll
        for (int cs = 0; cs < 4; ++cs)
            #pragma unroll
            for (int r = 0; r < 4; ++r) {
                int tl = w*16 + 4*lk + r;
                int off = tl*256 + (n*64 + cs*16 + lr)*2;
                *(_Float16*)(fT + (off ^ ((tl&7)<<4))) =
                    (_Float16)fmaxf(acc[cs][r], 0.f);
            }
    }
    __syncthreads();

    // ---- phase 2: qkv GEMM (B-frags from LDS) ----
    const _Float16* W  = (const _Float16*)(ws + OFF_WCAT);
    const float* bc = ws + OFF_BCAT;
    _Float16* QT = (_Float16*)(ws + OFF_QT) + (size_t)b*TOK*64;
    _Float16* KT = (_Float16*)(ws + OFF_KT) + (size_t)b*TOK*64;
    _Float16* VH = (_Float16*)(ws + OFF_VH) + (size_t)b*64*TOK;

    half8 bf[4][4];
    #pragma unroll
    for (int tt = 0; tt < 4; ++tt)
        #pragma unroll
        for (int kc = 0; kc < 4; ++kc) {
            int tl = tt*16 + lr;
            bf[tt][kc] = *(const half8*)(fT + ((tl*256 + kc*64 + lk*16) ^ ((tl&7)<<4)));
        }

    half8 af3[3][4];
    #pragma unroll
    for (int i = 0; i < 3; ++i)
        #pragma unroll
        for (int kc = 0; kc < 4; ++kc)
            af3[i][kc] = *(const half8*)&W[(size_t)((w*3 + i)*16 + lr)*128 + kc*32 + lk*8];

    #pragma unroll
    for (int i = 0; i < 3; ++i) {
        int ot = w*3 + i;
        f32x4 a[4];
        #pragma unroll
        for (int r = 0; r < 4; ++r) {
            float bv = bc[ot*16 + 4*lk + r];
            #pragma unroll
            for (int tt = 0; tt < 4; ++tt) a[tt][r] = bv;
        }
        #pragma unroll
        for (int kc = 0; kc < 4; ++kc)
            #pragma unroll
            for (int tt = 0; tt < 4; ++tt)
                a[tt] = __builtin_amdgcn_mfma_f32_16x16x32_f16(af3[i][kc], bf[tt][kc], a[tt], 0, 0, 0);
        #pragma unroll
        for (int tt = 0; tt < 4; ++tt) {
            int tg = tile*64 + tt*16 + lr;
            if (ot < 4) {
                union { _Float16 h[4]; uint2 u; } p;
                #pragma unroll
                for (int r = 0; r < 4; ++r) p.h[r] = (_Float16)a[tt][r];
                *(uint2*)&QT[(size_t)tg*64 + ot*16 + 4*lk] = p.u;
            } else if (ot < 8) {
                union { _Float16 h[4]; uint2 u; } p;
                #pragma unroll
                for (int r = 0; r < 4; ++r) p.h[r] = (_Float16)a[tt][r];
                *(uint2*)&KT[(size_t)tg*64 + (ot-4)*16 + 4*lk] = p.u;
            } else {
                #pragma unroll
                for (int r = 0; r < 4; ++r)
                    VH[(size_t)((ot-8)*16 + 4*lk + r)*TOK + tg] = (_Float16)a[tt][r];
            }
        }
    }
}

// ---------------- flash attention partial: 8 waves x 128q, KVBLK=64 (frozen r19) ----------------
__global__ __launch_bounds__(512, 6) void attn_kernel(float* __restrict__ ws)
{
    __shared__ __align__(16) char smem[32768];   // K0|K1|V0|V1 (4x8KB); epilogue f32 [64][68]
    float* ldsf = (float*)smem;

    int bid = blockIdx.x;       // 2 * 72 * KSPLIT = 720
    int b   = bid / (72*KSPLIT);
    int rem = bid % (72*KSPLIT);
    int qt  = rem / KSPLIT;
    int ks  = rem % KSPLIT;
    int tid = threadIdx.x;
    int lane = tid & 63, w = tid >> 6;          // 8 waves
    int wq = w & 3;
    int q0 = qt * 128;
    int lr = lane & 15;
    int lk = lane >> 4;

    int kb0 = (ks*144)/KSPLIT, kb1 = ((ks+1)*144)/KSPLIT;   // 64-wide kt tiles
    int nit = kb1 - kb0;
    int slab = b*KSPLIT + ks;

    const _Float16* Qt = (const _Float16*)(ws + OFF_QT) + (size_t)b*TOK*64;
    const _Float16* Kt = (const _Float16*)(ws + OFF_KT) + (size_t)b*TOK*64;
    const _Float16* Vh = (const _Float16*)(ws + OFF_VH) + (size_t)b*64*TOK;
    float* part = part_base(ws, slab);
    float* ml   = ws + OFF_ML2 + (size_t)slab*2*TOK;

    half8 qB[2];
    #pragma unroll
    for (int ch = 0; ch < 2; ++ch)
        qB[ch] = *(const half8*)&Qt[(size_t)(q0 + w*16 + lr)*64 + ch*32 + lk*8];

    const f32x4 Z4 = (f32x4){0.f, 0.f, 0.f, 0.f};
    half8 ones;
    #pragma unroll
    for (int i = 0; i < 8; ++i) ones[i] = (_Float16)1.0f;

    f32x4 O[4];
    #pragma unroll
    for (int cs = 0; cs < 4; ++cs) O[cs] = Z4;
    f32x4 lacc = Z4;
    float mM = -INFINITY;

    int segl = ((lane & 7) ^ ((lane >> 3) & 7)) * 8;
    int rrow = w*8 + (lane >> 3);
    unsigned kOff = (unsigned)(kb0*64 + rrow)*64u + (unsigned)segl;
    unsigned vOff = (unsigned)rrow*(unsigned)TOK + (unsigned)(kb0*64) + (unsigned)segl;
    unsigned wbase = (unsigned)(w * 1024);

    GLOAD_LDS(Kt + kOff, smem +         wbase);
    GLOAD_LDS(Vh + vOff, smem + 16384 + wbase);
    asm volatile("s_waitcnt vmcnt(0)" ::: "memory");
    __builtin_amdgcn_s_barrier();

    for (int it = 0; it < nit; ++it) {
        char* sKb = smem +         (it & 1) * 8192;
        char* sVb = smem + 16384 + (it & 1) * 8192;

        if (it + 1 < nit) {
            unsigned bufo = (unsigned)(((it + 1) & 1) * 8192) + wbase;
            GLOAD_LDS(Kt + kOff + (unsigned)(it + 1) * 4096u, smem + bufo);
            GLOAD_LDS(Vh + vOff + (unsigned)(it + 1) * 64u,   smem + 16384 + bufo);
        }

        f32x4 S[4];
        __builtin_amdgcn_s_setprio(1);
        #pragma unroll
        for (int st = 0; st < 4; ++st) {
            int t = st*16 + lr;
            half8 kA0 = *(const half8*)(sKb + ((t*128 +      lk*16) ^ ((t&7)<<4)));
            half8 kA1 = *(const half8*)(sKb + ((t*128 + 64 + lk*16) ^ ((t&7)<<4)));
            f32x4 s = __builtin_amdgcn_mfma_f32_16x16x32_f16(kA0, qB[0], Z4, 0, 0, 0);
            S[st]   = __builtin_amdgcn_mfma_f32_16x16x32_f16(kA1, qB[1], s,  0, 0, 0);
        }
        __builtin_amdgcn_s_setprio(0);

        float a0 = fmaxf(fmaxf(S[0][0], S[0][1]), S[0][2]);
        float a1 = fmaxf(fmaxf(S[0][3], S[1][0]), S[1][1]);
        float a2 = fmaxf(fmaxf(S[1][2], S[1][3]), S[2][0]);
        float a3 = fmaxf(fmaxf(S[2][1], S[2][2]), S[2][3]);
        float a4 = fmaxf(fmaxf(S[3][0], S[3][1]), S[3][2]);
        float pm = fmaxf(fmaxf(fmaxf(a0, a1), a2),
                         fmaxf(fmaxf(a3, a4), S[3][3]));
        pm = fmaxf(pm, __shfl_xor(pm, 16));
        pm = fmaxf(pm, __shfl_xor(pm, 32));

        if (__any(pm > mM + 8.0f)) {
            float mn = fmaxf(mM, pm);
            float fs = exp2f(mM - mn);
            mM = mn;
            #pragma unroll
            for (int cs = 0; cs < 4; ++cs)
                #pragma unroll
                for (int r = 0; r < 4; ++r) O[cs][r] *= fs;
            #pragma unroll
            for (int r = 0; r < 4; ++r) lacc[r] *= fs;
        }

        #pragma unroll
        for (int st = 0; st < 4; ++st)
            #pragma unroll
            for (int r = 0; r < 4; ++r)
                S[st][r] = exp2f(S[st][r] - mM);

        unsigned int pk2[4][2];
        #pragma unroll
        for (int st = 0; st < 4; ++st) {
            pk2[st][0] = __builtin_bit_cast(unsigned int,
                             __builtin_amdgcn_cvt_pkrtz(S[st][0], S[st][1]));
            pk2[st][1] = __builtin_bit_cast(unsigned int,
                             __builtin_amdgcn_cvt_pkrtz(S[st][2], S[st][3]));
        }

        int srcA = lr + 32*(lk & 1);
        int sel  = lk >> 1;
        __builtin_amdgcn_s_setprio(1);
        #pragma unroll
        for (int ch2 = 0; ch2 < 2; ++ch2) {
            union { unsigned int u[4]; half8 h; } pb;
            #pragma unroll
            for (int w2 = 0; w2 < 4; ++w2) {
                int src = srcA + 16*(w2 >> 1);
                int lo = __shfl((int)pk2[ch2*2 + 0][w2 & 1], src);
                int hi = __shfl((int)pk2[ch2*2 + 1][w2 & 1], src);
                pb.u[w2] = (unsigned int)(sel ? hi : lo);
            }
            lacc = __builtin_amdgcn_mfma_f32_16x16x32_f16(ones, pb.h, lacc, 0, 0, 0);
            #pragma unroll
            for (int cs = 0; cs < 4; ++cs) {
                int crow = cs*16 + lr;
                half8 vA = *(const half8*)(sVb + ((crow*128 + ch2*64 + lk*16) ^ ((crow&7)<<4)));
                O[cs] = __builtin_amdgcn_mfma_f32_16x16x32_f16(vA, pb.h, O[cs], 0, 0, 0);
            }
        }
        __builtin_amdgcn_s_setprio(0);

        asm volatile("s_waitcnt vmcnt(0)" ::: "memory");
        __builtin_amdgcn_s_barrier();
    }

    if (lk == 0) {
        ml[q0 + w*16 + lr]       = mM;
        ml[TOK + q0 + w*16 + lr] = lacc[0];
    }

    #pragma unroll
    for (int h = 0; h < 2; ++h) {
        if ((w >> 2) == h) {
            #pragma unroll
            for (int cs = 0; cs < 4; ++cs)
                #pragma unroll
                for (int r = 0; r < 4; ++r)
                    ldsf[(cs*16 + 4*lk + r)*68 + wq*16 + lr] = O[cs][r];
        }
        __syncthreads();
        int c = tid >> 3, qs = (tid & 7) * 8;
        const float* srcr = &ldsf[c*68 + qs];
        float* dstr = &part[(size_t)c*TOK + q0 + h*64 + qs];
        *(float4*)&dstr[0] = *(const float4*)&srcr[0];
        *(float4*)&dstr[4] = *(const float4*)&srcr[4];
        __syncthreads();
    }
}

// ---------------- recombine KV-split partials (exp2 domain, float4, 288 blocks) ----------------
__global__ __launch_bounds__(256) void recombine_kernel(
    const float* __restrict__ ws, float* __restrict__ out)
{
    int bid = blockIdx.x;                       // 288
    int b   = bid / 144;
    int g2  = (bid % 144) * 256 + threadIdx.x;  // 0..36863
    int cq  = g2 / 2304;                        // channel quad 0..15
    int t   = (g2 % 2304) * 4;
    const float* mlp = ws + OFF_ML2;

    float4 m4[KSPLIT], l4[KSPLIT];
    float4 M = {-INFINITY, -INFINITY, -INFINITY, -INFINITY};
    #pragma unroll
    for (int ks = 0; ks < KSPLIT; ++ks) {
        int slab = b*KSPLIT + ks;
        m4[ks] = *(const float4*)&mlp[(size_t)slab*2*TOK + t];
        l4[ks] = *(const float4*)&mlp[(size_t)slab*2*TOK + TOK + t];
        M.x = fmaxf(M.x, m4[ks].x); M.y = fmaxf(M.y, m4[ks].y);
        M.z = fmaxf(M.z, m4[ks].z); M.w = fmaxf(M.w, m4[ks].w);
    }
    float4 wgt[KSPLIT];
    float4 den = {0.f, 0.f, 0.f, 0.f};
    #pragma unroll
    for (int ks = 0; ks < KSPLIT; ++ks) {
        wgt[ks].x = exp2f(m4[ks].x - M.x); wgt[ks].y = exp2f(m4[ks].y - M.y);
        wgt[ks].z = exp2f(m4[ks].z - M.z); wgt[ks].w = exp2f(m4[ks].w - M.w);
        den.x += l4[ks].x * wgt[ks].x; den.y += l4[ks].y * wgt[ks].y;
        den.z += l4[ks].z * wgt[ks].z; den.w += l4[ks].w * wgt[ks].w;
    }
    float4 inv = {1.f/den.x, 1.f/den.y, 1.f/den.z, 1.f/den.w};
    #pragma unroll
    for (int cc = 0; cc < 4; ++cc) {
        int c = cq*4 + cc;
        float4 acc = {0.f, 0.f, 0.f, 0.f};
        #pragma unroll
        for (int ks = 0; ks < KSPLIT; ++ks) {
            const float* part = part_base_c(ws, b*KSPLIT + ks);
            float4 p4 = *(const float4*)&part[(size_t)c*TOK + t];
            acc.x += p4.x * wgt[ks].x; acc.y += p4.y * wgt[ks].y;
            acc.z += p4.z * wgt[ks].z; acc.w += p4.w * wgt[ks].w;
        }
        float4 o4 = {acc.x*inv.x, acc.y*inv.y, acc.z*inv.z, acc.w*inv.w};
        *(float4*)&out[(size_t)(b*64 + c)*TOK + t] = o4;
    }
}

extern "C" void kernel_launch(void* const* d_in, const int* in_sizes, int n_in,
                              void* d_out, int out_size, void* d_ws, size_t ws_size,
                              hipStream_t stream)
{
    const float* frames = (const float*)d_in[0];
    const float* w1 = (const float*)d_in[1];
    const float* b1 = (const float*)d_in[2];
    const float* w2 = (const float*)d_in[3];
    const float* b2 = (const float*)d_in[4];
    const float* qw = (const float*)d_in[5];
    const float* qb = (const float*)d_in[6];
    const float* kw = (const float*)d_in[7];
    const float* kb = (const float*)d_in[8];
    const float* vw = (const float*)d_in[9];
    const float* vb = (const float*)d_in[10];
    float* ws = (float*)d_ws;
    float* out = (float*)d_out;

    hipLaunchKernelGGL(conv1_kernel, dim3(288), dim3(256), 0, stream,
                       frames, w1, b1, w2, b2, qw, qb, kw, kb, vw, vb, ws);
    hipLaunchKernelGGL(conv2qkv_kernel, dim3(288), dim3(256), 0, stream, ws);
    hipLaunchKernelGGL(attn_kernel, dim3(2*72*KSPLIT), dim3(512), 0, stream, ws);
    hipLaunchKernelGGL(recombine_kernel, dim3(288), dim3(256), 0, stream, ws, out);
}